// Round 6
// baseline (2826.014 us; speedup 1.0000x reference)
//
#include <hip/hip_runtime.h>
#include <math.h>

#define DEV __device__ __forceinline__

typedef __attribute__((ext_vector_type(8))) short bf8_t;   // 8 x bf16 (4 VGPR)
typedef __attribute__((ext_vector_type(4))) float f4_t;    // MFMA acc

DEV float gelu_f(float v) { return 0.5f * v * (1.0f + erff(v * 0.70710678118654752f)); }
DEV float sigm_f(float v) { return 1.0f / (1.0f + expf(-v)); }
DEV unsigned short f2bf(float f) {            // RNE float->bf16
  unsigned u = __float_as_uint(f);
  u = (u + 0x7FFFu + ((u >> 16) & 1u)) >> 16;
  return (unsigned short)u;
}
DEV float bf2f(unsigned short u) { return __uint_as_float((unsigned)u << 16); }

// ---------------------------------------------------------------------------
// Weight prep: conv weights -> bf16 [co][kh][kw][ci]; FLIP=1 for tconv
// ---------------------------------------------------------------------------
__global__ __launch_bounds__(256) void prepw_k(
    const float* __restrict__ w, unsigned short* __restrict__ wb,
    int COUT, int CIN, int FLIP)
{
  int idx = blockIdx.x * 256 + threadIdx.x;
  int total = COUT * CIN * 9;
  if (idx >= total) return;
  int ci = idx % CIN;
  int r  = idx / CIN;
  int kw = r % 3; r /= 3;
  int kh = r % 3;
  int co = r / 3;
  float v = FLIP ? w[((ci * COUT + co) * 3 + (2 - kh)) * 3 + (2 - kw)]
                 : w[((co * CIN + ci) * 3 + kh) * 3 + kw];
  wb[idx] = f2bf(v);
}

// el_w (256,4096 k_ref=c*64+s) -> bf16 [n][k_new=(s*64+c)]
__global__ __launch_bounds__(256) void prep_el_k(
    const float* __restrict__ w, unsigned short* __restrict__ wb)
{
  int idx = blockIdx.x * 256 + threadIdx.x;     // < 256*4096
  int kn = idx & 4095, n = idx >> 12;
  wb[idx] = f2bf(w[(size_t)n * 4096 + ((kn & 63) * 64 + (kn >> 6))]);
}

// dl_w (4096,256) row r=c*64+s -> bf16 rows nout=s*64+c
__global__ __launch_bounds__(256) void prep_dl_k(
    const float* __restrict__ w, unsigned short* __restrict__ wb)
{
  int idx = blockIdx.x * 256 + threadIdx.x;     // < 4096*256
  int k = idx & 255, nout = idx >> 8;
  wb[idx] = f2bf(w[(size_t)((nout & 63) * 64 + (nout >> 6)) * 256 + k]);
}

// LSTM weights (10,1024,256) -> bf16 frag-contiguous:
// wb[((l*64+nt)*8+ks)*512 + lane*8 + e] = W[l][nt*16+(lane&15)][ks*32+(lane>>4)*8+e]
__global__ __launch_bounds__(256) void prep_wlstm_k(
    const float* __restrict__ w, unsigned short* __restrict__ wb)
{
  int idx = blockIdx.x * 256 + threadIdx.x;   // exactly 2621440 = 10240 blocks
  int e = idx & 7, lane = (idx >> 3) & 63, ks = (idx >> 9) & 7;
  int nt = (idx >> 12) & 63, l = idx >> 18;
  wb[idx] = f2bf(w[((size_t)l * 1024 + nt * 16 + (lane & 15)) * 256
                   + ks * 32 + (lane >> 4) * 8 + e]);
}

// single-layer (1024x256) bf16 [j][k] -> frag layout (as prep_wlstm, l=0)
__global__ __launch_bounds__(256) void prep_wl1_k(
    const unsigned short* __restrict__ src, unsigned short* __restrict__ wb)
{
  int idx = blockIdx.x * 256 + threadIdx.x;   // 262144 = 1024 blocks
  int e = idx & 7, lane = (idx >> 3) & 63, ks = (idx >> 9) & 7, nt = idx >> 12;
  wb[idx] = src[(size_t)(nt * 16 + (lane & 15)) * 256 + ks * 32 + (lane >> 4) * 8 + e];
}

// fp32 -> bf16 flat cast
__global__ __launch_bounds__(256) void cast_bf16_k(
    const float* __restrict__ src, unsigned short* __restrict__ dst, int count)
{
  int idx = blockIdx.x * 256 + threadIdx.x;
  if (idx < count) dst[idx] = f2bf(src[idx]);
}

// lwT bf16: lwTb[kcol*256 + n] = lw[n*256 + kcol]
__global__ __launch_bounds__(256) void prep_lwt_k(
    const float* __restrict__ lw, unsigned short* __restrict__ lwTb)
{
  int idx = blockIdx.x * 256 + threadIdx.x;   // 65536
  int n = idx & 255, kcol = idx >> 8;
  lwTb[idx] = f2bf(lw[(size_t)n * 256 + kcol]);
}

// beff[j] = sum_n Wih0[j,n]*lb[n] + bih0[j]
__global__ __launch_bounds__(256) void beff_k(
    const float* __restrict__ Wih, const float* __restrict__ lb,
    const float* __restrict__ bih, float* __restrict__ beff)
{
  int j = blockIdx.x * 256 + threadIdx.x;     // < 1024
  float s = bih[j];
  const float* row = Wih + (size_t)j * 256;
  for (int n = 0; n < 256; ++n) s = fmaf(row[n], lb[n], s);
  beff[j] = s;
}

// ---------------------------------------------------------------------------
// ec1: 1ch 64x64 s2 -> 32ch 32x32, NHWC bf16 out. 1024 images.
// ---------------------------------------------------------------------------
__global__ __launch_bounds__(256) void ec1_k(
    const float* __restrict__ x, const float* __restrict__ t,
    const float* __restrict__ w, const float* __restrict__ bias,
    unsigned short* __restrict__ out)
{
  __shared__ float sw[288];
  __shared__ float sb[32];
  for (int i = threadIdx.x; i < 288; i += 256) sw[i] = w[i];
  if (threadIdx.x < 32) sb[threadIdx.x] = bias[threadIdx.x];
  __syncthreads();
  int idx = blockIdx.x * 256 + threadIdx.x;     // < 1024*32*32
  int ox = idx & 31, oy = (idx >> 5) & 31, n = idx >> 10;
  int b = n >> 5, j = n & 31;
  const float* ip = (j < 16) ? (x + (size_t)(b * 16 + j) * 4096)
                             : (t + (size_t)(b * 16 + j - 16) * 4096);
  float pv[9];
#pragma unroll
  for (int kh = 0; kh < 3; ++kh) {
    int iy = oy * 2 + kh - 1;
#pragma unroll
    for (int kw = 0; kw < 3; ++kw) {
      int ix = ox * 2 + kw - 1;
      pv[kh * 3 + kw] = ((unsigned)iy < 64u && (unsigned)ix < 64u) ? ip[iy * 64 + ix] : 0.f;
    }
  }
  unsigned short u[32];
#pragma unroll
  for (int co = 0; co < 32; ++co) {
    float a = sb[co];
#pragma unroll
    for (int i = 0; i < 9; ++i) a = fmaf(pv[i], sw[co * 9 + i], a);
    u[co] = f2bf(gelu_f(a));
  }
  unsigned short* op = out + (size_t)idx * 32;
#pragma unroll
  for (int p = 0; p < 4; ++p) {
    uint4 v;
    v.x = u[p*8+0] | (u[p*8+1] << 16);
    v.y = u[p*8+2] | (u[p*8+3] << 16);
    v.z = u[p*8+4] | (u[p*8+5] << 16);
    v.w = u[p*8+6] | (u[p*8+7] << 16);
    *(uint4*)&op[p * 8] = v;
  }
}

// ---------------------------------------------------------------------------
// MFMA implicit-GEMM conv. NHWC bf16 in/out. MODE: 0=s1, 1=s2, 2=tconv(ups2).
// ---------------------------------------------------------------------------
template<int CIN, int COUT, int HIN, int WIN, int TH, int TW, int MODE>
__global__ __launch_bounds__(256) void convmf_k(
    const unsigned short* __restrict__ in, const unsigned short* __restrict__ wb,
    const float* __restrict__ bias, unsigned short* __restrict__ out)
{
  constexpr int HO  = (MODE == 1) ? HIN / 2 : (MODE == 2 ? HIN * 2 : HIN);
  constexpr int WO  = (MODE == 1) ? WIN / 2 : (MODE == 2 ? WIN * 2 : WIN);
  constexpr int TIH = (MODE == 1) ? 2 * TH + 1 : TH + 2;
  constexpr int TIW = (MODE == 1) ? 2 * TW + 1 : TW + 2;
  constexpr int CG  = CIN / 8;
  constexpr int K   = 9 * CIN;
  constexpr int KS  = K / 32;
  constexpr int NT  = COUT / 16;
  constexpr int MT  = (TH * TW) / 16;
  constexpr int MPW = MT / 4;
  constexpr int TY  = HO / TH, TX = WO / TW;

  __shared__ unsigned short lds[TIH * TIW * CG * 8];

  const int bid = blockIdx.x;
  const int n = bid / (TY * TX);
  const int trem = bid % (TY * TX);
  const int ty0 = (trem / TX) * TH, tx0 = (trem % TX) * TW;

  constexpr int ENT = TIH * TIW * CG;
  for (int e = threadIdx.x; e < ENT; e += 256) {
    int txx = e % TIW;
    int rr  = e / TIW;
    int cg  = rr % CG;
    int tyy = rr / CG;
    int iy, ix; bool ok;
    if (MODE == 0) {
      iy = ty0 + tyy - 1; ix = tx0 + txx - 1;
      ok = (unsigned)iy < (unsigned)HIN && (unsigned)ix < (unsigned)WIN;
    } else if (MODE == 1) {
      iy = 2 * ty0 + tyy - 1; ix = 2 * tx0 + txx - 1;
      ok = (unsigned)iy < (unsigned)HIN && (unsigned)ix < (unsigned)WIN;
    } else {
      int vy = ty0 + tyy - 1, vx = tx0 + txx - 1;
      ok = vy >= 0 && vx >= 0 && !(vy & 1) && !(vx & 1);
      iy = vy >> 1; ix = vx >> 1;
      ok = ok && iy < HIN && ix < WIN;
    }
    int4 val = {0, 0, 0, 0};
    if (ok) val = *(const int4*)&in[(((size_t)n * HIN + iy) * WIN + ix) * CIN + cg * 8];
    *(int4*)&lds[(size_t)e * 8] = val;
  }
  __syncthreads();

  const int lane = threadIdx.x & 63, wv = threadIdx.x >> 6;
  const int l15 = lane & 15, l4 = lane >> 4;

  f4_t acc[MPW][NT] = {};
  for (int ks = 0; ks < KS; ++ks) {
    const int tap = (ks * 32) / CIN;
    const int kh = tap / 3, kw = tap % 3;
    const int cb = ((ks * 32) % CIN) / 8 + l4;
    bf8_t bf[NT];
#pragma unroll
    for (int nt = 0; nt < NT; ++nt)
      bf[nt] = *(const bf8_t*)&wb[(size_t)(nt * 16 + l15) * K + ks * 32 + 8 * l4];
#pragma unroll
    for (int mi = 0; mi < MPW; ++mi) {
      int m = (wv * MPW + mi) * 16 + l15;
      int oy = m / TW, ox = m % TW;
      int rt = ((MODE == 1) ? 2 * oy : oy) + kh;
      int ct = ((MODE == 1) ? 2 * ox : ox) + kw;
      bf8_t a = *(const bf8_t*)&lds[(((size_t)rt * CG + cb) * TIW + ct) * 8];
#pragma unroll
      for (int nt = 0; nt < NT; ++nt)
        acc[mi][nt] = __builtin_amdgcn_mfma_f32_16x16x32_bf16(a, bf[nt], acc[mi][nt], 0, 0, 0);
    }
  }

#pragma unroll
  for (int mi = 0; mi < MPW; ++mi) {
    int mbase = (wv * MPW + mi) * 16;
#pragma unroll
    for (int nt = 0; nt < NT; ++nt) {
      int co = nt * 16 + l15;
      float bv = bias[co];
#pragma unroll
      for (int r = 0; r < 4; ++r) {
        int m = mbase + l4 * 4 + r;
        int oy = m / TW, ox = m % TW;
        float v = acc[mi][nt][r] + bv;
        out[(((size_t)n * HO + ty0 + oy) * WO + (tx0 + ox)) * COUT + co] = f2bf(gelu_f(v));
      }
    }
  }
}

// ---------------------------------------------------------------------------
// MFMA GEMM: C[m][n] = act(sum_k A[m][k]*B[n][k] + bias).
// BIASMODE: 0 = bias[col], 1 = dl-permuted bias, 2 = no bias.
// ---------------------------------------------------------------------------
template<int BIASMODE, bool GELU, bool OUTBF16>
__global__ __launch_bounds__(256) void gemm16_k(
    const unsigned short* __restrict__ A, const unsigned short* __restrict__ Bw,
    const float* __restrict__ bias, void* __restrict__ Cv, int M, int N, int K)
{
  const int lane = threadIdx.x & 63, wv = threadIdx.x >> 6;
  const int l15 = lane & 15, l4 = lane >> 4;
  const int mbase = blockIdx.y * 64 + wv * 16;
  const int nbase = blockIdx.x * 64;
  f4_t acc[4] = {};
  for (int k0 = 0; k0 < K; k0 += 32) {
    bf8_t a = *(const bf8_t*)&A[(size_t)(mbase + l15) * K + k0 + 8 * l4];
#pragma unroll
    for (int nt = 0; nt < 4; ++nt) {
      bf8_t b = *(const bf8_t*)&Bw[(size_t)(nbase + nt * 16 + l15) * K + k0 + 8 * l4];
      acc[nt] = __builtin_amdgcn_mfma_f32_16x16x32_bf16(a, b, acc[nt], 0, 0, 0);
    }
  }
#pragma unroll
  for (int nt = 0; nt < 4; ++nt) {
    int col = nbase + nt * 16 + l15;
    float bv = 0.f;
    if (BIASMODE == 0) bv = bias[col];
    if (BIASMODE == 1) bv = bias[(col & 63) * 64 + (col >> 6)];
#pragma unroll
    for (int r = 0; r < 4; ++r) {
      int row = mbase + l4 * 4 + r;
      float v = acc[nt][r] + bv;
      if (GELU) v = gelu_f(v);
      if (OUTBF16) ((unsigned short*)Cv)[(size_t)row * N + col] = f2bf(v);
      else         ((float*)Cv)[(size_t)row * N + col] = v;
    }
  }
}

// ---------------------------------------------------------------------------
// dt3 (tconv 32->1) + tanh + fused loss partials. bf16 NHWC in. 1024 images.
// ---------------------------------------------------------------------------
__global__ __launch_bounds__(256) void dt3_loss_k(
    const unsigned short* __restrict__ in,
    const float* __restrict__ w, const float* __restrict__ bias,
    const float* __restrict__ xref, const float* __restrict__ tref,
    float* __restrict__ fout, float* __restrict__ partials)
{
  __shared__ float sw[288];
  for (int i = threadIdx.x; i < 288; i += 256) sw[i] = w[i];
  __syncthreads();
  int idx = blockIdx.x * 256 + threadIdx.x;
  int q = idx & 63, p = (idx >> 6) & 63, n = idx >> 12;
  float acc = bias[0];
#pragma unroll
  for (int kh = 0; kh < 3; ++kh) {
    int u = p + kh - 1;
    if (u < 0 || (u & 1) || u >= 64) continue;
#pragma unroll
    for (int kw = 0; kw < 3; ++kw) {
      int v = q + kw - 1;
      if (v < 0 || (v & 1) || v >= 64) continue;
      const unsigned short* row = in + (((size_t)n * 32 + (u >> 1)) * 32 + (v >> 1)) * 32;
      int wo = (2 - kh) * 3 + (2 - kw);
#pragma unroll
      for (int w2 = 0; w2 < 16; ++w2) {
        unsigned dv = *(const unsigned*)&row[w2 * 2];
        acc = fmaf(__uint_as_float(dv << 16),        sw[(2 * w2) * 9 + wo], acc);
        acc = fmaf(__uint_as_float(dv & 0xffff0000u), sw[(2 * w2 + 1) * 9 + wo], acc);
      }
    }
  }
  float val = tanhf(acc);
  float d;
  int pix = p * 64 + q;
  if (n < 512) {
    fout[(size_t)n * 4096 + pix] = val;
    d = val - tref[(size_t)n * 4096 + pix];
  } else {
    d = val - xref[(size_t)(n - 512) * 4096 + pix];
  }
  __shared__ float red[256];
  red[threadIdx.x] = d * d;
  __syncthreads();
#pragma unroll
  for (int s = 128; s > 0; s >>= 1) {
    if (threadIdx.x < s) red[threadIdx.x] += red[threadIdx.x + s];
    __syncthreads();
  }
  if (threadIdx.x == 0) partials[blockIdx.x] = red[0];
}

__global__ __launch_bounds__(256) void loss_final_k(
    const float* __restrict__ partials, float* __restrict__ out01)
{
  __shared__ float red[256];
  int base = blockIdx.x * 8192;
  float s = 0.f;
  for (int i = threadIdx.x; i < 8192; i += 256) s += partials[base + i];
  red[threadIdx.x] = s;
  __syncthreads();
#pragma unroll
  for (int st = 128; st > 0; st >>= 1) {
    if (threadIdx.x < st) red[threadIdx.x] += red[threadIdx.x + st];
    __syncthreads();
  }
  if (threadIdx.x == 0) out01[blockIdx.x] = red[0] * (1.0f / 2097152.0f);
}

// ---------------------------------------------------------------------------
// LSTM v5: MFMA, 16 blocks x 256 thr (4 waves = 4 gates), register-prefetch
// cell (all 48 fragment loads issued before the MFMA chain; 4 acc chains).
// Phase 1: diagonal wavefront t=0..15 (25 barriers). Phase 2: t=16..30
// serial with lw-projection folded into l=0 (Meff), 150 barriers.
// h9 snapshots -> post-loop GEMM for outs.
// ---------------------------------------------------------------------------
#define LSTM_NB 16

DEV void gridbar(unsigned* bar, unsigned target) {
  __syncthreads();
  if (threadIdx.x == 0) {
    __hip_atomic_fetch_add(bar, 1u, __ATOMIC_RELEASE, __HIP_MEMORY_SCOPE_AGENT);
    unsigned spins = 0;
    while (__hip_atomic_load(bar, __ATOMIC_RELAXED, __HIP_MEMORY_SCOPE_AGENT) < target) {
      __builtin_amdgcn_s_sleep(2);
      if (++spins > (1u << 24)) break;   // safety valve
    }
    (void)__hip_atomic_load(bar, __ATOMIC_ACQUIRE, __HIP_MEMORY_SCOPE_AGENT);
  }
  __syncthreads();
}

__global__ __launch_bounds__(256, 1) void lstm5_k(
    const float* __restrict__ z,              // (1024,256) fp32, row = b*32+t
    const unsigned short* __restrict__ wihb,  // frag-swizzled bf16 (10 layers)
    const unsigned short* __restrict__ whhb,
    const unsigned short* __restrict__ meffb, // frag-swizzled Meff (1 layer)
    const float* __restrict__ bih, const float* __restrict__ bhh,
    const float* __restrict__ beff,
    unsigned short* __restrict__ zbf,     // (16,32,256) bf16 [t][b][k]
    unsigned short* __restrict__ hbf,     // (2,10,32,256) bf16
    unsigned short* __restrict__ h9sav,   // (16,32,256) bf16, slot tt=t-15
    unsigned* __restrict__ bar)
{
  __shared__ float zsm[4 * 32 * 17];    // [gate][row][col16 pad17]
  __shared__ float cls[10 * 32 * 16];   // c state [l][b][j]
  __shared__ float sbias[640];          // bih+bhh [l][g][j]
  __shared__ float sb2[64];             // beff+bhh0 [g][j]

  const int tid = threadIdx.x;
  const int bid = blockIdx.x;           // 0..15
  const int col0 = bid * 16;
  const int lane = tid & 63, g = tid >> 6;      // wave = gate
  const int l15 = lane & 15, l4 = lane >> 4;
  const int gtid = bid * 256 + tid;

  // ---- init ----
  for (int i = gtid; i < 16 * 32 * 256; i += LSTM_NB * 256) {
    int k = i & 255, r = i >> 8;              // dest row r = t*32 + b
    int tt = r >> 5, b = r & 31;
    zbf[i] = f2bf(z[(size_t)(b * 32 + tt) * 256 + k]);
  }
  for (int i = gtid; i < 81920; i += LSTM_NB * 256) hbf[81920 + i] = 0;
  for (int i = tid; i < 5120; i += 256) cls[i] = 0.f;
  for (int i = tid; i < 640; i += 256) {
    int l = i >> 6, gg = (i >> 4) & 3, j = i & 15;
    sbias[i] = bih[l * 1024 + gg * 256 + col0 + j]
             + bhh[l * 1024 + gg * 256 + col0 + j];
  }
  if (tid < 64) {
    int gg = tid >> 4, j = tid & 15;
    sb2[tid] = beff[gg * 256 + col0 + j] + bhh[gg * 256 + col0 + j];
  }

  unsigned ep = 0;
  ++ep; gridbar(bar, ep * LSTM_NB);

  auto cell = [&](int t, int l, bool p2l0) {
    const int cur = t & 1, prv = cur ^ 1;
    const unsigned short* xb =
        p2l0 ? (hbf + (size_t)((prv * 10 + 9) * 32) * 256)
             : ((l == 0) ? (zbf + (size_t)t * 32 * 256)
                         : (hbf + (size_t)((cur * 10 + l - 1) * 32) * 256));
    const unsigned short* hb = hbf + (size_t)((prv * 10 + l) * 32) * 256;
    const unsigned short* wi =
        p2l0 ? (meffb + (size_t)((g * 16 + bid) * 8) * 512)
             : (wihb + (size_t)((l * 64 + g * 16 + bid) * 8) * 512);
    const unsigned short* wh = whhb + (size_t)((l * 64 + g * 16 + bid) * 8) * 512;

    // ---- prefetch ALL fragments into registers (48 independent loads) ----
    bf8_t bwi[8], bwh[8], ax0[8], ax1[8], ah0[8], ah1[8];
#pragma unroll
    for (int ks = 0; ks < 8; ++ks) {
      bwi[ks] = *(const bf8_t*)&wi[ks * 512 + lane * 8];
      bwh[ks] = *(const bf8_t*)&wh[ks * 512 + lane * 8];
    }
#pragma unroll
    for (int ks = 0; ks < 8; ++ks) {
      ax0[ks] = *(const bf8_t*)&xb[(l15) * 256 + ks * 32 + l4 * 8];
      ax1[ks] = *(const bf8_t*)&xb[(16 + l15) * 256 + ks * 32 + l4 * 8];
      ah0[ks] = *(const bf8_t*)&hb[(l15) * 256 + ks * 32 + l4 * 8];
      ah1[ks] = *(const bf8_t*)&hb[(16 + l15) * 256 + ks * 32 + l4 * 8];
    }
    // ---- 4 independent MFMA chains of 8 ----
    f4_t a0 = {}, a1 = {}, b0 = {}, b1 = {};
#pragma unroll
    for (int ks = 0; ks < 8; ++ks) {
      a0 = __builtin_amdgcn_mfma_f32_16x16x32_bf16(ax0[ks], bwi[ks], a0, 0, 0, 0);
      a1 = __builtin_amdgcn_mfma_f32_16x16x32_bf16(ax1[ks], bwi[ks], a1, 0, 0, 0);
      b0 = __builtin_amdgcn_mfma_f32_16x16x32_bf16(ah0[ks], bwh[ks], b0, 0, 0, 0);
      b1 = __builtin_amdgcn_mfma_f32_16x16x32_bf16(ah1[ks], bwh[ks], b1, 0, 0, 0);
    }
#pragma unroll
    for (int r = 0; r < 4; ++r) {
      zsm[(g * 32 + l4 * 4 + r) * 17 + l15] = a0[r] + b0[r];
      zsm[(g * 32 + 16 + l4 * 4 + r) * 17 + l15] = a1[r] + b1[r];
    }
    __syncthreads();
    // gate math: 32 rows x 16 cols = 512 elems, 2 per thread
#pragma unroll
    for (int half = 0; half < 2; ++half) {
      int e = tid + half * 256;
      int b = e >> 4, j = e & 15;
      float bi_, bf_, bg_, bo_;
      if (p2l0) { bi_ = sb2[j]; bf_ = sb2[16 + j]; bg_ = sb2[32 + j]; bo_ = sb2[48 + j]; }
      else {
        bi_ = sbias[l * 64 + j];      bf_ = sbias[l * 64 + 16 + j];
        bg_ = sbias[l * 64 + 32 + j]; bo_ = sbias[l * 64 + 48 + j];
      }
      float zi = zsm[(0 * 32 + b) * 17 + j] + bi_;
      float zf = zsm[(1 * 32 + b) * 17 + j] + bf_;
      float zg = zsm[(2 * 32 + b) * 17 + j] + bg_;
      float zo = zsm[(3 * 32 + b) * 17 + j] + bo_;
      float cold = cls[(l * 32 + b) * 16 + j];
      float cn = sigm_f(zf) * cold + sigm_f(zi) * tanhf(zg);
      cls[(l * 32 + b) * 16 + j] = cn;
      float hn = sigm_f(zo) * tanhf(cn);
      unsigned short hv = f2bf(hn);
      hbf[(size_t)(((t & 1) * 10 + l) * 32 + b) * 256 + col0 + j] = hv;
      if (l == 9 && t >= 15) h9sav[(size_t)((t - 15) * 32 + b) * 256 + col0 + j] = hv;
    }
    __syncthreads();
  };

  // ---- phase 1: diagonal wavefront over (t,l), t<=15 ----
  for (int d = 0; d <= 24; ++d) {
    int tlo = d - 9 > 0 ? d - 9 : 0;
    int thi = d < 15 ? d : 15;
    for (int t = tlo; t <= thi; ++t) cell(t, d - t, false);
    ++ep; gridbar(bar, ep * LSTM_NB);
  }
  // ---- phase 2: serial t=16..30 (out(30) needs the full t=30 stack) ----
  for (int t = 16; t <= 30; ++t) {
    for (int l = 0; l < 10; ++l) {
      cell(t, l, l == 0);
      ++ep; gridbar(bar, ep * LSTM_NB);
    }
  }
}

// ---------------------------------------------------------------------------
// Decoder input gather -> bf16: rows 0..511 = y_t, rows 512..1023 = z_x
// ---------------------------------------------------------------------------
__global__ __launch_bounds__(256) void gather_dec_k(
    const float* __restrict__ outs, const float* __restrict__ z,
    unsigned short* __restrict__ ydec)
{
  int idx = blockIdx.x * 256 + threadIdx.x;   // < 262144
  int rrow = idx >> 8, k = idx & 255;
  float v;
  if (rrow < 512) {
    int b = rrow >> 4, i = rrow & 15;
    v = outs[(size_t)((15 + i) * 32 + b) * 256 + k];
  } else {
    int rr = rrow - 512;
    int b = rr >> 4, tt = rr & 15;
    v = z[(size_t)(b * 32 + tt) * 256 + k];
  }
  ydec[idx] = f2bf(v);
}

// ---------------------------------------------------------------------------
extern "C" void kernel_launch(void* const* d_in, const int* in_sizes, int n_in,
                              void* d_out, int out_size, void* d_ws, size_t ws_size,
                              hipStream_t stream) {
  const float* x     = (const float*)d_in[0];
  const float* t     = (const float*)d_in[1];
  const float* ec1_w = (const float*)d_in[2];
  const float* ec1_b = (const float*)d_in[3];
  const float* ec2_w = (const float*)d_in[4];
  const float* ec2_b = (const float*)d_in[5];
  const float* ec3_w = (const float*)d_in[6];
  const float* ec3_b = (const float*)d_in[7];
  const float* ec4_w = (const float*)d_in[8];
  const float* ec4_b = (const float*)d_in[9];
  const float* ec5_w = (const float*)d_in[10];
  const float* ec5_b = (const float*)d_in[11];
  const float* el_w  = (const float*)d_in[12];
  const float* el_b  = (const float*)d_in[13];
  const float* dl_w  = (const float*)d_in[14];
  const float* dl_b  = (const float*)d_in[15];
  const float* dt1_w = (const float*)d_in[16];
  const float* dt1_b = (const float*)d_in[17];
  const float* dc1_w = (const float*)d_in[18];
  const float* dc1_b = (const float*)d_in[19];
  const float* dt2_w = (const float*)d_in[20];
  const float* dt2_b = (const float*)d_in[21];
  const float* dc2_w = (const float*)d_in[22];
  const float* dc2_b = (const float*)d_in[23];
  const float* dt3_w = (const float*)d_in[24];
  const float* dt3_b = (const float*)d_in[25];
  const float* Wih   = (const float*)d_in[26];
  const float* Whh   = (const float*)d_in[27];
  const float* bih   = (const float*)d_in[28];
  const float* bhh   = (const float*)d_in[29];
  const float* lw    = (const float*)d_in[30];
  const float* lb    = (const float*)d_in[31];
  float* out = (float*)d_out;

  char* base = (char*)d_ws;
  size_t off = 0;
  auto alloc = [&](size_t bytes) -> char* {
    char* p = base + off;
    off += (bytes + 255) & ~(size_t)255;
    return p;
  };
  typedef unsigned short us;
  unsigned* bar   = (unsigned*)alloc(256);
  float* zbuf     = (float*)alloc((size_t)1024 * 256 * 4);
  float* outsbuf  = (float*)alloc((size_t)31 * 32 * 256 * 4);
  us*    zbf      = (us*)alloc((size_t)16 * 32 * 256 * 2);
  us*    hbf      = (us*)alloc((size_t)2 * 10 * 32 * 256 * 2);
  us*    h9sav    = (us*)alloc((size_t)16 * 32 * 256 * 2);
  us*    ydec     = (us*)alloc((size_t)1024 * 256 * 2);
  float* partials = (float*)alloc((size_t)16384 * 4);
  us* wb_ec2 = (us*)alloc((size_t)32 * 288 * 2);
  us* wb_ec3 = (us*)alloc((size_t)64 * 288 * 2);
  us* wb_ec4 = (us*)alloc((size_t)64 * 576 * 2);
  us* wb_ec5 = (us*)alloc((size_t)64 * 576 * 2);
  us* wb_dt1 = (us*)alloc((size_t)64 * 576 * 2);
  us* wb_dc1 = (us*)alloc((size_t)64 * 576 * 2);
  us* wb_dt2 = (us*)alloc((size_t)32 * 576 * 2);
  us* wb_dc2 = (us*)alloc((size_t)32 * 288 * 2);
  us* elWb   = (us*)alloc((size_t)256 * 4096 * 2);
  us* dlWb   = (us*)alloc((size_t)4096 * 256 * 2);
  us* wihb   = (us*)alloc((size_t)10 * 1024 * 256 * 2);      // 5 MB
  us* whhb   = (us*)alloc((size_t)10 * 1024 * 256 * 2);      // 5 MB
  us* wih0b  = (us*)alloc((size_t)1024 * 256 * 2);
  us* lwTb   = (us*)alloc((size_t)256 * 256 * 2);
  us* lwbp   = (us*)alloc((size_t)256 * 256 * 2);
  us* meffp  = (us*)alloc((size_t)1024 * 256 * 2);
  us* meffb  = (us*)alloc((size_t)1024 * 256 * 2);
  float* beff = (float*)alloc((size_t)1024 * 4);
  us* enc5   = (us*)alloc((size_t)1024 * 4096 * 2);          // 8.4 MB
  us* bufA   = (us*)alloc((size_t)1024 * 32 * 32 * 32 * 2);  // 67 MB
  us* bufB   = (us*)alloc((size_t)1024 * 32 * 32 * 32 * 2);  // 67 MB
  (void)in_sizes; (void)n_in; (void)out_size; (void)ws_size;

  hipMemsetAsync(bar, 0, 16, stream);

  // ---- weight prep ----
  prepw_k<<<(32*32*9+255)/256, 256, 0, stream>>>(ec2_w, wb_ec2, 32, 32, 0);
  prepw_k<<<(64*32*9+255)/256, 256, 0, stream>>>(ec3_w, wb_ec3, 64, 32, 0);
  prepw_k<<<(64*64*9+255)/256, 256, 0, stream>>>(ec4_w, wb_ec4, 64, 64, 0);
  prepw_k<<<(64*64*9+255)/256, 256, 0, stream>>>(ec5_w, wb_ec5, 64, 64, 0);
  prepw_k<<<(64*64*9+255)/256, 256, 0, stream>>>(dt1_w, wb_dt1, 64, 64, 1);
  prepw_k<<<(64*64*9+255)/256, 256, 0, stream>>>(dc1_w, wb_dc1, 64, 64, 0);
  prepw_k<<<(32*64*9+255)/256, 256, 0, stream>>>(dt2_w, wb_dt2, 32, 64, 1);
  prepw_k<<<(32*32*9+255)/256, 256, 0, stream>>>(dc2_w, wb_dc2, 32, 32, 0);
  prep_el_k<<<4096, 256, 0, stream>>>(el_w, elWb);
  prep_dl_k<<<4096, 256, 0, stream>>>(dl_w, dlWb);
  prep_wlstm_k<<<10240, 256, 0, stream>>>(Wih, wihb);
  prep_wlstm_k<<<10240, 256, 0, stream>>>(Whh, whhb);
  // Meff = Wih0 @ lw (1024x256), beff = Wih0 @ lb + bih0
  cast_bf16_k<<<1024, 256, 0, stream>>>(Wih, wih0b, 262144);
  prep_lwt_k<<<256, 256, 0, stream>>>(lw, lwTb);
  cast_bf16_k<<<256, 256, 0, stream>>>(lw, lwbp, 65536);
  gemm16_k<2, false, true><<<dim3(4, 16), 256, 0, stream>>>(wih0b, lwTb, lb, meffp, 1024, 256, 256);
  prep_wl1_k<<<1024, 256, 0, stream>>>(meffp, meffb);
  beff_k<<<4, 256, 0, stream>>>(Wih, lb, bih, beff);

  // ---- encoder: single 1024-image pass ----
  ec1_k<<<4096, 256, 0, stream>>>(x, t, ec1_w, ec1_b, bufA);
  convmf_k<32, 32, 32, 32, 32, 32, 0><<<1024, 256, 0, stream>>>(bufA, wb_ec2, ec2_b, bufB);
  convmf_k<32, 64, 32, 32, 16, 16, 1><<<1024, 256, 0, stream>>>(bufB, wb_ec3, ec3_b, bufA);
  convmf_k<64, 64, 16, 16, 16, 16, 0><<<1024, 256, 0, stream>>>(bufA, wb_ec4, ec4_b, bufB);
  convmf_k<64, 64, 16, 16, 8, 8, 1><<<1024, 256, 0, stream>>>(bufB, wb_ec5, ec5_b, enc5);
  gemm16_k<0, false, false><<<dim3(4, 16), 256, 0, stream>>>(enc5, elWb, el_b, zbuf, 1024, 256, 4096);

  // ---- LSTM (MFMA, 16 blocks, 176 grid barriers) ----
  lstm5_k<<<LSTM_NB, 256, 0, stream>>>(zbuf, wihb, whhb, meffb, bih, bhh, beff,
                                       zbf, hbf, h9sav, bar);
  // outs[t=15..30] = h9sav @ lw^T + lb
  gemm16_k<0, false, false><<<dim3(4, 8), 256, 0, stream>>>(
      h9sav, lwbp, lb, outsbuf + (size_t)15 * 32 * 256, 512, 256, 256);

  // ---- decoder: single 1024-row pass (rows 0..511 pred, 512..1023 rec) ----
  gather_dec_k<<<1024, 256, 0, stream>>>(outsbuf, zbuf, ydec);
  gemm16_k<1, true, true><<<dim3(64, 16), 256, 0, stream>>>(ydec, dlWb, dl_b, bufB, 1024, 4096, 256);
  convmf_k<64, 64, 8, 8, 16, 16, 2><<<1024, 256, 0, stream>>>(bufB, wb_dt1, dt1_b, bufA);
  convmf_k<64, 64, 16, 16, 16, 16, 0><<<1024, 256, 0, stream>>>(bufA, wb_dc1, dc1_b, bufB);
  convmf_k<64, 32, 16, 16, 16, 32, 2><<<2048, 256, 0, stream>>>(bufB, wb_dt2, dt2_b, bufA);
  convmf_k<32, 32, 32, 32, 32, 32, 0><<<1024, 256, 0, stream>>>(bufA, wb_dc2, dc2_b, bufB);
  dt3_loss_k<<<16384, 256, 0, stream>>>(bufB, dt3_w, dt3_b, x, t, out + 2, partials);
  loss_final_k<<<2, 256, 0, stream>>>(partials, out);
}

// Round 7
// 2334.515 us; speedup vs baseline: 1.2105x; 1.2105x over previous
//
#include <hip/hip_runtime.h>
#include <math.h>

#define DEV __device__ __forceinline__

typedef __attribute__((ext_vector_type(8))) short bf8_t;   // 8 x bf16 (4 VGPR)
typedef __attribute__((ext_vector_type(4))) float f4_t;    // MFMA acc

DEV float gelu_f(float v) { return 0.5f * v * (1.0f + erff(v * 0.70710678118654752f)); }
DEV float sigm_f(float v) { return 1.0f / (1.0f + expf(-v)); }
DEV unsigned short f2bf(float f) {            // RNE float->bf16
  unsigned u = __float_as_uint(f);
  u = (u + 0x7FFFu + ((u >> 16) & 1u)) >> 16;
  return (unsigned short)u;
}
DEV float bf2f(unsigned short u) { return __uint_as_float((unsigned)u << 16); }

// ---------------------------------------------------------------------------
// Weight prep: conv weights -> bf16 [co][kh][kw][ci]; FLIP=1 for tconv
// ---------------------------------------------------------------------------
__global__ __launch_bounds__(256) void prepw_k(
    const float* __restrict__ w, unsigned short* __restrict__ wb,
    int COUT, int CIN, int FLIP)
{
  int idx = blockIdx.x * 256 + threadIdx.x;
  int total = COUT * CIN * 9;
  if (idx >= total) return;
  int ci = idx % CIN;
  int r  = idx / CIN;
  int kw = r % 3; r /= 3;
  int kh = r % 3;
  int co = r / 3;
  float v = FLIP ? w[((ci * COUT + co) * 3 + (2 - kh)) * 3 + (2 - kw)]
                 : w[((co * CIN + ci) * 3 + kh) * 3 + kw];
  wb[idx] = f2bf(v);
}

// el_w (256,4096 k_ref=c*64+s) -> bf16 [n][k_new=(s*64+c)]
__global__ __launch_bounds__(256) void prep_el_k(
    const float* __restrict__ w, unsigned short* __restrict__ wb)
{
  int idx = blockIdx.x * 256 + threadIdx.x;     // < 256*4096
  int kn = idx & 4095, n = idx >> 12;
  wb[idx] = f2bf(w[(size_t)n * 4096 + ((kn & 63) * 64 + (kn >> 6))]);
}

// dl_w (4096,256) row r=c*64+s -> bf16 rows nout=s*64+c
__global__ __launch_bounds__(256) void prep_dl_k(
    const float* __restrict__ w, unsigned short* __restrict__ wb)
{
  int idx = blockIdx.x * 256 + threadIdx.x;     // < 4096*256
  int k = idx & 255, nout = idx >> 8;
  wb[idx] = f2bf(w[(size_t)((nout & 63) * 64 + (nout >> 6)) * 256 + k]);
}

// LSTM weights (10,1024,256) -> bf16 frag-contiguous:
// wb[((l*64+nt)*8+ks)*512 + lane*8 + e] = W[l][nt*16+(lane&15)][ks*32+(lane>>4)*8+e]
__global__ __launch_bounds__(256) void prep_wlstm_k(
    const float* __restrict__ w, unsigned short* __restrict__ wb)
{
  int idx = blockIdx.x * 256 + threadIdx.x;   // exactly 2621440 = 10240 blocks
  int e = idx & 7, lane = (idx >> 3) & 63, ks = (idx >> 9) & 7;
  int nt = (idx >> 12) & 63, l = idx >> 18;
  wb[idx] = f2bf(w[((size_t)l * 1024 + nt * 16 + (lane & 15)) * 256
                   + ks * 32 + (lane >> 4) * 8 + e]);
}

// single-layer (1024x256) bf16 [j][k] -> frag layout (as prep_wlstm, l=0)
__global__ __launch_bounds__(256) void prep_wl1_k(
    const unsigned short* __restrict__ src, unsigned short* __restrict__ wb)
{
  int idx = blockIdx.x * 256 + threadIdx.x;   // 262144 = 1024 blocks
  int e = idx & 7, lane = (idx >> 3) & 63, ks = (idx >> 9) & 7, nt = idx >> 12;
  wb[idx] = src[(size_t)(nt * 16 + (lane & 15)) * 256 + ks * 32 + (lane >> 4) * 8 + e];
}

// fp32 -> bf16 flat cast
__global__ __launch_bounds__(256) void cast_bf16_k(
    const float* __restrict__ src, unsigned short* __restrict__ dst, int count)
{
  int idx = blockIdx.x * 256 + threadIdx.x;
  if (idx < count) dst[idx] = f2bf(src[idx]);
}

// lwT bf16: lwTb[kcol*256 + n] = lw[n*256 + kcol]
__global__ __launch_bounds__(256) void prep_lwt_k(
    const float* __restrict__ lw, unsigned short* __restrict__ lwTb)
{
  int idx = blockIdx.x * 256 + threadIdx.x;   // 65536
  int n = idx & 255, kcol = idx >> 8;
  lwTb[idx] = f2bf(lw[(size_t)n * 256 + kcol]);
}

// beff[j] = sum_n Wih0[j,n]*lb[n] + bih0[j]
__global__ __launch_bounds__(256) void beff_k(
    const float* __restrict__ Wih, const float* __restrict__ lb,
    const float* __restrict__ bih, float* __restrict__ beff)
{
  int j = blockIdx.x * 256 + threadIdx.x;     // < 1024
  float s = bih[j];
  const float* row = Wih + (size_t)j * 256;
  for (int n = 0; n < 256; ++n) s = fmaf(row[n], lb[n], s);
  beff[j] = s;
}

// ---------------------------------------------------------------------------
// ec1: 1ch 64x64 s2 -> 32ch 32x32, NHWC bf16 out. 1024 images.
// ---------------------------------------------------------------------------
__global__ __launch_bounds__(256) void ec1_k(
    const float* __restrict__ x, const float* __restrict__ t,
    const float* __restrict__ w, const float* __restrict__ bias,
    unsigned short* __restrict__ out)
{
  __shared__ float sw[288];
  __shared__ float sb[32];
  for (int i = threadIdx.x; i < 288; i += 256) sw[i] = w[i];
  if (threadIdx.x < 32) sb[threadIdx.x] = bias[threadIdx.x];
  __syncthreads();
  int idx = blockIdx.x * 256 + threadIdx.x;     // < 1024*32*32
  int ox = idx & 31, oy = (idx >> 5) & 31, n = idx >> 10;
  int b = n >> 5, j = n & 31;
  const float* ip = (j < 16) ? (x + (size_t)(b * 16 + j) * 4096)
                             : (t + (size_t)(b * 16 + j - 16) * 4096);
  float pv[9];
#pragma unroll
  for (int kh = 0; kh < 3; ++kh) {
    int iy = oy * 2 + kh - 1;
#pragma unroll
    for (int kw = 0; kw < 3; ++kw) {
      int ix = ox * 2 + kw - 1;
      pv[kh * 3 + kw] = ((unsigned)iy < 64u && (unsigned)ix < 64u) ? ip[iy * 64 + ix] : 0.f;
    }
  }
  unsigned short u[32];
#pragma unroll
  for (int co = 0; co < 32; ++co) {
    float a = sb[co];
#pragma unroll
    for (int i = 0; i < 9; ++i) a = fmaf(pv[i], sw[co * 9 + i], a);
    u[co] = f2bf(gelu_f(a));
  }
  unsigned short* op = out + (size_t)idx * 32;
#pragma unroll
  for (int p = 0; p < 4; ++p) {
    uint4 v;
    v.x = u[p*8+0] | (u[p*8+1] << 16);
    v.y = u[p*8+2] | (u[p*8+3] << 16);
    v.z = u[p*8+4] | (u[p*8+5] << 16);
    v.w = u[p*8+6] | (u[p*8+7] << 16);
    *(uint4*)&op[p * 8] = v;
  }
}

// ---------------------------------------------------------------------------
// MFMA implicit-GEMM conv. NHWC bf16 in/out. MODE: 0=s1, 1=s2, 2=tconv(ups2).
// ---------------------------------------------------------------------------
template<int CIN, int COUT, int HIN, int WIN, int TH, int TW, int MODE>
__global__ __launch_bounds__(256) void convmf_k(
    const unsigned short* __restrict__ in, const unsigned short* __restrict__ wb,
    const float* __restrict__ bias, unsigned short* __restrict__ out)
{
  constexpr int HO  = (MODE == 1) ? HIN / 2 : (MODE == 2 ? HIN * 2 : HIN);
  constexpr int WO  = (MODE == 1) ? WIN / 2 : (MODE == 2 ? WIN * 2 : WIN);
  constexpr int TIH = (MODE == 1) ? 2 * TH + 1 : TH + 2;
  constexpr int TIW = (MODE == 1) ? 2 * TW + 1 : TW + 2;
  constexpr int CG  = CIN / 8;
  constexpr int K   = 9 * CIN;
  constexpr int KS  = K / 32;
  constexpr int NT  = COUT / 16;
  constexpr int MT  = (TH * TW) / 16;
  constexpr int MPW = MT / 4;
  constexpr int TY  = HO / TH, TX = WO / TW;

  __shared__ unsigned short lds[TIH * TIW * CG * 8];

  const int bid = blockIdx.x;
  const int n = bid / (TY * TX);
  const int trem = bid % (TY * TX);
  const int ty0 = (trem / TX) * TH, tx0 = (trem % TX) * TW;

  constexpr int ENT = TIH * TIW * CG;
  for (int e = threadIdx.x; e < ENT; e += 256) {
    int txx = e % TIW;
    int rr  = e / TIW;
    int cg  = rr % CG;
    int tyy = rr / CG;
    int iy, ix; bool ok;
    if (MODE == 0) {
      iy = ty0 + tyy - 1; ix = tx0 + txx - 1;
      ok = (unsigned)iy < (unsigned)HIN && (unsigned)ix < (unsigned)WIN;
    } else if (MODE == 1) {
      iy = 2 * ty0 + tyy - 1; ix = 2 * tx0 + txx - 1;
      ok = (unsigned)iy < (unsigned)HIN && (unsigned)ix < (unsigned)WIN;
    } else {
      int vy = ty0 + tyy - 1, vx = tx0 + txx - 1;
      ok = vy >= 0 && vx >= 0 && !(vy & 1) && !(vx & 1);
      iy = vy >> 1; ix = vx >> 1;
      ok = ok && iy < HIN && ix < WIN;
    }
    int4 val = {0, 0, 0, 0};
    if (ok) val = *(const int4*)&in[(((size_t)n * HIN + iy) * WIN + ix) * CIN + cg * 8];
    *(int4*)&lds[(size_t)e * 8] = val;
  }
  __syncthreads();

  const int lane = threadIdx.x & 63, wv = threadIdx.x >> 6;
  const int l15 = lane & 15, l4 = lane >> 4;

  f4_t acc[MPW][NT] = {};
  for (int ks = 0; ks < KS; ++ks) {
    const int tap = (ks * 32) / CIN;
    const int kh = tap / 3, kw = tap % 3;
    const int cb = ((ks * 32) % CIN) / 8 + l4;
    bf8_t bf[NT];
#pragma unroll
    for (int nt = 0; nt < NT; ++nt)
      bf[nt] = *(const bf8_t*)&wb[(size_t)(nt * 16 + l15) * K + ks * 32 + 8 * l4];
#pragma unroll
    for (int mi = 0; mi < MPW; ++mi) {
      int m = (wv * MPW + mi) * 16 + l15;
      int oy = m / TW, ox = m % TW;
      int rt = ((MODE == 1) ? 2 * oy : oy) + kh;
      int ct = ((MODE == 1) ? 2 * ox : ox) + kw;
      bf8_t a = *(const bf8_t*)&lds[(((size_t)rt * CG + cb) * TIW + ct) * 8];
#pragma unroll
      for (int nt = 0; nt < NT; ++nt)
        acc[mi][nt] = __builtin_amdgcn_mfma_f32_16x16x32_bf16(a, bf[nt], acc[mi][nt], 0, 0, 0);
    }
  }

#pragma unroll
  for (int mi = 0; mi < MPW; ++mi) {
    int mbase = (wv * MPW + mi) * 16;
#pragma unroll
    for (int nt = 0; nt < NT; ++nt) {
      int co = nt * 16 + l15;
      float bv = bias[co];
#pragma unroll
      for (int r = 0; r < 4; ++r) {
        int m = mbase + l4 * 4 + r;
        int oy = m / TW, ox = m % TW;
        float v = acc[mi][nt][r] + bv;
        out[(((size_t)n * HO + ty0 + oy) * WO + (tx0 + ox)) * COUT + co] = f2bf(gelu_f(v));
      }
    }
  }
}

// ---------------------------------------------------------------------------
// MFMA GEMM: C[m][n] = act(sum_k A[m][k]*B[n][k] + bias).
// BIASMODE: 0 = bias[col], 1 = dl-permuted bias, 2 = no bias.
// ---------------------------------------------------------------------------
template<int BIASMODE, bool GELU, bool OUTBF16>
__global__ __launch_bounds__(256) void gemm16_k(
    const unsigned short* __restrict__ A, const unsigned short* __restrict__ Bw,
    const float* __restrict__ bias, void* __restrict__ Cv, int M, int N, int K)
{
  const int lane = threadIdx.x & 63, wv = threadIdx.x >> 6;
  const int l15 = lane & 15, l4 = lane >> 4;
  const int mbase = blockIdx.y * 64 + wv * 16;
  const int nbase = blockIdx.x * 64;
  f4_t acc[4] = {};
  for (int k0 = 0; k0 < K; k0 += 32) {
    bf8_t a = *(const bf8_t*)&A[(size_t)(mbase + l15) * K + k0 + 8 * l4];
#pragma unroll
    for (int nt = 0; nt < 4; ++nt) {
      bf8_t b = *(const bf8_t*)&Bw[(size_t)(nbase + nt * 16 + l15) * K + k0 + 8 * l4];
      acc[nt] = __builtin_amdgcn_mfma_f32_16x16x32_bf16(a, b, acc[nt], 0, 0, 0);
    }
  }
#pragma unroll
  for (int nt = 0; nt < 4; ++nt) {
    int col = nbase + nt * 16 + l15;
    float bv = 0.f;
    if (BIASMODE == 0) bv = bias[col];
    if (BIASMODE == 1) bv = bias[(col & 63) * 64 + (col >> 6)];
#pragma unroll
    for (int r = 0; r < 4; ++r) {
      int row = mbase + l4 * 4 + r;
      float v = acc[nt][r] + bv;
      if (GELU) v = gelu_f(v);
      if (OUTBF16) ((unsigned short*)Cv)[(size_t)row * N + col] = f2bf(v);
      else         ((float*)Cv)[(size_t)row * N + col] = v;
    }
  }
}

// ---------------------------------------------------------------------------
// dt3 (tconv 32->1) + tanh + fused loss partials. bf16 NHWC in. 1024 images.
// ---------------------------------------------------------------------------
__global__ __launch_bounds__(256) void dt3_loss_k(
    const unsigned short* __restrict__ in,
    const float* __restrict__ w, const float* __restrict__ bias,
    const float* __restrict__ xref, const float* __restrict__ tref,
    float* __restrict__ fout, float* __restrict__ partials)
{
  __shared__ float sw[288];
  for (int i = threadIdx.x; i < 288; i += 256) sw[i] = w[i];
  __syncthreads();
  int idx = blockIdx.x * 256 + threadIdx.x;
  int q = idx & 63, p = (idx >> 6) & 63, n = idx >> 12;
  float acc = bias[0];
#pragma unroll
  for (int kh = 0; kh < 3; ++kh) {
    int u = p + kh - 1;
    if (u < 0 || (u & 1) || u >= 64) continue;
#pragma unroll
    for (int kw = 0; kw < 3; ++kw) {
      int v = q + kw - 1;
      if (v < 0 || (v & 1) || v >= 64) continue;
      const unsigned short* row = in + (((size_t)n * 32 + (u >> 1)) * 32 + (v >> 1)) * 32;
      int wo = (2 - kh) * 3 + (2 - kw);
#pragma unroll
      for (int w2 = 0; w2 < 16; ++w2) {
        unsigned dv = *(const unsigned*)&row[w2 * 2];
        acc = fmaf(__uint_as_float(dv << 16),        sw[(2 * w2) * 9 + wo], acc);
        acc = fmaf(__uint_as_float(dv & 0xffff0000u), sw[(2 * w2 + 1) * 9 + wo], acc);
      }
    }
  }
  float val = tanhf(acc);
  float d;
  int pix = p * 64 + q;
  if (n < 512) {
    fout[(size_t)n * 4096 + pix] = val;
    d = val - tref[(size_t)n * 4096 + pix];
  } else {
    d = val - xref[(size_t)(n - 512) * 4096 + pix];
  }
  __shared__ float red[256];
  red[threadIdx.x] = d * d;
  __syncthreads();
#pragma unroll
  for (int s = 128; s > 0; s >>= 1) {
    if (threadIdx.x < s) red[threadIdx.x] += red[threadIdx.x + s];
    __syncthreads();
  }
  if (threadIdx.x == 0) partials[blockIdx.x] = red[0];
}

__global__ __launch_bounds__(256) void loss_final_k(
    const float* __restrict__ partials, float* __restrict__ out01)
{
  __shared__ float red[256];
  int base = blockIdx.x * 8192;
  float s = 0.f;
  for (int i = threadIdx.x; i < 8192; i += 256) s += partials[base + i];
  red[threadIdx.x] = s;
  __syncthreads();
#pragma unroll
  for (int st = 128; st > 0; st >>= 1) {
    if (threadIdx.x < st) red[threadIdx.x] += red[threadIdx.x + st];
    __syncthreads();
  }
  if (threadIdx.x == 0) out01[blockIdx.x] = red[0] * (1.0f / 2097152.0f);
}

// ---------------------------------------------------------------------------
// LSTM v6: 160 blocks = (layer l, colgroup jg). Wave = gate. Weights for the
// block's layer live in LDS (64 KB, staged once -> immune to barrier cache
// invalidation). x/h staged to LDS per cell with XOR swizzle (conflict-free
// frag reads). Phase 1 = diagonal wavefront, each layer's blocks do <=1 cell
// per step (true parallelism). Phase 2 = serial, Meff folded into l=0 (LDS
// region hot-swapped at the phase boundary). 176 grid barriers total.
// ---------------------------------------------------------------------------
#define LSTM_NB 160

DEV void gridbar(unsigned* bar, unsigned target) {
  __syncthreads();
  if (threadIdx.x == 0) {
    __hip_atomic_fetch_add(bar, 1u, __ATOMIC_RELEASE, __HIP_MEMORY_SCOPE_AGENT);
    unsigned spins = 0;
    while (__hip_atomic_load(bar, __ATOMIC_RELAXED, __HIP_MEMORY_SCOPE_AGENT) < target) {
      __builtin_amdgcn_s_sleep(2);
      if (++spins > (1u << 24)) break;   // safety valve
    }
    (void)__hip_atomic_load(bar, __ATOMIC_ACQUIRE, __HIP_MEMORY_SCOPE_AGENT);
  }
  __syncthreads();
}

__global__ __launch_bounds__(256, 1) void lstm6_k(
    const float* __restrict__ z,              // (1024,256) fp32, row = b*32+t
    const unsigned short* __restrict__ wihb,  // frag-swizzled bf16 (10 layers)
    const unsigned short* __restrict__ whhb,
    const unsigned short* __restrict__ meffb, // frag-swizzled Meff (1 layer)
    const float* __restrict__ bih, const float* __restrict__ bhh,
    const float* __restrict__ beff,
    unsigned short* __restrict__ zbf,     // (16,32,256) bf16 [t][b][k]
    unsigned short* __restrict__ hbf,     // (2,10,32,256) bf16
    unsigned short* __restrict__ h9sav,   // (16,32,256) bf16, slot tt=t-15
    unsigned* __restrict__ bar)
{
  __shared__ unsigned short s_w[4 * 2 * 4096]; // 64KB [g][wi/wh][frag 4096]
  __shared__ unsigned short s_x[8192];         // 16KB swizzled [32 rows][32 ch]
  __shared__ unsigned short s_h[8192];         // 16KB
  __shared__ float zsm[4 * 32 * 17];           // 8.7KB [gate][row][col pad17]
  __shared__ float cls[32 * 16];               // c state for this layer
  __shared__ float sbias[64];                  // bih+bhh for this layer [g][j]
  __shared__ float sb2[64];                    // beff+bhh0 [g][j]

  const int tid = threadIdx.x;
  const int bid = blockIdx.x;
  const int l   = bid >> 4;                    // layer 0..9
  const int jg  = bid & 15;
  const int col0 = jg * 16;
  const int lane = tid & 63, g = tid >> 6;     // wave = gate
  const int l15 = lane & 15, l4 = lane >> 4;
  const int gtid = bid * 256 + tid;

  // ---- init: zbf transpose+bf16, zero hbf parity 1 ----
  for (int i = gtid; i < 16 * 32 * 256; i += LSTM_NB * 256) {
    int k = i & 255, r = i >> 8;
    int tt = r >> 5, b = r & 31;
    zbf[i] = f2bf(z[(size_t)(b * 32 + tt) * 256 + k]);
  }
  for (int i = gtid; i < 81920; i += LSTM_NB * 256) hbf[81920 + i] = 0;
  // ---- stage this layer's weights into LDS (4096 chunks of 16B) ----
  for (int c = tid; c < 4096; c += 256) {
    int gm = c >> 9;                 // g*2 + m
    int gg = gm >> 1, m = gm & 1;
    int c2 = c & 511;
    const unsigned short* src = (m == 0 ? wihb : whhb)
        + ((size_t)(l * 64 + gg * 16 + jg) * 8) * 512;
    *(int4*)&s_w[(size_t)c * 8] = *(const int4*)&src[(size_t)c2 * 8];
  }
  for (int i = tid; i < 512; i += 256) cls[i] = 0.f;
  if (tid < 64) {
    int gg = tid >> 4, j = tid & 15;
    sbias[tid] = bih[l * 1024 + gg * 256 + col0 + j]
               + bhh[l * 1024 + gg * 256 + col0 + j];
    sb2[tid]   = beff[gg * 256 + col0 + j] + bhh[gg * 256 + col0 + j];
  }

  unsigned ep = 0;
  ++ep; gridbar(bar, ep * LSTM_NB);

  auto cell = [&](int t, bool p2) {
    const int cur = t & 1, prv = cur ^ 1;
    const bool p2l0 = p2 && (l == 0);
    const unsigned short* xb =
        (l == 0) ? (p2 ? (hbf + (size_t)((prv * 10 + 9) * 32) * 256)
                       : (zbf + (size_t)t * 32 * 256))
                 : (hbf + (size_t)((cur * 10 + l - 1) * 32) * 256);
    const unsigned short* hb = hbf + (size_t)((prv * 10 + l) * 32) * 256;
    // ---- stage x,h -> LDS (XOR-swizzled), 4+4 parallel 16B loads/thread ----
#pragma unroll
    for (int i = 0; i < 4; ++i) {
      int c = tid + i * 256;                     // chunk 0..1023
      int sw = (c & ~31) | ((c & 31) ^ ((c >> 5) & 7));
      *(int4*)&s_x[(size_t)sw * 8] = *(const int4*)&xb[(size_t)c * 8];
      *(int4*)&s_h[(size_t)sw * 8] = *(const int4*)&hb[(size_t)c * 8];
    }
    __syncthreads();
    // ---- MFMA: 4 chains of 8, frags from LDS ----
    f4_t a0 = {}, a1 = {}, b0 = {}, b1 = {};
#pragma unroll
    for (int ks = 0; ks < 8; ++ks) {
      bf8_t bwi = *(const bf8_t*)&s_w[(size_t)((g * 2 + 0) * 4096 + ks * 512 + lane * 8)];
      bf8_t bwh = *(const bf8_t*)&s_w[(size_t)((g * 2 + 1) * 4096 + ks * 512 + lane * 8)];
      int cx0 = (l15 << 5) | ((ks * 4 + l4) ^ (l15 & 7));
      int cx1 = ((16 + l15) << 5) | ((ks * 4 + l4) ^ (l15 & 7));
      bf8_t ax0 = *(const bf8_t*)&s_x[(size_t)cx0 * 8];
      bf8_t ax1 = *(const bf8_t*)&s_x[(size_t)cx1 * 8];
      bf8_t ah0 = *(const bf8_t*)&s_h[(size_t)cx0 * 8];
      bf8_t ah1 = *(const bf8_t*)&s_h[(size_t)cx1 * 8];
      a0 = __builtin_amdgcn_mfma_f32_16x16x32_bf16(ax0, bwi, a0, 0, 0, 0);
      a1 = __builtin_amdgcn_mfma_f32_16x16x32_bf16(ax1, bwi, a1, 0, 0, 0);
      b0 = __builtin_amdgcn_mfma_f32_16x16x32_bf16(ah0, bwh, b0, 0, 0, 0);
      b1 = __builtin_amdgcn_mfma_f32_16x16x32_bf16(ah1, bwh, b1, 0, 0, 0);
    }
#pragma unroll
    for (int r = 0; r < 4; ++r) {
      zsm[(g * 32 + l4 * 4 + r) * 17 + l15] = a0[r] + b0[r];
      zsm[(g * 32 + 16 + l4 * 4 + r) * 17 + l15] = a1[r] + b1[r];
    }
    __syncthreads();
    // ---- gate math: 512 elems, 2/thread ----
#pragma unroll
    for (int half = 0; half < 2; ++half) {
      int e = tid + half * 256;
      int b = e >> 4, j = e & 15;
      float zi = zsm[(0 * 32 + b) * 17 + j] + (p2l0 ? sb2[j]      : sbias[j]);
      float zf = zsm[(1 * 32 + b) * 17 + j] + (p2l0 ? sb2[16 + j] : sbias[16 + j]);
      float zg = zsm[(2 * 32 + b) * 17 + j] + (p2l0 ? sb2[32 + j] : sbias[32 + j]);
      float zo = zsm[(3 * 32 + b) * 17 + j] + (p2l0 ? sb2[48 + j] : sbias[48 + j]);
      float cold = cls[b * 16 + j];
      float cn = sigm_f(zf) * cold + sigm_f(zi) * tanhf(zg);
      cls[b * 16 + j] = cn;
      float hn = sigm_f(zo) * tanhf(cn);
      unsigned short hv = f2bf(hn);
      hbf[(size_t)((cur * 10 + l) * 32 + b) * 256 + col0 + j] = hv;
      if (l == 9 && t >= 15) h9sav[(size_t)((t - 15) * 32 + b) * 256 + col0 + j] = hv;
    }
    __syncthreads();
  };

  // ---- phase 1: diagonal wavefront, each block <=1 cell per step ----
  for (int d = 0; d <= 24; ++d) {
    int t = d - l;
    if (t >= 0 && t <= 15) cell(t, false);
    ++ep; gridbar(bar, ep * LSTM_NB);
  }
  // ---- l=0 blocks: hot-swap wi LDS region -> Meff (block-local) ----
  if (l == 0) {
    for (int c = tid; c < 2048; c += 256) {
      int gg = c >> 9, c2 = c & 511;
      const unsigned short* src = meffb + ((size_t)(gg * 16 + jg) * 8) * 512;
      *(int4*)&s_w[(size_t)((gg * 2) * 512 + c2) * 8] = *(const int4*)&src[(size_t)c2 * 8];
    }
    __syncthreads();
  }
  // ---- phase 2: serial t=16..30 (out(30) needed by y_t slice) ----
  for (int t = 16; t <= 30; ++t) {
    for (int ll = 0; ll < 10; ++ll) {
      if (ll == l) cell(t, true);
      ++ep; gridbar(bar, ep * LSTM_NB);
    }
  }
}

// ---------------------------------------------------------------------------
// Decoder input gather -> bf16: rows 0..511 = y_t, rows 512..1023 = z_x
// ---------------------------------------------------------------------------
__global__ __launch_bounds__(256) void gather_dec_k(
    const float* __restrict__ outs, const float* __restrict__ z,
    unsigned short* __restrict__ ydec)
{
  int idx = blockIdx.x * 256 + threadIdx.x;   // < 262144
  int rrow = idx >> 8, k = idx & 255;
  float v;
  if (rrow < 512) {
    int b = rrow >> 4, i = rrow & 15;
    v = outs[(size_t)((15 + i) * 32 + b) * 256 + k];
  } else {
    int rr = rrow - 512;
    int b = rr >> 4, tt = rr & 15;
    v = z[(size_t)(b * 32 + tt) * 256 + k];
  }
  ydec[idx] = f2bf(v);
}

// ---------------------------------------------------------------------------
extern "C" void kernel_launch(void* const* d_in, const int* in_sizes, int n_in,
                              void* d_out, int out_size, void* d_ws, size_t ws_size,
                              hipStream_t stream) {
  const float* x     = (const float*)d_in[0];
  const float* t     = (const float*)d_in[1];
  const float* ec1_w = (const float*)d_in[2];
  const float* ec1_b = (const float*)d_in[3];
  const float* ec2_w = (const float*)d_in[4];
  const float* ec2_b = (const float*)d_in[5];
  const float* ec3_w = (const float*)d_in[6];
  const float* ec3_b = (const float*)d_in[7];
  const float* ec4_w = (const float*)d_in[8];
  const float* ec4_b = (const float*)d_in[9];
  const float* ec5_w = (const float*)d_in[10];
  const float* ec5_b = (const float*)d_in[11];
  const float* el_w  = (const float*)d_in[12];
  const float* el_b  = (const float*)d_in[13];
  const float* dl_w  = (const float*)d_in[14];
  const float* dl_b  = (const float*)d_in[15];
  const float* dt1_w = (const float*)d_in[16];
  const float* dt1_b = (const float*)d_in[17];
  const float* dc1_w = (const float*)d_in[18];
  const float* dc1_b = (const float*)d_in[19];
  const float* dt2_w = (const float*)d_in[20];
  const float* dt2_b = (const float*)d_in[21];
  const float* dc2_w = (const float*)d_in[22];
  const float* dc2_b = (const float*)d_in[23];
  const float* dt3_w = (const float*)d_in[24];
  const float* dt3_b = (const float*)d_in[25];
  const float* Wih   = (const float*)d_in[26];
  const float* Whh   = (const float*)d_in[27];
  const float* bih   = (const float*)d_in[28];
  const float* bhh   = (const float*)d_in[29];
  const float* lw    = (const float*)d_in[30];
  const float* lb    = (const float*)d_in[31];
  float* out = (float*)d_out;

  char* base = (char*)d_ws;
  size_t off = 0;
  auto alloc = [&](size_t bytes) -> char* {
    char* p = base + off;
    off += (bytes + 255) & ~(size_t)255;
    return p;
  };
  typedef unsigned short us;
  unsigned* bar   = (unsigned*)alloc(256);
  float* zbuf     = (float*)alloc((size_t)1024 * 256 * 4);
  float* outsbuf  = (float*)alloc((size_t)31 * 32 * 256 * 4);
  us*    zbf      = (us*)alloc((size_t)16 * 32 * 256 * 2);
  us*    hbf      = (us*)alloc((size_t)2 * 10 * 32 * 256 * 2);
  us*    h9sav    = (us*)alloc((size_t)16 * 32 * 256 * 2);
  us*    ydec     = (us*)alloc((size_t)1024 * 256 * 2);
  float* partials = (float*)alloc((size_t)16384 * 4);
  us* wb_ec2 = (us*)alloc((size_t)32 * 288 * 2);
  us* wb_ec3 = (us*)alloc((size_t)64 * 288 * 2);
  us* wb_ec4 = (us*)alloc((size_t)64 * 576 * 2);
  us* wb_ec5 = (us*)alloc((size_t)64 * 576 * 2);
  us* wb_dt1 = (us*)alloc((size_t)64 * 576 * 2);
  us* wb_dc1 = (us*)alloc((size_t)64 * 576 * 2);
  us* wb_dt2 = (us*)alloc((size_t)32 * 576 * 2);
  us* wb_dc2 = (us*)alloc((size_t)32 * 288 * 2);
  us* elWb   = (us*)alloc((size_t)256 * 4096 * 2);
  us* dlWb   = (us*)alloc((size_t)4096 * 256 * 2);
  us* wihb   = (us*)alloc((size_t)10 * 1024 * 256 * 2);      // 5 MB
  us* whhb   = (us*)alloc((size_t)10 * 1024 * 256 * 2);      // 5 MB
  us* wih0b  = (us*)alloc((size_t)1024 * 256 * 2);
  us* lwTb   = (us*)alloc((size_t)256 * 256 * 2);
  us* lwbp   = (us*)alloc((size_t)256 * 256 * 2);
  us* meffp  = (us*)alloc((size_t)1024 * 256 * 2);
  us* meffb  = (us*)alloc((size_t)1024 * 256 * 2);
  float* beff = (float*)alloc((size_t)1024 * 4);
  us* enc5   = (us*)alloc((size_t)1024 * 4096 * 2);          // 8.4 MB
  us* bufA   = (us*)alloc((size_t)1024 * 32 * 32 * 32 * 2);  // 67 MB
  us* bufB   = (us*)alloc((size_t)1024 * 32 * 32 * 32 * 2);  // 67 MB
  (void)in_sizes; (void)n_in; (void)out_size; (void)ws_size;

  hipMemsetAsync(bar, 0, 16, stream);

  // ---- weight prep ----
  prepw_k<<<(32*32*9+255)/256, 256, 0, stream>>>(ec2_w, wb_ec2, 32, 32, 0);
  prepw_k<<<(64*32*9+255)/256, 256, 0, stream>>>(ec3_w, wb_ec3, 64, 32, 0);
  prepw_k<<<(64*64*9+255)/256, 256, 0, stream>>>(ec4_w, wb_ec4, 64, 64, 0);
  prepw_k<<<(64*64*9+255)/256, 256, 0, stream>>>(ec5_w, wb_ec5, 64, 64, 0);
  prepw_k<<<(64*64*9+255)/256, 256, 0, stream>>>(dt1_w, wb_dt1, 64, 64, 1);
  prepw_k<<<(64*64*9+255)/256, 256, 0, stream>>>(dc1_w, wb_dc1, 64, 64, 0);
  prepw_k<<<(32*64*9+255)/256, 256, 0, stream>>>(dt2_w, wb_dt2, 32, 64, 1);
  prepw_k<<<(32*32*9+255)/256, 256, 0, stream>>>(dc2_w, wb_dc2, 32, 32, 0);
  prep_el_k<<<4096, 256, 0, stream>>>(el_w, elWb);
  prep_dl_k<<<4096, 256, 0, stream>>>(dl_w, dlWb);
  prep_wlstm_k<<<10240, 256, 0, stream>>>(Wih, wihb);
  prep_wlstm_k<<<10240, 256, 0, stream>>>(Whh, whhb);
  // Meff = Wih0 @ lw (1024x256), beff = Wih0 @ lb + bih0
  cast_bf16_k<<<1024, 256, 0, stream>>>(Wih, wih0b, 262144);
  prep_lwt_k<<<256, 256, 0, stream>>>(lw, lwTb);
  cast_bf16_k<<<256, 256, 0, stream>>>(lw, lwbp, 65536);
  gemm16_k<2, false, true><<<dim3(4, 16), 256, 0, stream>>>(wih0b, lwTb, lb, meffp, 1024, 256, 256);
  prep_wl1_k<<<1024, 256, 0, stream>>>(meffp, meffb);
  beff_k<<<4, 256, 0, stream>>>(Wih, lb, bih, beff);

  // ---- encoder: single 1024-image pass ----
  ec1_k<<<4096, 256, 0, stream>>>(x, t, ec1_w, ec1_b, bufA);
  convmf_k<32, 32, 32, 32, 32, 32, 0><<<1024, 256, 0, stream>>>(bufA, wb_ec2, ec2_b, bufB);
  convmf_k<32, 64, 32, 32, 16, 16, 1><<<1024, 256, 0, stream>>>(bufB, wb_ec3, ec3_b, bufA);
  convmf_k<64, 64, 16, 16, 16, 16, 0><<<1024, 256, 0, stream>>>(bufA, wb_ec4, ec4_b, bufB);
  convmf_k<64, 64, 16, 16, 8, 8, 1><<<1024, 256, 0, stream>>>(bufB, wb_ec5, ec5_b, enc5);
  gemm16_k<0, false, false><<<dim3(4, 16), 256, 0, stream>>>(enc5, elWb, el_b, zbuf, 1024, 256, 4096);

  // ---- LSTM (MFMA, 160 blocks (layer,colgroup), LDS-resident weights) ----
  lstm6_k<<<LSTM_NB, 256, 0, stream>>>(zbuf, wihb, whhb, meffb, bih, bhh, beff,
                                       zbf, hbf, h9sav, bar);
  // outs[t=15..30] = h9sav @ lw^T + lb
  gemm16_k<0, false, false><<<dim3(4, 8), 256, 0, stream>>>(
      h9sav, lwbp, lb, outsbuf + (size_t)15 * 32 * 256, 512, 256, 256);

  // ---- decoder: single 1024-row pass (rows 0..511 pred, 512..1023 rec) ----
  gather_dec_k<<<1024, 256, 0, stream>>>(outsbuf, zbuf, ydec);
  gemm16_k<1, true, true><<<dim3(64, 16), 256, 0, stream>>>(ydec, dlWb, dl_b, bufB, 1024, 4096, 256);
  convmf_k<64, 64, 8, 8, 16, 16, 2><<<1024, 256, 0, stream>>>(bufB, wb_dt1, dt1_b, bufA);
  convmf_k<64, 64, 16, 16, 16, 16, 0><<<1024, 256, 0, stream>>>(bufA, wb_dc1, dc1_b, bufB);
  convmf_k<64, 32, 16, 16, 16, 32, 2><<<2048, 256, 0, stream>>>(bufB, wb_dt2, dt2_b, bufA);
  convmf_k<32, 32, 32, 32, 32, 32, 0><<<1024, 256, 0, stream>>>(bufA, wb_dc2, dc2_b, bufB);
  dt3_loss_k<<<16384, 256, 0, stream>>>(bufB, dt3_w, dt3_b, x, t, out + 2, partials);
  loss_final_k<<<2, 256, 0, stream>>>(partials, out);
}

// Round 8
// 1851.077 us; speedup vs baseline: 1.5267x; 1.2612x over previous
//
#include <hip/hip_runtime.h>
#include <math.h>

#define DEV __device__ __forceinline__

typedef __attribute__((ext_vector_type(8))) short bf8_t;   // 8 x bf16 (4 VGPR)
typedef __attribute__((ext_vector_type(4))) float f4_t;    // MFMA acc

DEV float gelu_f(float v) { return 0.5f * v * (1.0f + erff(v * 0.70710678118654752f)); }
DEV float sigm_f(float v) { return 1.0f / (1.0f + expf(-v)); }
DEV unsigned short f2bf(float f) {            // RNE float->bf16
  unsigned u = __float_as_uint(f);
  u = (u + 0x7FFFu + ((u >> 16) & 1u)) >> 16;
  return (unsigned short)u;
}
DEV float bf2f(unsigned short u) { return __uint_as_float((unsigned)u << 16); }

// ---------------------------------------------------------------------------
// Weight prep: conv weights -> bf16 [co][kh][kw][ci]; FLIP=1 for tconv
// ---------------------------------------------------------------------------
__global__ __launch_bounds__(256) void prepw_k(
    const float* __restrict__ w, unsigned short* __restrict__ wb,
    int COUT, int CIN, int FLIP)
{
  int idx = blockIdx.x * 256 + threadIdx.x;
  int total = COUT * CIN * 9;
  if (idx >= total) return;
  int ci = idx % CIN;
  int r  = idx / CIN;
  int kw = r % 3; r /= 3;
  int kh = r % 3;
  int co = r / 3;
  float v = FLIP ? w[((ci * COUT + co) * 3 + (2 - kh)) * 3 + (2 - kw)]
                 : w[((co * CIN + ci) * 3 + kh) * 3 + kw];
  wb[idx] = f2bf(v);
}

// el_w (256,4096 k_ref=c*64+s) -> bf16 [n][k_new=(s*64+c)]
__global__ __launch_bounds__(256) void prep_el_k(
    const float* __restrict__ w, unsigned short* __restrict__ wb)
{
  int idx = blockIdx.x * 256 + threadIdx.x;     // < 256*4096
  int kn = idx & 4095, n = idx >> 12;
  wb[idx] = f2bf(w[(size_t)n * 4096 + ((kn & 63) * 64 + (kn >> 6))]);
}

// dl_w (4096,256) row r=c*64+s -> bf16 rows nout=s*64+c
__global__ __launch_bounds__(256) void prep_dl_k(
    const float* __restrict__ w, unsigned short* __restrict__ wb)
{
  int idx = blockIdx.x * 256 + threadIdx.x;     // < 4096*256
  int k = idx & 255, nout = idx >> 8;
  wb[idx] = f2bf(w[(size_t)((nout & 63) * 64 + (nout >> 6)) * 256 + k]);
}

// LSTM weights (10,1024,256) -> bf16 frag-contiguous:
// wb[((l*64+nt)*8+ks)*512 + lane*8 + e] = W[l][nt*16+(lane&15)][ks*32+(lane>>4)*8+e]
__global__ __launch_bounds__(256) void prep_wlstm_k(
    const float* __restrict__ w, unsigned short* __restrict__ wb)
{
  int idx = blockIdx.x * 256 + threadIdx.x;   // exactly 2621440 = 10240 blocks
  int e = idx & 7, lane = (idx >> 3) & 63, ks = (idx >> 9) & 7;
  int nt = (idx >> 12) & 63, l = idx >> 18;
  wb[idx] = f2bf(w[((size_t)l * 1024 + nt * 16 + (lane & 15)) * 256
                   + ks * 32 + (lane >> 4) * 8 + e]);
}

// single-layer (1024x256) bf16 [j][k] -> frag layout (as prep_wlstm, l=0)
__global__ __launch_bounds__(256) void prep_wl1_k(
    const unsigned short* __restrict__ src, unsigned short* __restrict__ wb)
{
  int idx = blockIdx.x * 256 + threadIdx.x;   // 262144 = 1024 blocks
  int e = idx & 7, lane = (idx >> 3) & 63, ks = (idx >> 9) & 7, nt = idx >> 12;
  wb[idx] = src[(size_t)(nt * 16 + (lane & 15)) * 256 + ks * 32 + (lane >> 4) * 8 + e];
}

// fp32 -> bf16 flat cast
__global__ __launch_bounds__(256) void cast_bf16_k(
    const float* __restrict__ src, unsigned short* __restrict__ dst, int count)
{
  int idx = blockIdx.x * 256 + threadIdx.x;
  if (idx < count) dst[idx] = f2bf(src[idx]);
}

// lwT bf16: lwTb[kcol*256 + n] = lw[n*256 + kcol]
__global__ __launch_bounds__(256) void prep_lwt_k(
    const float* __restrict__ lw, unsigned short* __restrict__ lwTb)
{
  int idx = blockIdx.x * 256 + threadIdx.x;   // 65536
  int n = idx & 255, kcol = idx >> 8;
  lwTb[idx] = f2bf(lw[(size_t)n * 256 + kcol]);
}

// beff[j] = sum_n Wih0[j,n]*lb[n] + bih0[j]
__global__ __launch_bounds__(256) void beff_k(
    const float* __restrict__ Wih, const float* __restrict__ lb,
    const float* __restrict__ bih, float* __restrict__ beff)
{
  int j = blockIdx.x * 256 + threadIdx.x;     // < 1024
  float s = bih[j];
  const float* row = Wih + (size_t)j * 256;
  for (int n = 0; n < 256; ++n) s = fmaf(row[n], lb[n], s);
  beff[j] = s;
}

// ---------------------------------------------------------------------------
// ec1: 1ch 64x64 s2 -> 32ch 32x32, NHWC bf16 out. 1024 images.
// ---------------------------------------------------------------------------
__global__ __launch_bounds__(256) void ec1_k(
    const float* __restrict__ x, const float* __restrict__ t,
    const float* __restrict__ w, const float* __restrict__ bias,
    unsigned short* __restrict__ out)
{
  __shared__ float sw[288];
  __shared__ float sb[32];
  for (int i = threadIdx.x; i < 288; i += 256) sw[i] = w[i];
  if (threadIdx.x < 32) sb[threadIdx.x] = bias[threadIdx.x];
  __syncthreads();
  int idx = blockIdx.x * 256 + threadIdx.x;     // < 1024*32*32
  int ox = idx & 31, oy = (idx >> 5) & 31, n = idx >> 10;
  int b = n >> 5, j = n & 31;
  const float* ip = (j < 16) ? (x + (size_t)(b * 16 + j) * 4096)
                             : (t + (size_t)(b * 16 + j - 16) * 4096);
  float pv[9];
#pragma unroll
  for (int kh = 0; kh < 3; ++kh) {
    int iy = oy * 2 + kh - 1;
#pragma unroll
    for (int kw = 0; kw < 3; ++kw) {
      int ix = ox * 2 + kw - 1;
      pv[kh * 3 + kw] = ((unsigned)iy < 64u && (unsigned)ix < 64u) ? ip[iy * 64 + ix] : 0.f;
    }
  }
  unsigned short u[32];
#pragma unroll
  for (int co = 0; co < 32; ++co) {
    float a = sb[co];
#pragma unroll
    for (int i = 0; i < 9; ++i) a = fmaf(pv[i], sw[co * 9 + i], a);
    u[co] = f2bf(gelu_f(a));
  }
  unsigned short* op = out + (size_t)idx * 32;
#pragma unroll
  for (int p = 0; p < 4; ++p) {
    uint4 v;
    v.x = u[p*8+0] | (u[p*8+1] << 16);
    v.y = u[p*8+2] | (u[p*8+3] << 16);
    v.z = u[p*8+4] | (u[p*8+5] << 16);
    v.w = u[p*8+6] | (u[p*8+7] << 16);
    *(uint4*)&op[p * 8] = v;
  }
}

// ---------------------------------------------------------------------------
// MFMA implicit-GEMM conv. NHWC bf16 in/out. MODE: 0=s1, 1=s2, 2=tconv(ups2).
// ---------------------------------------------------------------------------
template<int CIN, int COUT, int HIN, int WIN, int TH, int TW, int MODE>
__global__ __launch_bounds__(256) void convmf_k(
    const unsigned short* __restrict__ in, const unsigned short* __restrict__ wb,
    const float* __restrict__ bias, unsigned short* __restrict__ out)
{
  constexpr int HO  = (MODE == 1) ? HIN / 2 : (MODE == 2 ? HIN * 2 : HIN);
  constexpr int WO  = (MODE == 1) ? WIN / 2 : (MODE == 2 ? WIN * 2 : WIN);
  constexpr int TIH = (MODE == 1) ? 2 * TH + 1 : TH + 2;
  constexpr int TIW = (MODE == 1) ? 2 * TW + 1 : TW + 2;
  constexpr int CG  = CIN / 8;
  constexpr int K   = 9 * CIN;
  constexpr int KS  = K / 32;
  constexpr int NT  = COUT / 16;
  constexpr int MT  = (TH * TW) / 16;
  constexpr int MPW = MT / 4;
  constexpr int TY  = HO / TH, TX = WO / TW;

  __shared__ unsigned short lds[TIH * TIW * CG * 8];

  const int bid = blockIdx.x;
  const int n = bid / (TY * TX);
  const int trem = bid % (TY * TX);
  const int ty0 = (trem / TX) * TH, tx0 = (trem % TX) * TW;

  constexpr int ENT = TIH * TIW * CG;
  for (int e = threadIdx.x; e < ENT; e += 256) {
    int txx = e % TIW;
    int rr  = e / TIW;
    int cg  = rr % CG;
    int tyy = rr / CG;
    int iy, ix; bool ok;
    if (MODE == 0) {
      iy = ty0 + tyy - 1; ix = tx0 + txx - 1;
      ok = (unsigned)iy < (unsigned)HIN && (unsigned)ix < (unsigned)WIN;
    } else if (MODE == 1) {
      iy = 2 * ty0 + tyy - 1; ix = 2 * tx0 + txx - 1;
      ok = (unsigned)iy < (unsigned)HIN && (unsigned)ix < (unsigned)WIN;
    } else {
      int vy = ty0 + tyy - 1, vx = tx0 + txx - 1;
      ok = vy >= 0 && vx >= 0 && !(vy & 1) && !(vx & 1);
      iy = vy >> 1; ix = vx >> 1;
      ok = ok && iy < HIN && ix < WIN;
    }
    int4 val = {0, 0, 0, 0};
    if (ok) val = *(const int4*)&in[(((size_t)n * HIN + iy) * WIN + ix) * CIN + cg * 8];
    *(int4*)&lds[(size_t)e * 8] = val;
  }
  __syncthreads();

  const int lane = threadIdx.x & 63, wv = threadIdx.x >> 6;
  const int l15 = lane & 15, l4 = lane >> 4;

  f4_t acc[MPW][NT] = {};
  for (int ks = 0; ks < KS; ++ks) {
    const int tap = (ks * 32) / CIN;
    const int kh = tap / 3, kw = tap % 3;
    const int cb = ((ks * 32) % CIN) / 8 + l4;
    bf8_t bf[NT];
#pragma unroll
    for (int nt = 0; nt < NT; ++nt)
      bf[nt] = *(const bf8_t*)&wb[(size_t)(nt * 16 + l15) * K + ks * 32 + 8 * l4];
#pragma unroll
    for (int mi = 0; mi < MPW; ++mi) {
      int m = (wv * MPW + mi) * 16 + l15;
      int oy = m / TW, ox = m % TW;
      int rt = ((MODE == 1) ? 2 * oy : oy) + kh;
      int ct = ((MODE == 1) ? 2 * ox : ox) + kw;
      bf8_t a = *(const bf8_t*)&lds[(((size_t)rt * CG + cb) * TIW + ct) * 8];
#pragma unroll
      for (int nt = 0; nt < NT; ++nt)
        acc[mi][nt] = __builtin_amdgcn_mfma_f32_16x16x32_bf16(a, bf[nt], acc[mi][nt], 0, 0, 0);
    }
  }

#pragma unroll
  for (int mi = 0; mi < MPW; ++mi) {
    int mbase = (wv * MPW + mi) * 16;
#pragma unroll
    for (int nt = 0; nt < NT; ++nt) {
      int co = nt * 16 + l15;
      float bv = bias[co];
#pragma unroll
      for (int r = 0; r < 4; ++r) {
        int m = mbase + l4 * 4 + r;
        int oy = m / TW, ox = m % TW;
        float v = acc[mi][nt][r] + bv;
        out[(((size_t)n * HO + ty0 + oy) * WO + (tx0 + ox)) * COUT + co] = f2bf(gelu_f(v));
      }
    }
  }
}

// ---------------------------------------------------------------------------
// MFMA GEMM: C[m][n] = act(sum_k A[m][k]*B[n][k] + bias).
// BIASMODE: 0 = bias[col], 1 = dl-permuted bias, 2 = no bias.
// ---------------------------------------------------------------------------
template<int BIASMODE, bool GELU, bool OUTBF16>
__global__ __launch_bounds__(256) void gemm16_k(
    const unsigned short* __restrict__ A, const unsigned short* __restrict__ Bw,
    const float* __restrict__ bias, void* __restrict__ Cv, int M, int N, int K)
{
  const int lane = threadIdx.x & 63, wv = threadIdx.x >> 6;
  const int l15 = lane & 15, l4 = lane >> 4;
  const int mbase = blockIdx.y * 64 + wv * 16;
  const int nbase = blockIdx.x * 64;
  f4_t acc[4] = {};
  for (int k0 = 0; k0 < K; k0 += 32) {
    bf8_t a = *(const bf8_t*)&A[(size_t)(mbase + l15) * K + k0 + 8 * l4];
#pragma unroll
    for (int nt = 0; nt < 4; ++nt) {
      bf8_t b = *(const bf8_t*)&Bw[(size_t)(nbase + nt * 16 + l15) * K + k0 + 8 * l4];
      acc[nt] = __builtin_amdgcn_mfma_f32_16x16x32_bf16(a, b, acc[nt], 0, 0, 0);
    }
  }
#pragma unroll
  for (int nt = 0; nt < 4; ++nt) {
    int col = nbase + nt * 16 + l15;
    float bv = 0.f;
    if (BIASMODE == 0) bv = bias[col];
    if (BIASMODE == 1) bv = bias[(col & 63) * 64 + (col >> 6)];
#pragma unroll
    for (int r = 0; r < 4; ++r) {
      int row = mbase + l4 * 4 + r;
      float v = acc[nt][r] + bv;
      if (GELU) v = gelu_f(v);
      if (OUTBF16) ((unsigned short*)Cv)[(size_t)row * N + col] = f2bf(v);
      else         ((float*)Cv)[(size_t)row * N + col] = v;
    }
  }
}

// ---------------------------------------------------------------------------
// dt3 (tconv 32->1) + tanh + fused loss partials. bf16 NHWC in. 1024 images.
// ---------------------------------------------------------------------------
__global__ __launch_bounds__(256) void dt3_loss_k(
    const unsigned short* __restrict__ in,
    const float* __restrict__ w, const float* __restrict__ bias,
    const float* __restrict__ xref, const float* __restrict__ tref,
    float* __restrict__ fout, float* __restrict__ partials)
{
  __shared__ float sw[288];
  for (int i = threadIdx.x; i < 288; i += 256) sw[i] = w[i];
  __syncthreads();
  int idx = blockIdx.x * 256 + threadIdx.x;
  int q = idx & 63, p = (idx >> 6) & 63, n = idx >> 12;
  float acc = bias[0];
#pragma unroll
  for (int kh = 0; kh < 3; ++kh) {
    int u = p + kh - 1;
    if (u < 0 || (u & 1) || u >= 64) continue;
#pragma unroll
    for (int kw = 0; kw < 3; ++kw) {
      int v = q + kw - 1;
      if (v < 0 || (v & 1) || v >= 64) continue;
      const unsigned short* row = in + (((size_t)n * 32 + (u >> 1)) * 32 + (v >> 1)) * 32;
      int wo = (2 - kh) * 3 + (2 - kw);
#pragma unroll
      for (int w2 = 0; w2 < 16; ++w2) {
        unsigned dv = *(const unsigned*)&row[w2 * 2];
        acc = fmaf(__uint_as_float(dv << 16),        sw[(2 * w2) * 9 + wo], acc);
        acc = fmaf(__uint_as_float(dv & 0xffff0000u), sw[(2 * w2 + 1) * 9 + wo], acc);
      }
    }
  }
  float val = tanhf(acc);
  float d;
  int pix = p * 64 + q;
  if (n < 512) {
    fout[(size_t)n * 4096 + pix] = val;
    d = val - tref[(size_t)n * 4096 + pix];
  } else {
    d = val - xref[(size_t)(n - 512) * 4096 + pix];
  }
  __shared__ float red[256];
  red[threadIdx.x] = d * d;
  __syncthreads();
#pragma unroll
  for (int s = 128; s > 0; s >>= 1) {
    if (threadIdx.x < s) red[threadIdx.x] += red[threadIdx.x + s];
    __syncthreads();
  }
  if (threadIdx.x == 0) partials[blockIdx.x] = red[0];
}

__global__ __launch_bounds__(256) void loss_final_k(
    const float* __restrict__ partials, float* __restrict__ out01)
{
  __shared__ float red[256];
  int base = blockIdx.x * 8192;
  float s = 0.f;
  for (int i = threadIdx.x; i < 8192; i += 256) s += partials[base + i];
  red[threadIdx.x] = s;
  __syncthreads();
#pragma unroll
  for (int st = 128; st > 0; st >>= 1) {
    if (threadIdx.x < st) red[threadIdx.x] += red[threadIdx.x + st];
    __syncthreads();
  }
  if (threadIdx.x == 0) out01[blockIdx.x] = red[0] * (1.0f / 2097152.0f);
}

// ---------------------------------------------------------------------------
// LSTM v7: 160 blocks = (layer l, colgroup jg), LDS-resident weights, but
// POINT-TO-POINT producer/consumer counters instead of a global barrier:
//   cnt[l] += 1 per block per finished cell (16/cell). Cell (l,t) waits:
//     l>0:            cnt[l-1] >= 16*(t+1)      (x-input ready)
//     l==0 && t>=16:  cnt[9]   >= 16*t          (feedback h9 ready)
//     WAR guard t>=2: l<9: cnt[l+1] >= 16*(t-1); l==9 && t>=17: cnt[0] >= 16*t
// Phase 1 (t<16) becomes a systolic pipeline (layer 0 teacher-forced, free);
// phase 2 pays one producer->consumer handoff per step, no 160-block barrier.
// One global barrier remains (after init staging).
// ---------------------------------------------------------------------------
#define LSTM_NB 160

DEV void gridbar(unsigned* bar, unsigned target) {
  __syncthreads();
  if (threadIdx.x == 0) {
    __hip_atomic_fetch_add(bar, 1u, __ATOMIC_RELEASE, __HIP_MEMORY_SCOPE_AGENT);
    unsigned spins = 0;
    while (__hip_atomic_load(bar, __ATOMIC_RELAXED, __HIP_MEMORY_SCOPE_AGENT) < target) {
      __builtin_amdgcn_s_sleep(2);
      if (++spins > (1u << 24)) break;   // safety valve
    }
    (void)__hip_atomic_load(bar, __ATOMIC_ACQUIRE, __HIP_MEMORY_SCOPE_AGENT);
  }
  __syncthreads();
}

DEV void spin_ge(unsigned* c, unsigned tgt) {
  unsigned spins = 0;
  while (__hip_atomic_load(c, __ATOMIC_RELAXED, __HIP_MEMORY_SCOPE_AGENT) < tgt) {
    __builtin_amdgcn_s_sleep(1);
    if (++spins > (1u << 24)) break;     // safety valve
  }
}

__global__ __launch_bounds__(256, 1) void lstm7_k(
    const float* __restrict__ z,              // (1024,256) fp32, row = b*32+t
    const unsigned short* __restrict__ wihb,  // frag-swizzled bf16 (10 layers)
    const unsigned short* __restrict__ whhb,
    const unsigned short* __restrict__ meffb, // frag-swizzled Meff (1 layer)
    const float* __restrict__ bih, const float* __restrict__ bhh,
    const float* __restrict__ beff,
    unsigned short* __restrict__ zbf,     // (16,32,256) bf16 [t][b][k]
    unsigned short* __restrict__ hbf,     // (2,10,32,256) bf16
    unsigned short* __restrict__ h9sav,   // (16,32,256) bf16, slot tt=t-15
    unsigned* __restrict__ bar)           // bar[0]=init barrier; cnt[l]=bar[32+l*32]
{
  __shared__ unsigned short s_w[4 * 2 * 4096]; // 64KB [g][wi/wh][frag 4096]
  __shared__ unsigned short s_x[8192];         // 16KB swizzled [32 rows][32 ch]
  __shared__ unsigned short s_h[8192];         // 16KB
  __shared__ float zsm[4 * 32 * 17];           // 8.7KB [gate][row][col pad17]
  __shared__ float cls[32 * 16];               // c state for this layer
  __shared__ float sbias[64];                  // bih+bhh for this layer [g][j]
  __shared__ float sb2[64];                    // beff+bhh0 [g][j]

  const int tid = threadIdx.x;
  const int bid = blockIdx.x;
  const int l   = bid >> 4;                    // layer 0..9
  const int jg  = bid & 15;
  const int col0 = jg * 16;
  const int lane = tid & 63, g = tid >> 6;     // wave = gate
  const int l15 = lane & 15, l4 = lane >> 4;
  const int gtid = bid * 256 + tid;

  unsigned* cown  = bar + 32 + l * 32;
  unsigned* cprev = bar + 32 + (l - 1) * 32;
  unsigned* cnext = bar + 32 + (l + 1) * 32;
  unsigned* c9    = bar + 32 + 9 * 32;
  unsigned* c0    = bar + 32;

  // ---- init: zbf transpose+bf16, zero hbf parity 1 ----
  for (int i = gtid; i < 16 * 32 * 256; i += LSTM_NB * 256) {
    int k = i & 255, r = i >> 8;
    int tt = r >> 5, b = r & 31;
    zbf[i] = f2bf(z[(size_t)(b * 32 + tt) * 256 + k]);
  }
  for (int i = gtid; i < 81920; i += LSTM_NB * 256) hbf[81920 + i] = 0;
  // ---- stage this layer's weights into LDS (4096 chunks of 16B) ----
  for (int c = tid; c < 4096; c += 256) {
    int gm = c >> 9;                 // g*2 + m
    int gg = gm >> 1, m = gm & 1;
    int c2 = c & 511;
    const unsigned short* src = (m == 0 ? wihb : whhb)
        + ((size_t)(l * 64 + gg * 16 + jg) * 8) * 512;
    *(int4*)&s_w[(size_t)c * 8] = *(const int4*)&src[(size_t)c2 * 8];
  }
  for (int i = tid; i < 512; i += 256) cls[i] = 0.f;
  if (tid < 64) {
    int gg = tid >> 4, j = tid & 15;
    sbias[tid] = bih[l * 1024 + gg * 256 + col0 + j]
               + bhh[l * 1024 + gg * 256 + col0 + j];
    sb2[tid]   = beff[gg * 256 + col0 + j] + bhh[gg * 256 + col0 + j];
  }

  gridbar(bar, LSTM_NB);   // one global barrier: init staging visible

  auto cell = [&](int t, bool p2) {
    const int cur = t & 1, prv = cur ^ 1;
    const bool p2l0 = p2 && (l == 0);
    const unsigned short* xb =
        (l == 0) ? (p2 ? (hbf + (size_t)((prv * 10 + 9) * 32) * 256)
                       : (zbf + (size_t)t * 32 * 256))
                 : (hbf + (size_t)((cur * 10 + l - 1) * 32) * 256);
    const unsigned short* hb = hbf + (size_t)((prv * 10 + l) * 32) * 256;
    // ---- stage x,h -> LDS (XOR-swizzled), 4+4 parallel 16B loads/thread ----
#pragma unroll
    for (int i = 0; i < 4; ++i) {
      int c = tid + i * 256;                     // chunk 0..1023
      int sw = (c & ~31) | ((c & 31) ^ ((c >> 5) & 7));
      *(int4*)&s_x[(size_t)sw * 8] = *(const int4*)&xb[(size_t)c * 8];
      *(int4*)&s_h[(size_t)sw * 8] = *(const int4*)&hb[(size_t)c * 8];
    }
    __syncthreads();
    // ---- MFMA: 4 chains of 8, frags from LDS ----
    f4_t a0 = {}, a1 = {}, b0 = {}, b1 = {};
#pragma unroll
    for (int ks = 0; ks < 8; ++ks) {
      bf8_t bwi = *(const bf8_t*)&s_w[(size_t)((g * 2 + 0) * 4096 + ks * 512 + lane * 8)];
      bf8_t bwh = *(const bf8_t*)&s_w[(size_t)((g * 2 + 1) * 4096 + ks * 512 + lane * 8)];
      int cx0 = (l15 << 5) | ((ks * 4 + l4) ^ (l15 & 7));
      int cx1 = ((16 + l15) << 5) | ((ks * 4 + l4) ^ (l15 & 7));
      bf8_t ax0 = *(const bf8_t*)&s_x[(size_t)cx0 * 8];
      bf8_t ax1 = *(const bf8_t*)&s_x[(size_t)cx1 * 8];
      bf8_t ah0 = *(const bf8_t*)&s_h[(size_t)cx0 * 8];
      bf8_t ah1 = *(const bf8_t*)&s_h[(size_t)cx1 * 8];
      a0 = __builtin_amdgcn_mfma_f32_16x16x32_bf16(ax0, bwi, a0, 0, 0, 0);
      a1 = __builtin_amdgcn_mfma_f32_16x16x32_bf16(ax1, bwi, a1, 0, 0, 0);
      b0 = __builtin_amdgcn_mfma_f32_16x16x32_bf16(ah0, bwh, b0, 0, 0, 0);
      b1 = __builtin_amdgcn_mfma_f32_16x16x32_bf16(ah1, bwh, b1, 0, 0, 0);
    }
#pragma unroll
    for (int r = 0; r < 4; ++r) {
      zsm[(g * 32 + l4 * 4 + r) * 17 + l15] = a0[r] + b0[r];
      zsm[(g * 32 + 16 + l4 * 4 + r) * 17 + l15] = a1[r] + b1[r];
    }
    __syncthreads();
    // ---- gate math: 512 elems, 2/thread ----
#pragma unroll
    for (int half = 0; half < 2; ++half) {
      int e = tid + half * 256;
      int b = e >> 4, j = e & 15;
      float zi = zsm[(0 * 32 + b) * 17 + j] + (p2l0 ? sb2[j]      : sbias[j]);
      float zf = zsm[(1 * 32 + b) * 17 + j] + (p2l0 ? sb2[16 + j] : sbias[16 + j]);
      float zg = zsm[(2 * 32 + b) * 17 + j] + (p2l0 ? sb2[32 + j] : sbias[32 + j]);
      float zo = zsm[(3 * 32 + b) * 17 + j] + (p2l0 ? sb2[48 + j] : sbias[48 + j]);
      float cold = cls[b * 16 + j];
      float cn = sigm_f(zf) * cold + sigm_f(zi) * tanhf(zg);
      cls[b * 16 + j] = cn;
      float hn = sigm_f(zo) * tanhf(cn);
      unsigned short hv = f2bf(hn);
      hbf[(size_t)((cur * 10 + l) * 32 + b) * 256 + col0 + j] = hv;
      if (l == 9 && t >= 15) h9sav[(size_t)((t - 15) * 32 + b) * 256 + col0 + j] = hv;
    }
    __syncthreads();   // drains stores (vmcnt) before release-increment
  };

  for (int t = 0; t <= 30; ++t) {
    // ---- dataflow waits (thread0 polls, acquire, then block joins) ----
    if (tid == 0) {
      if (l == 0) {
        if (t >= 16) spin_ge(c9, 16u * t);
      } else {
        spin_ge(cprev, 16u * (t + 1));
      }
      if (t >= 2) {
        if (l < 9) spin_ge(cnext, 16u * (t - 1));
        else if (t >= 17) spin_ge(c0, 16u * t);
      }
      (void)__hip_atomic_load(cown, __ATOMIC_ACQUIRE, __HIP_MEMORY_SCOPE_AGENT);
    }
    __syncthreads();
    cell(t, t >= 16);
    if (tid == 0)
      __hip_atomic_fetch_add(cown, 1u, __ATOMIC_RELEASE, __HIP_MEMORY_SCOPE_AGENT);
    // ---- l=0: hot-swap wi LDS region -> Meff between t=15 and t=16 ----
    if (l == 0 && t == 15) {
      for (int c = tid; c < 2048; c += 256) {
        int gg = c >> 9, c2 = c & 511;
        const unsigned short* src = meffb + ((size_t)(gg * 16 + jg) * 8) * 512;
        *(int4*)&s_w[(size_t)((gg * 2) * 512 + c2) * 8] = *(const int4*)&src[(size_t)c2 * 8];
      }
      __syncthreads();
    }
  }
}

// ---------------------------------------------------------------------------
// Decoder input gather -> bf16: rows 0..511 = y_t, rows 512..1023 = z_x
// ---------------------------------------------------------------------------
__global__ __launch_bounds__(256) void gather_dec_k(
    const float* __restrict__ outs, const float* __restrict__ z,
    unsigned short* __restrict__ ydec)
{
  int idx = blockIdx.x * 256 + threadIdx.x;   // < 262144
  int rrow = idx >> 8, k = idx & 255;
  float v;
  if (rrow < 512) {
    int b = rrow >> 4, i = rrow & 15;
    v = outs[(size_t)((15 + i) * 32 + b) * 256 + k];
  } else {
    int rr = rrow - 512;
    int b = rr >> 4, tt = rr & 15;
    v = z[(size_t)(b * 32 + tt) * 256 + k];
  }
  ydec[idx] = f2bf(v);
}

// ---------------------------------------------------------------------------
extern "C" void kernel_launch(void* const* d_in, const int* in_sizes, int n_in,
                              void* d_out, int out_size, void* d_ws, size_t ws_size,
                              hipStream_t stream) {
  const float* x     = (const float*)d_in[0];
  const float* t     = (const float*)d_in[1];
  const float* ec1_w = (const float*)d_in[2];
  const float* ec1_b = (const float*)d_in[3];
  const float* ec2_w = (const float*)d_in[4];
  const float* ec2_b = (const float*)d_in[5];
  const float* ec3_w = (const float*)d_in[6];
  const float* ec3_b = (const float*)d_in[7];
  const float* ec4_w = (const float*)d_in[8];
  const float* ec4_b = (const float*)d_in[9];
  const float* ec5_w = (const float*)d_in[10];
  const float* ec5_b = (const float*)d_in[11];
  const float* el_w  = (const float*)d_in[12];
  const float* el_b  = (const float*)d_in[13];
  const float* dl_w  = (const float*)d_in[14];
  const float* dl_b  = (const float*)d_in[15];
  const float* dt1_w = (const float*)d_in[16];
  const float* dt1_b = (const float*)d_in[17];
  const float* dc1_w = (const float*)d_in[18];
  const float* dc1_b = (const float*)d_in[19];
  const float* dt2_w = (const float*)d_in[20];
  const float* dt2_b = (const float*)d_in[21];
  const float* dc2_w = (const float*)d_in[22];
  const float* dc2_b = (const float*)d_in[23];
  const float* dt3_w = (const float*)d_in[24];
  const float* dt3_b = (const float*)d_in[25];
  const float* Wih   = (const float*)d_in[26];
  const float* Whh   = (const float*)d_in[27];
  const float* bih   = (const float*)d_in[28];
  const float* bhh   = (const float*)d_in[29];
  const float* lw    = (const float*)d_in[30];
  const float* lb    = (const float*)d_in[31];
  float* out = (float*)d_out;

  char* base = (char*)d_ws;
  size_t off = 0;
  auto alloc = [&](size_t bytes) -> char* {
    char* p = base + off;
    off += (bytes + 255) & ~(size_t)255;
    return p;
  };
  typedef unsigned short us;
  unsigned* bar   = (unsigned*)alloc(4096);
  float* zbuf     = (float*)alloc((size_t)1024 * 256 * 4);
  float* outsbuf  = (float*)alloc((size_t)31 * 32 * 256 * 4);
  us*    zbf      = (us*)alloc((size_t)16 * 32 * 256 * 2);
  us*    hbf      = (us*)alloc((size_t)2 * 10 * 32 * 256 * 2);
  us*    h9sav    = (us*)alloc((size_t)16 * 32 * 256 * 2);
  us*    ydec     = (us*)alloc((size_t)1024 * 256 * 2);
  float* partials = (float*)alloc((size_t)16384 * 4);
  us* wb_ec2 = (us*)alloc((size_t)32 * 288 * 2);
  us* wb_ec3 = (us*)alloc((size_t)64 * 288 * 2);
  us* wb_ec4 = (us*)alloc((size_t)64 * 576 * 2);
  us* wb_ec5 = (us*)alloc((size_t)64 * 576 * 2);
  us* wb_dt1 = (us*)alloc((size_t)64 * 576 * 2);
  us* wb_dc1 = (us*)alloc((size_t)64 * 576 * 2);
  us* wb_dt2 = (us*)alloc((size_t)32 * 576 * 2);
  us* wb_dc2 = (us*)alloc((size_t)32 * 288 * 2);
  us* elWb   = (us*)alloc((size_t)256 * 4096 * 2);
  us* dlWb   = (us*)alloc((size_t)4096 * 256 * 2);
  us* wihb   = (us*)alloc((size_t)10 * 1024 * 256 * 2);      // 5 MB
  us* whhb   = (us*)alloc((size_t)10 * 1024 * 256 * 2);      // 5 MB
  us* wih0b  = (us*)alloc((size_t)1024 * 256 * 2);
  us* lwTb   = (us*)alloc((size_t)256 * 256 * 2);
  us* lwbp   = (us*)alloc((size_t)256 * 256 * 2);
  us* meffp  = (us*)alloc((size_t)1024 * 256 * 2);
  us* meffb  = (us*)alloc((size_t)1024 * 256 * 2);
  float* beff = (float*)alloc((size_t)1024 * 4);
  us* enc5   = (us*)alloc((size_t)1024 * 4096 * 2);          // 8.4 MB
  us* bufA   = (us*)alloc((size_t)1024 * 32 * 32 * 32 * 2);  // 67 MB
  us* bufB   = (us*)alloc((size_t)1024 * 32 * 32 * 32 * 2);  // 67 MB
  (void)in_sizes; (void)n_in; (void)out_size; (void)ws_size;

  hipMemsetAsync(bar, 0, 4096, stream);

  // ---- weight prep ----
  prepw_k<<<(32*32*9+255)/256, 256, 0, stream>>>(ec2_w, wb_ec2, 32, 32, 0);
  prepw_k<<<(64*32*9+255)/256, 256, 0, stream>>>(ec3_w, wb_ec3, 64, 32, 0);
  prepw_k<<<(64*64*9+255)/256, 256, 0, stream>>>(ec4_w, wb_ec4, 64, 64, 0);
  prepw_k<<<(64*64*9+255)/256, 256, 0, stream>>>(ec5_w, wb_ec5, 64, 64, 0);
  prepw_k<<<(64*64*9+255)/256, 256, 0, stream>>>(dt1_w, wb_dt1, 64, 64, 1);
  prepw_k<<<(64*64*9+255)/256, 256, 0, stream>>>(dc1_w, wb_dc1, 64, 64, 0);
  prepw_k<<<(32*64*9+255)/256, 256, 0, stream>>>(dt2_w, wb_dt2, 32, 64, 1);
  prepw_k<<<(32*32*9+255)/256, 256, 0, stream>>>(dc2_w, wb_dc2, 32, 32, 0);
  prep_el_k<<<4096, 256, 0, stream>>>(el_w, elWb);
  prep_dl_k<<<4096, 256, 0, stream>>>(dl_w, dlWb);
  prep_wlstm_k<<<10240, 256, 0, stream>>>(Wih, wihb);
  prep_wlstm_k<<<10240, 256, 0, stream>>>(Whh, whhb);
  // Meff = Wih0 @ lw (1024x256), beff = Wih0 @ lb + bih0
  cast_bf16_k<<<1024, 256, 0, stream>>>(Wih, wih0b, 262144);
  prep_lwt_k<<<256, 256, 0, stream>>>(lw, lwTb);
  cast_bf16_k<<<256, 256, 0, stream>>>(lw, lwbp, 65536);
  gemm16_k<2, false, true><<<dim3(4, 16), 256, 0, stream>>>(wih0b, lwTb, lb, meffp, 1024, 256, 256);
  prep_wl1_k<<<1024, 256, 0, stream>>>(meffp, meffb);
  beff_k<<<4, 256, 0, stream>>>(Wih, lb, bih, beff);

  // ---- encoder: single 1024-image pass ----
  ec1_k<<<4096, 256, 0, stream>>>(x, t, ec1_w, ec1_b, bufA);
  convmf_k<32, 32, 32, 32, 32, 32, 0><<<1024, 256, 0, stream>>>(bufA, wb_ec2, ec2_b, bufB);
  convmf_k<32, 64, 32, 32, 16, 16, 1><<<1024, 256, 0, stream>>>(bufB, wb_ec3, ec3_b, bufA);
  convmf_k<64, 64, 16, 16, 16, 16, 0><<<1024, 256, 0, stream>>>(bufA, wb_ec4, ec4_b, bufB);
  convmf_k<64, 64, 16, 16, 8, 8, 1><<<1024, 256, 0, stream>>>(bufB, wb_ec5, ec5_b, enc5);
  gemm16_k<0, false, false><<<dim3(4, 16), 256, 0, stream>>>(enc5, elWb, el_b, zbuf, 1024, 256, 4096);

  // ---- LSTM (MFMA, 160 blocks, point-to-point dataflow sync) ----
  lstm7_k<<<LSTM_NB, 256, 0, stream>>>(zbuf, wihb, whhb, meffb, bih, bhh, beff,
                                       zbf, hbf, h9sav, bar);
  // outs[t=15..30] = h9sav @ lw^T + lb
  gemm16_k<0, false, false><<<dim3(4, 8), 256, 0, stream>>>(
      h9sav, lwbp, lb, outsbuf + (size_t)15 * 32 * 256, 512, 256, 256);

  // ---- decoder: single 1024-row pass (rows 0..511 pred, 512..1023 rec) ----
  gather_dec_k<<<1024, 256, 0, stream>>>(outsbuf, zbuf, ydec);
  gemm16_k<1, true, true><<<dim3(64, 16), 256, 0, stream>>>(ydec, dlWb, dl_b, bufB, 1024, 4096, 256);
  convmf_k<64, 64, 8, 8, 16, 16, 2><<<1024, 256, 0, stream>>>(bufB, wb_dt1, dt1_b, bufA);
  convmf_k<64, 64, 16, 16, 16, 16, 0><<<1024, 256, 0, stream>>>(bufA, wb_dc1, dc1_b, bufB);
  convmf_k<64, 32, 16, 16, 16, 32, 2><<<2048, 256, 0, stream>>>(bufB, wb_dt2, dt2_b, bufA);
  convmf_k<32, 32, 32, 32, 32, 32, 0><<<1024, 256, 0, stream>>>(bufA, wb_dc2, dc2_b, bufB);
  dt3_loss_k<<<16384, 256, 0, stream>>>(bufB, dt3_w, dt3_b, x, t, out + 2, partials);
  loss_final_k<<<2, 256, 0, stream>>>(partials, out);
}

// Round 9
// 1844.973 us; speedup vs baseline: 1.5317x; 1.0033x over previous
//
#include <hip/hip_runtime.h>
#include <math.h>

#define DEV __device__ __forceinline__

typedef __attribute__((ext_vector_type(8))) short bf8_t;   // 8 x bf16 (4 VGPR)
typedef __attribute__((ext_vector_type(4))) float f4_t;    // MFMA acc

DEV float gelu_f(float v) { return 0.5f * v * (1.0f + erff(v * 0.70710678118654752f)); }
DEV float sigm_f(float v) { return 1.0f / (1.0f + expf(-v)); }
DEV unsigned short f2bf(float f) {            // RNE float->bf16
  unsigned u = __float_as_uint(f);
  u = (u + 0x7FFFu + ((u >> 16) & 1u)) >> 16;
  return (unsigned short)u;
}
DEV float bf2f(unsigned short u) { return __uint_as_float((unsigned)u << 16); }

DEV unsigned aload(const unsigned* p) {
  return __hip_atomic_load(p, __ATOMIC_RELAXED, __HIP_MEMORY_SCOPE_AGENT);
}
DEV void astore(unsigned* p, unsigned v) {
  __hip_atomic_store(p, v, __ATOMIC_RELAXED, __HIP_MEMORY_SCOPE_AGENT);
}

// ---------------------------------------------------------------------------
// Weight prep: conv weights -> bf16 [co][kh][kw][ci] (no flip; stride convs)
// ---------------------------------------------------------------------------
__global__ __launch_bounds__(256) void prepw_k(
    const float* __restrict__ w, unsigned short* __restrict__ wb,
    int COUT, int CIN)
{
  int idx = blockIdx.x * 256 + threadIdx.x;
  int total = COUT * CIN * 9;
  if (idx >= total) return;
  int ci = idx % CIN;
  int r  = idx / CIN;
  int kw = r % 3; r /= 3;
  int kh = r % 3;
  int co = r / 3;
  wb[idx] = f2bf(w[((co * CIN + ci) * 3 + kh) * 3 + kw]);
}

// tconv weights (CIN,COUT,3,3) -> parity-ordered bf16 [co][ti*CIN+ci], flipped.
// TAPORD = {4, 3,5, 1,7, 0,2,6,8} (p00 | p01 | p10 | p11), tap = kh*3+kw.
__global__ __launch_bounds__(256) void prepw_par_k(
    const float* __restrict__ w, unsigned short* __restrict__ wbp,
    int COUT, int CIN)
{
  int idx = blockIdx.x * 256 + threadIdx.x;
  int total = COUT * CIN * 9;
  if (idx >= total) return;
  const int TAPORD[9] = {4, 3, 5, 1, 7, 0, 2, 6, 8};
  int ci = idx % CIN;
  int r  = idx / CIN;
  int ti = r % 9;
  int co = r / 9;
  int tap = TAPORD[ti];
  int kh = tap / 3, kw = tap % 3;
  wbp[idx] = f2bf(w[((ci * COUT + co) * 3 + (2 - kh)) * 3 + (2 - kw)]);
}

// el_w (256,4096 k_ref=c*64+s) -> bf16 [n][k_new=(s*64+c)]
__global__ __launch_bounds__(256) void prep_el_k(
    const float* __restrict__ w, unsigned short* __restrict__ wb)
{
  int idx = blockIdx.x * 256 + threadIdx.x;     // < 256*4096
  int kn = idx & 4095, n = idx >> 12;
  wb[idx] = f2bf(w[(size_t)n * 4096 + ((kn & 63) * 64 + (kn >> 6))]);
}

// dl_w (4096,256) row r=c*64+s -> bf16 rows nout=s*64+c
__global__ __launch_bounds__(256) void prep_dl_k(
    const float* __restrict__ w, unsigned short* __restrict__ wb)
{
  int idx = blockIdx.x * 256 + threadIdx.x;     // < 4096*256
  int k = idx & 255, nout = idx >> 8;
  wb[idx] = f2bf(w[(size_t)((nout & 63) * 64 + (nout >> 6)) * 256 + k]);
}

// LSTM weights (10,1024,256) -> bf16 frag-contiguous
__global__ __launch_bounds__(256) void prep_wlstm_k(
    const float* __restrict__ w, unsigned short* __restrict__ wb)
{
  int idx = blockIdx.x * 256 + threadIdx.x;   // exactly 2621440 = 10240 blocks
  int e = idx & 7, lane = (idx >> 3) & 63, ks = (idx >> 9) & 7;
  int nt = (idx >> 12) & 63, l = idx >> 18;
  wb[idx] = f2bf(w[((size_t)l * 1024 + nt * 16 + (lane & 15)) * 256
                   + ks * 32 + (lane >> 4) * 8 + e]);
}

// single-layer (1024x256) bf16 [j][k] -> frag layout
__global__ __launch_bounds__(256) void prep_wl1_k(
    const unsigned short* __restrict__ src, unsigned short* __restrict__ wb)
{
  int idx = blockIdx.x * 256 + threadIdx.x;   // 262144 = 1024 blocks
  int e = idx & 7, lane = (idx >> 3) & 63, ks = (idx >> 9) & 7, nt = idx >> 12;
  wb[idx] = src[(size_t)(nt * 16 + (lane & 15)) * 256 + ks * 32 + (lane >> 4) * 8 + e];
}

__global__ __launch_bounds__(256) void cast_bf16_k(
    const float* __restrict__ src, unsigned short* __restrict__ dst, int count)
{
  int idx = blockIdx.x * 256 + threadIdx.x;
  if (idx < count) dst[idx] = f2bf(src[idx]);
}

// lwT bf16: lwTb[kcol*256 + n] = lw[n*256 + kcol]
__global__ __launch_bounds__(256) void prep_lwt_k(
    const float* __restrict__ lw, unsigned short* __restrict__ lwTb)
{
  int idx = blockIdx.x * 256 + threadIdx.x;   // 65536
  int n = idx & 255, kcol = idx >> 8;
  lwTb[idx] = f2bf(lw[(size_t)n * 256 + kcol]);
}

// beff[j] = sum_n Wih0[j,n]*lb[n] + bih0[j]
__global__ __launch_bounds__(256) void beff_k(
    const float* __restrict__ Wih, const float* __restrict__ lb,
    const float* __restrict__ bih, float* __restrict__ beff)
{
  int j = blockIdx.x * 256 + threadIdx.x;     // < 1024
  float s = bih[j];
  const float* row = Wih + (size_t)j * 256;
  for (int n = 0; n < 256; ++n) s = fmaf(row[n], lb[n], s);
  beff[j] = s;
}

// ---------------------------------------------------------------------------
// ec1: 1ch 64x64 s2 -> 32ch 32x32, NHWC bf16 out. 1024 images.
// ---------------------------------------------------------------------------
__global__ __launch_bounds__(256) void ec1_k(
    const float* __restrict__ x, const float* __restrict__ t,
    const float* __restrict__ w, const float* __restrict__ bias,
    unsigned short* __restrict__ out)
{
  __shared__ float sw[288];
  __shared__ float sb[32];
  for (int i = threadIdx.x; i < 288; i += 256) sw[i] = w[i];
  if (threadIdx.x < 32) sb[threadIdx.x] = bias[threadIdx.x];
  __syncthreads();
  int idx = blockIdx.x * 256 + threadIdx.x;     // < 1024*32*32
  int ox = idx & 31, oy = (idx >> 5) & 31, n = idx >> 10;
  int b = n >> 5, j = n & 31;
  const float* ip = (j < 16) ? (x + (size_t)(b * 16 + j) * 4096)
                             : (t + (size_t)(b * 16 + j - 16) * 4096);
  float pv[9];
#pragma unroll
  for (int kh = 0; kh < 3; ++kh) {
    int iy = oy * 2 + kh - 1;
#pragma unroll
    for (int kw = 0; kw < 3; ++kw) {
      int ix = ox * 2 + kw - 1;
      pv[kh * 3 + kw] = ((unsigned)iy < 64u && (unsigned)ix < 64u) ? ip[iy * 64 + ix] : 0.f;
    }
  }
  unsigned short u[32];
#pragma unroll
  for (int co = 0; co < 32; ++co) {
    float a = sb[co];
#pragma unroll
    for (int i = 0; i < 9; ++i) a = fmaf(pv[i], sw[co * 9 + i], a);
    u[co] = f2bf(gelu_f(a));
  }
  unsigned short* op = out + (size_t)idx * 32;
#pragma unroll
  for (int p = 0; p < 4; ++p) {
    uint4 v;
    v.x = u[p*8+0] | (u[p*8+1] << 16);
    v.y = u[p*8+2] | (u[p*8+3] << 16);
    v.z = u[p*8+4] | (u[p*8+5] << 16);
    v.w = u[p*8+6] | (u[p*8+7] << 16);
    *(uint4*)&op[p * 8] = v;
  }
}

// ---------------------------------------------------------------------------
// MFMA implicit-GEMM conv. NHWC bf16 in/out. MODE: 0=s1, 1=s2.
// ---------------------------------------------------------------------------
template<int CIN, int COUT, int HIN, int WIN, int TH, int TW, int MODE>
__global__ __launch_bounds__(256) void convmf_k(
    const unsigned short* __restrict__ in, const unsigned short* __restrict__ wb,
    const float* __restrict__ bias, unsigned short* __restrict__ out)
{
  constexpr int HO  = (MODE == 1) ? HIN / 2 : HIN;
  constexpr int WO  = (MODE == 1) ? WIN / 2 : WIN;
  constexpr int TIH = (MODE == 1) ? 2 * TH + 1 : TH + 2;
  constexpr int TIW = (MODE == 1) ? 2 * TW + 1 : TW + 2;
  constexpr int CG  = CIN / 8;
  constexpr int K   = 9 * CIN;
  constexpr int KS  = K / 32;
  constexpr int NT  = COUT / 16;
  constexpr int MT  = (TH * TW) / 16;
  constexpr int MPW = MT / 4;
  constexpr int TY  = HO / TH, TX = WO / TW;

  __shared__ unsigned short lds[TIH * TIW * CG * 8];

  const int bid = blockIdx.x;
  const int n = bid / (TY * TX);
  const int trem = bid % (TY * TX);
  const int ty0 = (trem / TX) * TH, tx0 = (trem % TX) * TW;

  constexpr int ENT = TIH * TIW * CG;
  for (int e = threadIdx.x; e < ENT; e += 256) {
    int txx = e % TIW;
    int rr  = e / TIW;
    int cg  = rr % CG;
    int tyy = rr / CG;
    int iy, ix; bool ok;
    if (MODE == 0) {
      iy = ty0 + tyy - 1; ix = tx0 + txx - 1;
      ok = (unsigned)iy < (unsigned)HIN && (unsigned)ix < (unsigned)WIN;
    } else {
      iy = 2 * ty0 + tyy - 1; ix = 2 * tx0 + txx - 1;
      ok = (unsigned)iy < (unsigned)HIN && (unsigned)ix < (unsigned)WIN;
    }
    int4 val = {0, 0, 0, 0};
    if (ok) val = *(const int4*)&in[(((size_t)n * HIN + iy) * WIN + ix) * CIN + cg * 8];
    *(int4*)&lds[(size_t)e * 8] = val;
  }
  __syncthreads();

  const int lane = threadIdx.x & 63, wv = threadIdx.x >> 6;
  const int l15 = lane & 15, l4 = lane >> 4;

  f4_t acc[MPW][NT] = {};
  for (int ks = 0; ks < KS; ++ks) {
    const int tap = (ks * 32) / CIN;
    const int kh = tap / 3, kw = tap % 3;
    const int cb = ((ks * 32) % CIN) / 8 + l4;
    bf8_t bf[NT];
#pragma unroll
    for (int nt = 0; nt < NT; ++nt)
      bf[nt] = *(const bf8_t*)&wb[(size_t)(nt * 16 + l15) * K + ks * 32 + 8 * l4];
#pragma unroll
    for (int mi = 0; mi < MPW; ++mi) {
      int m = (wv * MPW + mi) * 16 + l15;
      int oy = m / TW, ox = m % TW;
      int rt = ((MODE == 1) ? 2 * oy : oy) + kh;
      int ct = ((MODE == 1) ? 2 * ox : ox) + kw;
      bf8_t a = *(const bf8_t*)&lds[(((size_t)rt * CG + cb) * TIW + ct) * 8];
#pragma unroll
      for (int nt = 0; nt < NT; ++nt)
        acc[mi][nt] = __builtin_amdgcn_mfma_f32_16x16x32_bf16(a, bf[nt], acc[mi][nt], 0, 0, 0);
    }
  }

#pragma unroll
  for (int mi = 0; mi < MPW; ++mi) {
    int mbase = (wv * MPW + mi) * 16;
#pragma unroll
    for (int nt = 0; nt < NT; ++nt) {
      int co = nt * 16 + l15;
      float bv = bias[co];
#pragma unroll
      for (int r = 0; r < 4; ++r) {
        int m = mbase + l4 * 4 + r;
        int oy = m / TW, ox = m % TW;
        float v = acc[mi][nt][r] + bv;
        out[(((size_t)n * HO + ty0 + oy) * WO + (tx0 + ox)) * COUT + co] = f2bf(gelu_f(v));
      }
    }
  }
}

// ---------------------------------------------------------------------------
// Parity-decomposed tconv (lhs_dilation=2, out = 2x upsample). Wave = parity
// (dy=wv>>1, dx=wv&1); per-parity K = {1,2,2,4} x CIN taps (vs 9 x CIN with
// zero-stuffing). Weights wbp parity-ordered (prepw_par_k). Staged input tile
// (SH+1)x(SW+1)xCIN covers output sub-tile (2SH x 2SW).
// ---------------------------------------------------------------------------
template<int CIN, int COUT, int HIN, int WIN, int SH, int SW>
__global__ __launch_bounds__(256) void tconvp_k(
    const unsigned short* __restrict__ in, const unsigned short* __restrict__ wbp,
    const float* __restrict__ bias, unsigned short* __restrict__ out)
{
  constexpr int HO = 2 * HIN, WO = 2 * WIN;
  constexpr int CG = CIN / 8;
  constexpr int TIH = SH + 1, TIW = SW + 1;
  constexpr int NT = COUT / 16;
  constexpr int MPW_P = (SH * SW) / 16;
  constexpr int TY = HIN / SH, TX = WIN / SW;

  __shared__ unsigned short lds[TIH * TIW * CG * 8];

  const int bid = blockIdx.x;
  const int n = bid / (TY * TX);
  const int trem = bid % (TY * TX);
  const int toy = trem / TX, tox = trem % TX;
  const int ty0s = toy * SH, tx0s = tox * SW;

  constexpr int ENT = TIH * TIW * CG;
  for (int e = threadIdx.x; e < ENT; e += 256) {
    int txx = e % TIW;
    int rr  = e / TIW;
    int cg  = rr % CG;
    int tyy = rr / CG;
    int iy = ty0s + tyy, ix = tx0s + txx;
    int4 val = {0, 0, 0, 0};
    if (iy < HIN && ix < WIN)
      val = *(const int4*)&in[(((size_t)n * HIN + iy) * WIN + ix) * CIN + cg * 8];
    *(int4*)&lds[(size_t)((tyy * CG + cg) * TIW + txx) * 8] = val;
  }
  __syncthreads();

  const int lane = threadIdx.x & 63, wv = threadIdx.x >> 6;
  const int l15 = lane & 15, l4 = lane >> 4;
  const int dy = wv >> 1, dx = wv & 1;
  const int NXT = 1 + dx;
  const int KS2 = ((1 + dy) * (1 + dx) * CIN) / 32;
  const int koff = (dy ? (dx ? 5 : 3) : (dx ? 1 : 0)) * CIN;

  f4_t acc[MPW_P][NT] = {};
  for (int ks = 0; ks < KS2; ++ks) {
    const int tapi = (ks * 32) / CIN;
    const int cb = ((ks * 32) % CIN) / 8 + l4;
    const int ra = tapi / NXT, rb = tapi % NXT;
    bf8_t bf[NT];
#pragma unroll
    for (int nt = 0; nt < NT; ++nt)
      bf[nt] = *(const bf8_t*)&wbp[(size_t)(nt * 16 + l15) * 9 * CIN + koff + ks * 32 + 8 * l4];
#pragma unroll
    for (int mi = 0; mi < MPW_P; ++mi) {
      int m = mi * 16 + l15;
      int i = m / SW, j = m % SW;
      bf8_t a = *(const bf8_t*)&lds[(size_t)(((i + ra) * CG + cb) * TIW + (j + rb)) * 8];
#pragma unroll
      for (int nt = 0; nt < NT; ++nt)
        acc[mi][nt] = __builtin_amdgcn_mfma_f32_16x16x32_bf16(a, bf[nt], acc[mi][nt], 0, 0, 0);
    }
  }

#pragma unroll
  for (int mi = 0; mi < MPW_P; ++mi) {
#pragma unroll
    for (int nt = 0; nt < NT; ++nt) {
      int co = nt * 16 + l15;
      float bv = bias[co];
#pragma unroll
      for (int r = 0; r < 4; ++r) {
        int m = mi * 16 + l4 * 4 + r;
        int i = m / SW, j = m % SW;
        int orow = 2 * (ty0s + i) + dy, ocol = 2 * (tx0s + j) + dx;
        float v = acc[mi][nt][r] + bv;
        out[(((size_t)n * HO + orow) * WO + ocol) * COUT + co] = f2bf(gelu_f(v));
      }
    }
  }
}

// ---------------------------------------------------------------------------
// MFMA GEMM: C[m][n] = act(sum_k A[m][k]*B[n][k] + bias).
// BIASMODE: 0 = bias[col], 1 = dl-permuted bias, 2 = no bias.
// ---------------------------------------------------------------------------
template<int BIASMODE, bool GELU, bool OUTBF16>
__global__ __launch_bounds__(256) void gemm16_k(
    const unsigned short* __restrict__ A, const unsigned short* __restrict__ Bw,
    const float* __restrict__ bias, void* __restrict__ Cv, int M, int N, int K)
{
  const int lane = threadIdx.x & 63, wv = threadIdx.x >> 6;
  const int l15 = lane & 15, l4 = lane >> 4;
  const int mbase = blockIdx.y * 64 + wv * 16;
  const int nbase = blockIdx.x * 64;
  f4_t acc[4] = {};
  for (int k0 = 0; k0 < K; k0 += 32) {
    bf8_t a = *(const bf8_t*)&A[(size_t)(mbase + l15) * K + k0 + 8 * l4];
#pragma unroll
    for (int nt = 0; nt < 4; ++nt) {
      bf8_t b = *(const bf8_t*)&Bw[(size_t)(nbase + nt * 16 + l15) * K + k0 + 8 * l4];
      acc[nt] = __builtin_amdgcn_mfma_f32_16x16x32_bf16(a, b, acc[nt], 0, 0, 0);
    }
  }
#pragma unroll
  for (int nt = 0; nt < 4; ++nt) {
    int col = nbase + nt * 16 + l15;
    float bv = 0.f;
    if (BIASMODE == 0) bv = bias[col];
    if (BIASMODE == 1) bv = bias[(col & 63) * 64 + (col >> 6)];
#pragma unroll
    for (int r = 0; r < 4; ++r) {
      int row = mbase + l4 * 4 + r;
      float v = acc[nt][r] + bv;
      if (GELU) v = gelu_f(v);
      if (OUTBF16) ((unsigned short*)Cv)[(size_t)row * N + col] = f2bf(v);
      else         ((float*)Cv)[(size_t)row * N + col] = v;
    }
  }
}

// ---------------------------------------------------------------------------
// dt3 (tconv 32->1) + tanh + fused loss partials. bf16 NHWC in. 1024 images.
// ---------------------------------------------------------------------------
__global__ __launch_bounds__(256) void dt3_loss_k(
    const unsigned short* __restrict__ in,
    const float* __restrict__ w, const float* __restrict__ bias,
    const float* __restrict__ xref, const float* __restrict__ tref,
    float* __restrict__ fout, float* __restrict__ partials)
{
  __shared__ float sw[288];
  for (int i = threadIdx.x; i < 288; i += 256) sw[i] = w[i];
  __syncthreads();
  int idx = blockIdx.x * 256 + threadIdx.x;
  int q = idx & 63, p = (idx >> 6) & 63, n = idx >> 12;
  float acc = bias[0];
#pragma unroll
  for (int kh = 0; kh < 3; ++kh) {
    int u = p + kh - 1;
    if (u < 0 || (u & 1) || u >= 64) continue;
#pragma unroll
    for (int kw = 0; kw < 3; ++kw) {
      int v = q + kw - 1;
      if (v < 0 || (v & 1) || v >= 64) continue;
      const unsigned short* row = in + (((size_t)n * 32 + (u >> 1)) * 32 + (v >> 1)) * 32;
      int wo = (2 - kh) * 3 + (2 - kw);
#pragma unroll
      for (int w2 = 0; w2 < 16; ++w2) {
        unsigned dv = *(const unsigned*)&row[w2 * 2];
        acc = fmaf(__uint_as_float(dv << 16),        sw[(2 * w2) * 9 + wo], acc);
        acc = fmaf(__uint_as_float(dv & 0xffff0000u), sw[(2 * w2 + 1) * 9 + wo], acc);
      }
    }
  }
  float val = tanhf(acc);
  float d;
  int pix = p * 64 + q;
  if (n < 512) {
    fout[(size_t)n * 4096 + pix] = val;
    d = val - tref[(size_t)n * 4096 + pix];
  } else {
    d = val - xref[(size_t)(n - 512) * 4096 + pix];
  }
  __shared__ float red[256];
  red[threadIdx.x] = d * d;
  __syncthreads();
#pragma unroll
  for (int s = 128; s > 0; s >>= 1) {
    if (threadIdx.x < s) red[threadIdx.x] += red[threadIdx.x + s];
    __syncthreads();
  }
  if (threadIdx.x == 0) partials[blockIdx.x] = red[0];
}

__global__ __launch_bounds__(256) void loss_final_k(
    const float* __restrict__ partials, float* __restrict__ out01)
{
  __shared__ float red[256];
  int base = blockIdx.x * 8192;
  float s = 0.f;
  for (int i = threadIdx.x; i < 8192; i += 256) s += partials[base + i];
  red[threadIdx.x] = s;
  __syncthreads();
#pragma unroll
  for (int st = 128; st > 0; st >>= 1) {
    if (threadIdx.x < st) red[threadIdx.x] += red[threadIdx.x + st];
    __syncthreads();
  }
  if (threadIdx.x == 0) out01[blockIdx.x] = red[0] * (1.0f / 2097152.0f);
}

// ---------------------------------------------------------------------------
// LSTM v8: like v7 (160 blocks, LDS weights, dataflow counters) but ALL
// cross-block data moves via agent-scope RELAXED atomics (executed at the
// device coherence point) -> flags are RELAXED adds, no wbL2/invL2 fences.
// Ordering: producer's atomic h-stores are vmcnt-drained by the cell's
// trailing __syncthreads (compiler emits full waitcnt before s_barrier)
// before thread0's flag add; consumer's staging loads are agent atomics.
// ---------------------------------------------------------------------------
#define LSTM_NB 160

DEV void gridbar(unsigned* bar, unsigned target) {
  __syncthreads();
  if (threadIdx.x == 0) {
    __hip_atomic_fetch_add(bar, 1u, __ATOMIC_RELEASE, __HIP_MEMORY_SCOPE_AGENT);
    unsigned spins = 0;
    while (__hip_atomic_load(bar, __ATOMIC_RELAXED, __HIP_MEMORY_SCOPE_AGENT) < target) {
      __builtin_amdgcn_s_sleep(2);
      if (++spins > (1u << 24)) break;   // safety valve
    }
    (void)__hip_atomic_load(bar, __ATOMIC_ACQUIRE, __HIP_MEMORY_SCOPE_AGENT);
  }
  __syncthreads();
}

DEV void spin_ge(unsigned* c, unsigned tgt) {
  unsigned spins = 0;
  while (__hip_atomic_load(c, __ATOMIC_RELAXED, __HIP_MEMORY_SCOPE_AGENT) < tgt) {
    __builtin_amdgcn_s_sleep(1);
    if (++spins > (1u << 24)) break;     // safety valve
  }
}

__global__ __launch_bounds__(256, 1) void lstm8_k(
    const float* __restrict__ z,              // (1024,256) fp32, row = b*32+t
    const unsigned short* __restrict__ wihb,  // frag-swizzled bf16 (10 layers)
    const unsigned short* __restrict__ whhb,
    const unsigned short* __restrict__ meffb, // frag-swizzled Meff (1 layer)
    const float* __restrict__ bih, const float* __restrict__ bhh,
    const float* __restrict__ beff,
    unsigned short* __restrict__ zbf,     // (16,32,256) bf16 [t][b][k]
    unsigned short* __restrict__ hbf,     // (2,10,32,256) bf16
    unsigned short* __restrict__ h9sav,   // (16,32,256) bf16, slot tt=t-15
    unsigned* __restrict__ bar)           // bar[0]=init barrier; cnt[l]=bar[32+l*32]
{
  __shared__ unsigned short s_w[4 * 2 * 4096]; // 64KB [g][wi/wh][frag 4096]
  __shared__ unsigned short s_x[8192];         // 16KB swizzled [32 rows][32 ch]
  __shared__ unsigned short s_h[8192];         // 16KB
  __shared__ float zsm[4 * 32 * 17];           // [gate][row][col pad17]
  __shared__ float cls[32 * 16];               // c state for this layer
  __shared__ float sbias[64];                  // bih+bhh for this layer [g][j]
  __shared__ float sb2[64];                    // beff+bhh0 [g][j]

  const int tid = threadIdx.x;
  const int bid = blockIdx.x;
  const int l   = bid >> 4;                    // layer 0..9
  const int jg  = bid & 15;
  const int col0 = jg * 16;
  const int lane = tid & 63, g = tid >> 6;     // wave = gate
  const int l15 = lane & 15, l4 = lane >> 4;
  const int gtid = bid * 256 + tid;

  unsigned* cown  = bar + 32 + l * 32;
  unsigned* cprev = bar + 32 + (l - 1) * 32;
  unsigned* cnext = bar + 32 + (l + 1) * 32;
  unsigned* c9    = bar + 32 + 9 * 32;
  unsigned* c0    = bar + 32;

  // ---- init: zbf transpose+bf16, zero hbf parity 1 (plain; gridbar flushes) ----
  for (int i = gtid; i < 16 * 32 * 256; i += LSTM_NB * 256) {
    int k = i & 255, r = i >> 8;
    int tt = r >> 5, b = r & 31;
    zbf[i] = f2bf(z[(size_t)(b * 32 + tt) * 256 + k]);
  }
  for (int i = gtid; i < 81920; i += LSTM_NB * 256) hbf[81920 + i] = 0;
  // ---- stage this layer's weights into LDS ----
  for (int c = tid; c < 4096; c += 256) {
    int gm = c >> 9;
    int gg = gm >> 1, m = gm & 1;
    int c2 = c & 511;
    const unsigned short* src = (m == 0 ? wihb : whhb)
        + ((size_t)(l * 64 + gg * 16 + jg) * 8) * 512;
    *(int4*)&s_w[(size_t)c * 8] = *(const int4*)&src[(size_t)c2 * 8];
  }
  for (int i = tid; i < 512; i += 256) cls[i] = 0.f;
  if (tid < 64) {
    int gg = tid >> 4, j = tid & 15;
    sbias[tid] = bih[l * 1024 + gg * 256 + col0 + j]
               + bhh[l * 1024 + gg * 256 + col0 + j];
    sb2[tid]   = beff[gg * 256 + col0 + j] + bhh[gg * 256 + col0 + j];
  }

  gridbar(bar, LSTM_NB);   // one global barrier: init staging visible

  auto cell = [&](int t, bool p2) {
    const int cur = t & 1, prv = cur ^ 1;
    const bool p2l0 = p2 && (l == 0);
    const unsigned short* xb =
        (l == 0) ? (p2 ? (hbf + (size_t)((prv * 10 + 9) * 32) * 256)
                       : (zbf + (size_t)t * 32 * 256))
                 : (hbf + (size_t)((cur * 10 + l - 1) * 32) * 256);
    const unsigned short* hb = hbf + (size_t)((prv * 10 + l) * 32) * 256;
    // ---- stage x,h -> LDS via agent-relaxed atomic loads (bypass stale L2) ----
#pragma unroll
    for (int i = 0; i < 4; ++i) {
      int c = tid + i * 256;                     // chunk 0..1023 (16B chunks)
      int sw = (c & ~31) | ((c & 31) ^ ((c >> 5) & 7));
      const unsigned* xw = (const unsigned*)xb + (size_t)c * 4;
      const unsigned* hw = (const unsigned*)hb + (size_t)c * 4;
      uint4 xv = { aload(xw + 0), aload(xw + 1), aload(xw + 2), aload(xw + 3) };
      uint4 hv = { aload(hw + 0), aload(hw + 1), aload(hw + 2), aload(hw + 3) };
      *(uint4*)&s_x[(size_t)sw * 8] = xv;
      *(uint4*)&s_h[(size_t)sw * 8] = hv;
    }
    __syncthreads();
    // ---- MFMA: 4 chains of 8, frags from LDS ----
    f4_t a0 = {}, a1 = {}, b0 = {}, b1 = {};
#pragma unroll
    for (int ks = 0; ks < 8; ++ks) {
      bf8_t bwi = *(const bf8_t*)&s_w[(size_t)((g * 2 + 0) * 4096 + ks * 512 + lane * 8)];
      bf8_t bwh = *(const bf8_t*)&s_w[(size_t)((g * 2 + 1) * 4096 + ks * 512 + lane * 8)];
      int cx0 = (l15 << 5) | ((ks * 4 + l4) ^ (l15 & 7));
      int cx1 = ((16 + l15) << 5) | ((ks * 4 + l4) ^ (l15 & 7));
      bf8_t ax0 = *(const bf8_t*)&s_x[(size_t)cx0 * 8];
      bf8_t ax1 = *(const bf8_t*)&s_x[(size_t)cx1 * 8];
      bf8_t ah0 = *(const bf8_t*)&s_h[(size_t)cx0 * 8];
      bf8_t ah1 = *(const bf8_t*)&s_h[(size_t)cx1 * 8];
      a0 = __builtin_amdgcn_mfma_f32_16x16x32_bf16(ax0, bwi, a0, 0, 0, 0);
      a1 = __builtin_amdgcn_mfma_f32_16x16x32_bf16(ax1, bwi, a1, 0, 0, 0);
      b0 = __builtin_amdgcn_mfma_f32_16x16x32_bf16(ah0, bwh, b0, 0, 0, 0);
      b1 = __builtin_amdgcn_mfma_f32_16x16x32_bf16(ah1, bwh, b1, 0, 0, 0);
    }
#pragma unroll
    for (int r = 0; r < 4; ++r) {
      zsm[(g * 32 + l4 * 4 + r) * 17 + l15] = a0[r] + b0[r];
      zsm[(g * 32 + 16 + l4 * 4 + r) * 17 + l15] = a1[r] + b1[r];
    }
    __syncthreads();
    // ---- gate math: 512 elems, 2/thread; packed agent-atomic h store ----
#pragma unroll
    for (int half = 0; half < 2; ++half) {
      int e = tid + half * 256;
      int b = e >> 4, j = e & 15;
      float zi = zsm[(0 * 32 + b) * 17 + j] + (p2l0 ? sb2[j]      : sbias[j]);
      float zf = zsm[(1 * 32 + b) * 17 + j] + (p2l0 ? sb2[16 + j] : sbias[16 + j]);
      float zg = zsm[(2 * 32 + b) * 17 + j] + (p2l0 ? sb2[32 + j] : sbias[32 + j]);
      float zo = zsm[(3 * 32 + b) * 17 + j] + (p2l0 ? sb2[48 + j] : sbias[48 + j]);
      float cold = cls[b * 16 + j];
      float cn = sigm_f(zf) * cold + sigm_f(zi) * tanhf(zg);
      cls[b * 16 + j] = cn;
      float hn = sigm_f(zo) * tanhf(cn);
      float hn_hi = __shfl_down(hn, 1);
      if (!(j & 1)) {
        unsigned pk = (unsigned)f2bf(hn) | ((unsigned)f2bf(hn_hi) << 16);
        astore((unsigned*)&hbf[(size_t)((cur * 10 + l) * 32 + b) * 256 + col0 + j], pk);
      }
      if (l == 9 && t >= 15)
        h9sav[(size_t)((t - 15) * 32 + b) * 256 + col0 + j] = f2bf(hn);
    }
    __syncthreads();   // drains all waves' atomic stores (vmcnt) before flag
  };

  for (int t = 0; t <= 30; ++t) {
    // ---- dataflow waits (thread0 polls relaxed; block joins at barrier) ----
    if (tid == 0) {
      if (l == 0) {
        if (t >= 16) spin_ge(c9, 16u * t);
      } else {
        spin_ge(cprev, 16u * (t + 1));
      }
      if (t >= 2) {
        if (l < 9) spin_ge(cnext, 16u * (t - 1));
        else if (t >= 17) spin_ge(c0, 16u * t);
      }
    }
    __syncthreads();
    cell(t, t >= 16);
    if (tid == 0)
      __hip_atomic_fetch_add(cown, 1u, __ATOMIC_RELAXED, __HIP_MEMORY_SCOPE_AGENT);
    // ---- l=0: hot-swap wi LDS region -> Meff between t=15 and t=16 ----
    if (l == 0 && t == 15) {
      for (int c = tid; c < 2048; c += 256) {
        int gg = c >> 9, c2 = c & 511;
        const unsigned short* src = meffb + ((size_t)(gg * 16 + jg) * 8) * 512;
        *(int4*)&s_w[(size_t)((gg * 2) * 512 + c2) * 8] = *(const int4*)&src[(size_t)c2 * 8];
      }
      __syncthreads();
    }
  }
}

// ---------------------------------------------------------------------------
// Decoder input gather -> bf16: rows 0..511 = y_t, rows 512..1023 = z_x
// ---------------------------------------------------------------------------
__global__ __launch_bounds__(256) void gather_dec_k(
    const float* __restrict__ outs, const float* __restrict__ z,
    unsigned short* __restrict__ ydec)
{
  int idx = blockIdx.x * 256 + threadIdx.x;   // < 262144
  int rrow = idx >> 8, k = idx & 255;
  float v;
  if (rrow < 512) {
    int b = rrow >> 4, i = rrow & 15;
    v = outs[(size_t)((15 + i) * 32 + b) * 256 + k];
  } else {
    int rr = rrow - 512;
    int b = rr >> 4, tt = rr & 15;
    v = z[(size_t)(b * 32 + tt) * 256 + k];
  }
  ydec[idx] = f2bf(v);
}

// ---------------------------------------------------------------------------
extern "C" void kernel_launch(void* const* d_in, const int* in_sizes, int n_in,
                              void* d_out, int out_size, void* d_ws, size_t ws_size,
                              hipStream_t stream) {
  const float* x     = (const float*)d_in[0];
  const float* t     = (const float*)d_in[1];
  const float* ec1_w = (const float*)d_in[2];
  const float* ec1_b = (const float*)d_in[3];
  const float* ec2_w = (const float*)d_in[4];
  const float* ec2_b = (const float*)d_in[5];
  const float* ec3_w = (const float*)d_in[6];
  const float* ec3_b = (const float*)d_in[7];
  const float* ec4_w = (const float*)d_in[8];
  const float* ec4_b = (const float*)d_in[9];
  const float* ec5_w = (const float*)d_in[10];
  const float* ec5_b = (const float*)d_in[11];
  const float* el_w  = (const float*)d_in[12];
  const float* el_b  = (const float*)d_in[13];
  const float* dl_w  = (const float*)d_in[14];
  const float* dl_b  = (const float*)d_in[15];
  const float* dt1_w = (const float*)d_in[16];
  const float* dt1_b = (const float*)d_in[17];
  const float* dc1_w = (const float*)d_in[18];
  const float* dc1_b = (const float*)d_in[19];
  const float* dt2_w = (const float*)d_in[20];
  const float* dt2_b = (const float*)d_in[21];
  const float* dc2_w = (const float*)d_in[22];
  const float* dc2_b = (const float*)d_in[23];
  const float* dt3_w = (const float*)d_in[24];
  const float* dt3_b = (const float*)d_in[25];
  const float* Wih   = (const float*)d_in[26];
  const float* Whh   = (const float*)d_in[27];
  const float* bih   = (const float*)d_in[28];
  const float* bhh   = (const float*)d_in[29];
  const float* lw    = (const float*)d_in[30];
  const float* lb    = (const float*)d_in[31];
  float* out = (float*)d_out;

  char* base = (char*)d_ws;
  size_t off = 0;
  auto alloc = [&](size_t bytes) -> char* {
    char* p = base + off;
    off += (bytes + 255) & ~(size_t)255;
    return p;
  };
  typedef unsigned short us;
  unsigned* bar   = (unsigned*)alloc(4096);
  float* zbuf     = (float*)alloc((size_t)1024 * 256 * 4);
  float* outsbuf  = (float*)alloc((size_t)31 * 32 * 256 * 4);
  us*    zbf      = (us*)alloc((size_t)16 * 32 * 256 * 2);
  us*    hbf      = (us*)alloc((size_t)2 * 10 * 32 * 256 * 2);
  us*    h9sav    = (us*)alloc((size_t)16 * 32 * 256 * 2);
  us*    ydec     = (us*)alloc((size_t)1024 * 256 * 2);
  float* partials = (float*)alloc((size_t)16384 * 4);
  us* wb_ec2 = (us*)alloc((size_t)32 * 288 * 2);
  us* wb_ec3 = (us*)alloc((size_t)64 * 288 * 2);
  us* wb_ec4 = (us*)alloc((size_t)64 * 576 * 2);
  us* wb_ec5 = (us*)alloc((size_t)64 * 576 * 2);
  us* wbp_dt1 = (us*)alloc((size_t)64 * 576 * 2);
  us* wb_dc1 = (us*)alloc((size_t)64 * 576 * 2);
  us* wbp_dt2 = (us*)alloc((size_t)32 * 576 * 2);
  us* wb_dc2 = (us*)alloc((size_t)32 * 288 * 2);
  us* elWb   = (us*)alloc((size_t)256 * 4096 * 2);
  us* dlWb   = (us*)alloc((size_t)4096 * 256 * 2);
  us* wihb   = (us*)alloc((size_t)10 * 1024 * 256 * 2);      // 5 MB
  us* whhb   = (us*)alloc((size_t)10 * 1024 * 256 * 2);      // 5 MB
  us* wih0b  = (us*)alloc((size_t)1024 * 256 * 2);
  us* lwTb   = (us*)alloc((size_t)256 * 256 * 2);
  us* lwbp   = (us*)alloc((size_t)256 * 256 * 2);
  us* meffp  = (us*)alloc((size_t)1024 * 256 * 2);
  us* meffb  = (us*)alloc((size_t)1024 * 256 * 2);
  float* beff = (float*)alloc((size_t)1024 * 4);
  us* enc5   = (us*)alloc((size_t)1024 * 4096 * 2);          // 8.4 MB
  us* bufA   = (us*)alloc((size_t)1024 * 32 * 32 * 32 * 2);  // 67 MB
  us* bufB   = (us*)alloc((size_t)1024 * 32 * 32 * 32 * 2);  // 67 MB
  (void)in_sizes; (void)n_in; (void)out_size; (void)ws_size;

  hipMemsetAsync(bar, 0, 4096, stream);

  // ---- weight prep ----
  prepw_k<<<(32*32*9+255)/256, 256, 0, stream>>>(ec2_w, wb_ec2, 32, 32);
  prepw_k<<<(64*32*9+255)/256, 256, 0, stream>>>(ec3_w, wb_ec3, 64, 32);
  prepw_k<<<(64*64*9+255)/256, 256, 0, stream>>>(ec4_w, wb_ec4, 64, 64);
  prepw_k<<<(64*64*9+255)/256, 256, 0, stream>>>(ec5_w, wb_ec5, 64, 64);
  prepw_par_k<<<(64*64*9+255)/256, 256, 0, stream>>>(dt1_w, wbp_dt1, 64, 64);
  prepw_k<<<(64*64*9+255)/256, 256, 0, stream>>>(dc1_w, wb_dc1, 64, 64);
  prepw_par_k<<<(32*64*9+255)/256, 256, 0, stream>>>(dt2_w, wbp_dt2, 32, 64);
  prepw_k<<<(32*32*9+255)/256, 256, 0, stream>>>(dc2_w, wb_dc2, 32, 32);
  prep_el_k<<<4096, 256, 0, stream>>>(el_w, elWb);
  prep_dl_k<<<4096, 256, 0, stream>>>(dl_w, dlWb);
  prep_wlstm_k<<<10240, 256, 0, stream>>>(Wih, wihb);
  prep_wlstm_k<<<10240, 256, 0, stream>>>(Whh, whhb);
  // Meff = Wih0 @ lw (1024x256), beff = Wih0 @ lb + bih0
  cast_bf16_k<<<1024, 256, 0, stream>>>(Wih, wih0b, 262144);
  prep_lwt_k<<<256, 256, 0, stream>>>(lw, lwTb);
  cast_bf16_k<<<256, 256, 0, stream>>>(lw, lwbp, 65536);
  gemm16_k<2, false, true><<<dim3(4, 16), 256, 0, stream>>>(wih0b, lwTb, lb, meffp, 1024, 256, 256);
  prep_wl1_k<<<1024, 256, 0, stream>>>(meffp, meffb);
  beff_k<<<4, 256, 0, stream>>>(Wih, lb, bih, beff);

  // ---- encoder: single 1024-image pass ----
  ec1_k<<<4096, 256, 0, stream>>>(x, t, ec1_w, ec1_b, bufA);
  convmf_k<32, 32, 32, 32, 32, 32, 0><<<1024, 256, 0, stream>>>(bufA, wb_ec2, ec2_b, bufB);
  convmf_k<32, 64, 32, 32, 16, 16, 1><<<1024, 256, 0, stream>>>(bufB, wb_ec3, ec3_b, bufA);
  convmf_k<64, 64, 16, 16, 16, 16, 0><<<1024, 256, 0, stream>>>(bufA, wb_ec4, ec4_b, bufB);
  convmf_k<64, 64, 16, 16, 8, 8, 1><<<1024, 256, 0, stream>>>(bufB, wb_ec5, ec5_b, enc5);
  gemm16_k<0, false, false><<<dim3(4, 16), 256, 0, stream>>>(enc5, elWb, el_b, zbuf, 1024, 256, 4096);

  // ---- LSTM (MFMA, 160 blocks, relaxed-atomic dataflow sync) ----
  lstm8_k<<<LSTM_NB, 256, 0, stream>>>(zbuf, wihb, whhb, meffb, bih, bhh, beff,
                                       zbf, hbf, h9sav, bar);
  // outs[t=15..30] = h9sav @ lw^T + lb
  gemm16_k<0, false, false><<<dim3(4, 8), 256, 0, stream>>>(
      h9sav, lwbp, lb, outsbuf + (size_t)15 * 32 * 256, 512, 256, 256);

  // ---- decoder: single 1024-row pass (rows 0..511 pred, 512..1023 rec) ----
  gather_dec_k<<<1024, 256, 0, stream>>>(outsbuf, zbuf, ydec);
  gemm16_k<1, true, true><<<dim3(64, 16), 256, 0, stream>>>(ydec, dlWb, dl_b, bufB, 1024, 4096, 256);
  tconvp_k<64, 64, 8, 8, 8, 8><<<1024, 256, 0, stream>>>(bufB, wbp_dt1, dt1_b, bufA);
  convmf_k<64, 64, 16, 16, 16, 16, 0><<<1024, 256, 0, stream>>>(bufA, wb_dc1, dc1_b, bufB);
  tconvp_k<64, 32, 16, 16, 8, 16><<<2048, 256, 0, stream>>>(bufB, wbp_dt2, dt2_b, bufA);
  convmf_k<32, 32, 32, 32, 32, 32, 0><<<1024, 256, 0, stream>>>(bufA, wb_dc2, dc2_b, bufB);
  dt3_loss_k<<<16384, 256, 0, stream>>>(bufB, dt3_w, dt3_b, x, t, out + 2, partials);
  loss_final_k<<<2, 256, 0, stream>>>(partials, out);
}

// Round 10
// 1751.665 us; speedup vs baseline: 1.6133x; 1.0533x over previous
//
#include <hip/hip_runtime.h>
#include <math.h>

#define DEV __device__ __forceinline__

typedef __attribute__((ext_vector_type(8))) short bf8_t;   // 8 x bf16 (4 VGPR)
typedef __attribute__((ext_vector_type(4))) float f4_t;    // MFMA acc

DEV float gelu_f(float v) { return 0.5f * v * (1.0f + erff(v * 0.70710678118654752f)); }
DEV float sigm_f(float v) { return 1.0f / (1.0f + expf(-v)); }
DEV unsigned short f2bf(float f) {            // RNE float->bf16
  unsigned u = __float_as_uint(f);
  u = (u + 0x7FFFu + ((u >> 16) & 1u)) >> 16;
  return (unsigned short)u;
}
DEV float bf2f(unsigned short u) { return __uint_as_float((unsigned)u << 16); }

// ---------------------------------------------------------------------------
// Fused conv-weight prep: 8 tensors in one launch.
// normal: wb[co][tap][ci] from w[co][ci][kh][kw]
// par   : wbp[co][ti][ci] from w[ci][co][2-kh][2-kw], TAPORD parity order
// ---------------------------------------------------------------------------
DEV void prep_norm(int li, const float* w, unsigned short* wb, int CIN) {
  int ci = li % CIN;
  int r  = li / CIN;
  int kw = r % 3; r /= 3;
  int kh = r % 3;
  int co = r / 3;
  wb[li] = f2bf(w[((co * CIN + ci) * 3 + kh) * 3 + kw]);
}
DEV void prep_par(int li, const float* w, unsigned short* wb, int COUT, int CIN) {
  const int TAPORD[9] = {4, 3, 5, 1, 7, 0, 2, 6, 8};
  int ci = li % CIN;
  int r  = li / CIN;
  int ti = r % 9;
  int co = r / 9;
  int tap = TAPORD[ti];
  int kh = tap / 3, kw = tap % 3;
  wb[li] = f2bf(w[((ci * COUT + co) * 3 + (2 - kh)) * 3 + (2 - kw)]);
}

__global__ __launch_bounds__(256) void prepw_all_k(
    const float* __restrict__ ec2, const float* __restrict__ ec3,
    const float* __restrict__ ec4, const float* __restrict__ ec5,
    const float* __restrict__ dt1, const float* __restrict__ dc1,
    const float* __restrict__ dt2, const float* __restrict__ dc2,
    unsigned short* __restrict__ o_ec2, unsigned short* __restrict__ o_ec3,
    unsigned short* __restrict__ o_ec4, unsigned short* __restrict__ o_ec5,
    unsigned short* __restrict__ o_dt1, unsigned short* __restrict__ o_dc1,
    unsigned short* __restrict__ o_dt2, unsigned short* __restrict__ o_dc2)
{
  int idx = blockIdx.x * 256 + threadIdx.x;            // < 202752
  if (idx < 9216)        prep_norm(idx,          ec2, o_ec2, 32);
  else if (idx < 27648)  prep_norm(idx - 9216,   ec3, o_ec3, 32);
  else if (idx < 64512)  prep_norm(idx - 27648,  ec4, o_ec4, 64);
  else if (idx < 101376) prep_norm(idx - 64512,  ec5, o_ec5, 64);
  else if (idx < 138240) prep_par (idx - 101376, dt1, o_dt1, 64, 64);
  else if (idx < 175104) prep_norm(idx - 138240, dc1, o_dc1, 64);
  else if (idx < 193536) prep_par (idx - 175104, dt2, o_dt2, 32, 64);
  else if (idx < 202752) prep_norm(idx - 193536, dc2, o_dc2, 32);
}

// misc prep: cast Wih->bf16, lwT, cast lw, beff
__global__ __launch_bounds__(256) void prep_misc_k(
    const float* __restrict__ Wih, const float* __restrict__ lw,
    const float* __restrict__ lb,  const float* __restrict__ bih,
    unsigned short* __restrict__ wih0b, unsigned short* __restrict__ lwTb,
    unsigned short* __restrict__ lwbp,  float* __restrict__ beff)
{
  int idx = blockIdx.x * 256 + threadIdx.x;            // < 394240
  if (idx < 262144) {
    wih0b[idx] = f2bf(Wih[idx]);
  } else if (idx < 327680) {
    int i = idx - 262144;
    int n = i & 255, kcol = i >> 8;
    lwTb[i] = f2bf(lw[(size_t)n * 256 + kcol]);
  } else if (idx < 393216) {
    int i = idx - 327680;
    lwbp[i] = f2bf(lw[i]);
  } else if (idx < 394240) {
    int j = idx - 393216;
    float s = bih[j];
    const float* row = Wih + (size_t)j * 256;
    for (int n = 0; n < 256; ++n) s = fmaf(row[n], lb[n], s);
    beff[j] = s;
  }
}

// el_w (256,4096 k_ref=c*64+s) -> bf16 [n][k_new=(s*64+c)]
__global__ __launch_bounds__(256) void prep_el_k(
    const float* __restrict__ w, unsigned short* __restrict__ wb)
{
  int idx = blockIdx.x * 256 + threadIdx.x;     // < 256*4096
  int kn = idx & 4095, n = idx >> 12;
  wb[idx] = f2bf(w[(size_t)n * 4096 + ((kn & 63) * 64 + (kn >> 6))]);
}

// dl_w (4096,256) row r=c*64+s -> bf16 rows nout=s*64+c
__global__ __launch_bounds__(256) void prep_dl_k(
    const float* __restrict__ w, unsigned short* __restrict__ wb)
{
  int idx = blockIdx.x * 256 + threadIdx.x;     // < 4096*256
  int k = idx & 255, nout = idx >> 8;
  wb[idx] = f2bf(w[(size_t)((nout & 63) * 64 + (nout >> 6)) * 256 + k]);
}

// LSTM weights (10,1024,256) -> bf16 frag-contiguous
__global__ __launch_bounds__(256) void prep_wlstm_k(
    const float* __restrict__ w, unsigned short* __restrict__ wb)
{
  int idx = blockIdx.x * 256 + threadIdx.x;   // exactly 2621440 = 10240 blocks
  int e = idx & 7, lane = (idx >> 3) & 63, ks = (idx >> 9) & 7;
  int nt = (idx >> 12) & 63, l = idx >> 18;
  wb[idx] = f2bf(w[((size_t)l * 1024 + nt * 16 + (lane & 15)) * 256
                   + ks * 32 + (lane >> 4) * 8 + e]);
}

// single-layer (1024x256) bf16 [j][k] -> frag layout
__global__ __launch_bounds__(256) void prep_wl1_k(
    const unsigned short* __restrict__ src, unsigned short* __restrict__ wb)
{
  int idx = blockIdx.x * 256 + threadIdx.x;   // 262144 = 1024 blocks
  int e = idx & 7, lane = (idx >> 3) & 63, ks = (idx >> 9) & 7, nt = idx >> 12;
  wb[idx] = src[(size_t)(nt * 16 + (lane & 15)) * 256 + ks * 32 + (lane >> 4) * 8 + e];
}

// ---------------------------------------------------------------------------
// ec1: 1ch 64x64 s2 -> 32ch 32x32, NHWC bf16 out. 1024 images.
// ---------------------------------------------------------------------------
__global__ __launch_bounds__(256) void ec1_k(
    const float* __restrict__ x, const float* __restrict__ t,
    const float* __restrict__ w, const float* __restrict__ bias,
    unsigned short* __restrict__ out)
{
  __shared__ float sw[288];
  __shared__ float sb[32];
  for (int i = threadIdx.x; i < 288; i += 256) sw[i] = w[i];
  if (threadIdx.x < 32) sb[threadIdx.x] = bias[threadIdx.x];
  __syncthreads();
  int idx = blockIdx.x * 256 + threadIdx.x;     // < 1024*32*32
  int ox = idx & 31, oy = (idx >> 5) & 31, n = idx >> 10;
  int b = n >> 5, j = n & 31;
  const float* ip = (j < 16) ? (x + (size_t)(b * 16 + j) * 4096)
                             : (t + (size_t)(b * 16 + j - 16) * 4096);
  float pv[9];
#pragma unroll
  for (int kh = 0; kh < 3; ++kh) {
    int iy = oy * 2 + kh - 1;
#pragma unroll
    for (int kw = 0; kw < 3; ++kw) {
      int ix = ox * 2 + kw - 1;
      pv[kh * 3 + kw] = ((unsigned)iy < 64u && (unsigned)ix < 64u) ? ip[iy * 64 + ix] : 0.f;
    }
  }
  unsigned short u[32];
#pragma unroll
  for (int co = 0; co < 32; ++co) {
    float a = sb[co];
#pragma unroll
    for (int i = 0; i < 9; ++i) a = fmaf(pv[i], sw[co * 9 + i], a);
    u[co] = f2bf(gelu_f(a));
  }
  unsigned short* op = out + (size_t)idx * 32;
#pragma unroll
  for (int p = 0; p < 4; ++p) {
    uint4 v;
    v.x = u[p*8+0] | (u[p*8+1] << 16);
    v.y = u[p*8+2] | (u[p*8+3] << 16);
    v.z = u[p*8+4] | (u[p*8+5] << 16);
    v.w = u[p*8+6] | (u[p*8+7] << 16);
    *(uint4*)&op[p * 8] = v;
  }
}

// ---------------------------------------------------------------------------
// MFMA implicit-GEMM conv. NHWC bf16 in/out. MODE: 0=s1, 1=s2.
// ---------------------------------------------------------------------------
template<int CIN, int COUT, int HIN, int WIN, int TH, int TW, int MODE>
__global__ __launch_bounds__(256) void convmf_k(
    const unsigned short* __restrict__ in, const unsigned short* __restrict__ wb,
    const float* __restrict__ bias, unsigned short* __restrict__ out)
{
  constexpr int HO  = (MODE == 1) ? HIN / 2 : HIN;
  constexpr int WO  = (MODE == 1) ? WIN / 2 : WIN;
  constexpr int TIH = (MODE == 1) ? 2 * TH + 1 : TH + 2;
  constexpr int TIW = (MODE == 1) ? 2 * TW + 1 : TW + 2;
  constexpr int CG  = CIN / 8;
  constexpr int K   = 9 * CIN;
  constexpr int KS  = K / 32;
  constexpr int NT  = COUT / 16;
  constexpr int MT  = (TH * TW) / 16;
  constexpr int MPW = MT / 4;
  constexpr int TY  = HO / TH, TX = WO / TW;

  __shared__ unsigned short lds[TIH * TIW * CG * 8];

  const int bid = blockIdx.x;
  const int n = bid / (TY * TX);
  const int trem = bid % (TY * TX);
  const int ty0 = (trem / TX) * TH, tx0 = (trem % TX) * TW;

  constexpr int ENT = TIH * TIW * CG;
  for (int e = threadIdx.x; e < ENT; e += 256) {
    int txx = e % TIW;
    int rr  = e / TIW;
    int cg  = rr % CG;
    int tyy = rr / CG;
    int iy, ix; bool ok;
    if (MODE == 0) {
      iy = ty0 + tyy - 1; ix = tx0 + txx - 1;
      ok = (unsigned)iy < (unsigned)HIN && (unsigned)ix < (unsigned)WIN;
    } else {
      iy = 2 * ty0 + tyy - 1; ix = 2 * tx0 + txx - 1;
      ok = (unsigned)iy < (unsigned)HIN && (unsigned)ix < (unsigned)WIN;
    }
    int4 val = {0, 0, 0, 0};
    if (ok) val = *(const int4*)&in[(((size_t)n * HIN + iy) * WIN + ix) * CIN + cg * 8];
    *(int4*)&lds[(size_t)e * 8] = val;
  }
  __syncthreads();

  const int lane = threadIdx.x & 63, wv = threadIdx.x >> 6;
  const int l15 = lane & 15, l4 = lane >> 4;

  f4_t acc[MPW][NT] = {};
  for (int ks = 0; ks < KS; ++ks) {
    const int tap = (ks * 32) / CIN;
    const int kh = tap / 3, kw = tap % 3;
    const int cb = ((ks * 32) % CIN) / 8 + l4;
    bf8_t bf[NT];
#pragma unroll
    for (int nt = 0; nt < NT; ++nt)
      bf[nt] = *(const bf8_t*)&wb[(size_t)(nt * 16 + l15) * K + ks * 32 + 8 * l4];
#pragma unroll
    for (int mi = 0; mi < MPW; ++mi) {
      int m = (wv * MPW + mi) * 16 + l15;
      int oy = m / TW, ox = m % TW;
      int rt = ((MODE == 1) ? 2 * oy : oy) + kh;
      int ct = ((MODE == 1) ? 2 * ox : ox) + kw;
      bf8_t a = *(const bf8_t*)&lds[(((size_t)rt * CG + cb) * TIW + ct) * 8];
#pragma unroll
      for (int nt = 0; nt < NT; ++nt)
        acc[mi][nt] = __builtin_amdgcn_mfma_f32_16x16x32_bf16(a, bf[nt], acc[mi][nt], 0, 0, 0);
    }
  }

#pragma unroll
  for (int mi = 0; mi < MPW; ++mi) {
    int mbase = (wv * MPW + mi) * 16;
#pragma unroll
    for (int nt = 0; nt < NT; ++nt) {
      int co = nt * 16 + l15;
      float bv = bias[co];
#pragma unroll
      for (int r = 0; r < 4; ++r) {
        int m = mbase + l4 * 4 + r;
        int oy = m / TW, ox = m % TW;
        float v = acc[mi][nt][r] + bv;
        out[(((size_t)n * HO + ty0 + oy) * WO + (tx0 + ox)) * COUT + co] = f2bf(gelu_f(v));
      }
    }
  }
}

// ---------------------------------------------------------------------------
// Parity-decomposed tconv (lhs_dilation=2). Wave = parity.
// ---------------------------------------------------------------------------
template<int CIN, int COUT, int HIN, int WIN, int SH, int SW>
__global__ __launch_bounds__(256) void tconvp_k(
    const unsigned short* __restrict__ in, const unsigned short* __restrict__ wbp,
    const float* __restrict__ bias, unsigned short* __restrict__ out)
{
  constexpr int HO = 2 * HIN, WO = 2 * WIN;
  constexpr int CG = CIN / 8;
  constexpr int TIH = SH + 1, TIW = SW + 1;
  constexpr int NT = COUT / 16;
  constexpr int MPW_P = (SH * SW) / 16;
  constexpr int TY = HIN / SH, TX = WIN / SW;

  __shared__ unsigned short lds[TIH * TIW * CG * 8];

  const int bid = blockIdx.x;
  const int n = bid / (TY * TX);
  const int trem = bid % (TY * TX);
  const int toy = trem / TX, tox = trem % TX;
  const int ty0s = toy * SH, tx0s = tox * SW;

  constexpr int ENT = TIH * TIW * CG;
  for (int e = threadIdx.x; e < ENT; e += 256) {
    int txx = e % TIW;
    int rr  = e / TIW;
    int cg  = rr % CG;
    int tyy = rr / CG;
    int iy = ty0s + tyy, ix = tx0s + txx;
    int4 val = {0, 0, 0, 0};
    if (iy < HIN && ix < WIN)
      val = *(const int4*)&in[(((size_t)n * HIN + iy) * WIN + ix) * CIN + cg * 8];
    *(int4*)&lds[(size_t)((tyy * CG + cg) * TIW + txx) * 8] = val;
  }
  __syncthreads();

  const int lane = threadIdx.x & 63, wv = threadIdx.x >> 6;
  const int l15 = lane & 15, l4 = lane >> 4;
  const int dy = wv >> 1, dx = wv & 1;
  const int NXT = 1 + dx;
  const int KS2 = ((1 + dy) * (1 + dx) * CIN) / 32;
  const int koff = (dy ? (dx ? 5 : 3) : (dx ? 1 : 0)) * CIN;

  f4_t acc[MPW_P][NT] = {};
  for (int ks = 0; ks < KS2; ++ks) {
    const int tapi = (ks * 32) / CIN;
    const int cb = ((ks * 32) % CIN) / 8 + l4;
    const int ra = tapi / NXT, rb = tapi % NXT;
    bf8_t bf[NT];
#pragma unroll
    for (int nt = 0; nt < NT; ++nt)
      bf[nt] = *(const bf8_t*)&wbp[(size_t)(nt * 16 + l15) * 9 * CIN + koff + ks * 32 + 8 * l4];
#pragma unroll
    for (int mi = 0; mi < MPW_P; ++mi) {
      int m = mi * 16 + l15;
      int i = m / SW, j = m % SW;
      bf8_t a = *(const bf8_t*)&lds[(size_t)(((i + ra) * CG + cb) * TIW + (j + rb)) * 8];
#pragma unroll
      for (int nt = 0; nt < NT; ++nt)
        acc[mi][nt] = __builtin_amdgcn_mfma_f32_16x16x32_bf16(a, bf[nt], acc[mi][nt], 0, 0, 0);
    }
  }

#pragma unroll
  for (int mi = 0; mi < MPW_P; ++mi) {
#pragma unroll
    for (int nt = 0; nt < NT; ++nt) {
      int co = nt * 16 + l15;
      float bv = bias[co];
#pragma unroll
      for (int r = 0; r < 4; ++r) {
        int m = mi * 16 + l4 * 4 + r;
        int i = m / SW, j = m % SW;
        int orow = 2 * (ty0s + i) + dy, ocol = 2 * (tx0s + j) + dx;
        float v = acc[mi][nt][r] + bv;
        out[(((size_t)n * HO + orow) * WO + ocol) * COUT + co] = f2bf(gelu_f(v));
      }
    }
  }
}

// ---------------------------------------------------------------------------
// MFMA GEMM: C[m][n] = act(sum_k A[m][k]*B[n][k] + bias).
// BIASMODE: 0 = bias[col], 1 = dl-permuted bias, 2 = no bias.
// ---------------------------------------------------------------------------
template<int BIASMODE, bool GELU, bool OUTBF16>
__global__ __launch_bounds__(256) void gemm16_k(
    const unsigned short* __restrict__ A, const unsigned short* __restrict__ Bw,
    const float* __restrict__ bias, void* __restrict__ Cv, int M, int N, int K)
{
  const int lane = threadIdx.x & 63, wv = threadIdx.x >> 6;
  const int l15 = lane & 15, l4 = lane >> 4;
  const int mbase = blockIdx.y * 64 + wv * 16;
  const int nbase = blockIdx.x * 64;
  f4_t acc[4] = {};
  for (int k0 = 0; k0 < K; k0 += 32) {
    bf8_t a = *(const bf8_t*)&A[(size_t)(mbase + l15) * K + k0 + 8 * l4];
#pragma unroll
    for (int nt = 0; nt < 4; ++nt) {
      bf8_t b = *(const bf8_t*)&Bw[(size_t)(nbase + nt * 16 + l15) * K + k0 + 8 * l4];
      acc[nt] = __builtin_amdgcn_mfma_f32_16x16x32_bf16(a, b, acc[nt], 0, 0, 0);
    }
  }
#pragma unroll
  for (int nt = 0; nt < 4; ++nt) {
    int col = nbase + nt * 16 + l15;
    float bv = 0.f;
    if (BIASMODE == 0) bv = bias[col];
    if (BIASMODE == 1) bv = bias[(col & 63) * 64 + (col >> 6)];
#pragma unroll
    for (int r = 0; r < 4; ++r) {
      int row = mbase + l4 * 4 + r;
      float v = acc[nt][r] + bv;
      if (GELU) v = gelu_f(v);
      if (OUTBF16) ((unsigned short*)Cv)[(size_t)row * N + col] = f2bf(v);
      else         ((float*)Cv)[(size_t)row * N + col] = v;
    }
  }
}

// ---------------------------------------------------------------------------
// dt3 (tconv 32->1) + tanh + fused loss partials. Vectorized uint4 loads,
// wave-shuffle reduction (1 sync).
// ---------------------------------------------------------------------------
__global__ __launch_bounds__(256) void dt3_loss_k(
    const unsigned short* __restrict__ in,
    const float* __restrict__ w, const float* __restrict__ bias,
    const float* __restrict__ xref, const float* __restrict__ tref,
    float* __restrict__ fout, float* __restrict__ partials)
{
  __shared__ float sw[288];
  for (int i = threadIdx.x; i < 288; i += 256) sw[i] = w[i];
  __syncthreads();
  int idx = blockIdx.x * 256 + threadIdx.x;
  int q = idx & 63, p = (idx >> 6) & 63, n = idx >> 12;
  float acc = bias[0];
#pragma unroll
  for (int kh = 0; kh < 3; ++kh) {
    int u = p + kh - 1;
    if (u < 0 || (u & 1) || u >= 64) continue;
#pragma unroll
    for (int kw = 0; kw < 3; ++kw) {
      int v = q + kw - 1;
      if (v < 0 || (v & 1) || v >= 64) continue;
      const uint4* r4 = (const uint4*)(in + (((size_t)n * 32 + (u >> 1)) * 32 + (v >> 1)) * 32);
      int wo = (2 - kh) * 3 + (2 - kw);
#pragma unroll
      for (int q4 = 0; q4 < 4; ++q4) {
        uint4 dv = r4[q4];
        unsigned wr[4] = {dv.x, dv.y, dv.z, dv.w};
#pragma unroll
        for (int h2 = 0; h2 < 4; ++h2) {
          unsigned d2 = wr[h2];
          int c = q4 * 8 + h2 * 2;
          acc = fmaf(__uint_as_float(d2 << 16),         sw[c * 9 + wo], acc);
          acc = fmaf(__uint_as_float(d2 & 0xffff0000u), sw[(c + 1) * 9 + wo], acc);
        }
      }
    }
  }
  float val = tanhf(acc);
  float d;
  int pix = p * 64 + q;
  if (n < 512) {
    fout[(size_t)n * 4096 + pix] = val;
    d = val - tref[(size_t)n * 4096 + pix];
  } else {
    d = val - xref[(size_t)(n - 512) * 4096 + pix];
  }
  float s = d * d;
#pragma unroll
  for (int off = 32; off > 0; off >>= 1) s += __shfl_down(s, off);
  __shared__ float ws4[4];
  if ((threadIdx.x & 63) == 0) ws4[threadIdx.x >> 6] = s;
  __syncthreads();
  if (threadIdx.x == 0) partials[blockIdx.x] = ws4[0] + ws4[1] + ws4[2] + ws4[3];
}

__global__ __launch_bounds__(256) void loss_final_k(
    const float* __restrict__ partials, float* __restrict__ out01)
{
  __shared__ float red[256];
  int base = blockIdx.x * 8192;
  float s = 0.f;
  for (int i = threadIdx.x; i < 8192; i += 256) s += partials[base + i];
  red[threadIdx.x] = s;
  __syncthreads();
#pragma unroll
  for (int st = 128; st > 0; st >>= 1) {
    if (threadIdx.x < st) red[threadIdx.x] += red[threadIdx.x + st];
    __syncthreads();
  }
  if (threadIdx.x == 0) out01[blockIdx.x] = red[0] * (1.0f / 2097152.0f);
}

// ---------------------------------------------------------------------------
// LSTM v9: 160 blocks = (layer l, colgroup jg), LDS-resident weights,
// release/acquire dataflow counters (proven R8 scheme) PLUS sibling guard:
//   before cell t, also wait cnt[l] >= 16*t  (all layer-l blocks done t-1 —
//   needed because h_prev reads ALL columns of own layer; closes the latent
//   race found in the R9 audit; for l=0 it's a true h-recurrence dependency).
// ---------------------------------------------------------------------------
#define LSTM_NB 160

DEV void gridbar(unsigned* bar, unsigned target) {
  __syncthreads();
  if (threadIdx.x == 0) {
    __hip_atomic_fetch_add(bar, 1u, __ATOMIC_RELEASE, __HIP_MEMORY_SCOPE_AGENT);
    unsigned spins = 0;
    while (__hip_atomic_load(bar, __ATOMIC_RELAXED, __HIP_MEMORY_SCOPE_AGENT) < target) {
      __builtin_amdgcn_s_sleep(2);
      if (++spins > (1u << 24)) break;   // safety valve
    }
    (void)__hip_atomic_load(bar, __ATOMIC_ACQUIRE, __HIP_MEMORY_SCOPE_AGENT);
  }
  __syncthreads();
}

DEV void spin_ge(unsigned* c, unsigned tgt) {
  unsigned spins = 0;
  while (__hip_atomic_load(c, __ATOMIC_RELAXED, __HIP_MEMORY_SCOPE_AGENT) < tgt) {
    __builtin_amdgcn_s_sleep(1);
    if (++spins > (1u << 24)) break;     // safety valve
  }
}

__global__ __launch_bounds__(256, 1) void lstm9_k(
    const float* __restrict__ z,              // (1024,256) fp32, row = b*32+t
    const unsigned short* __restrict__ wihb,  // frag-swizzled bf16 (10 layers)
    const unsigned short* __restrict__ whhb,
    const unsigned short* __restrict__ meffb, // frag-swizzled Meff (1 layer)
    const float* __restrict__ bih, const float* __restrict__ bhh,
    const float* __restrict__ beff,
    unsigned short* __restrict__ zbf,     // (16,32,256) bf16 [t][b][k]
    unsigned short* __restrict__ hbf,     // (2,10,32,256) bf16
    unsigned short* __restrict__ h9sav,   // (16,32,256) bf16, slot tt=t-15
    unsigned* __restrict__ bar)           // bar[0]=init barrier; cnt[l]=bar[32+l*32]
{
  __shared__ unsigned short s_w[4 * 2 * 4096]; // 64KB [g][wi/wh][frag 4096]
  __shared__ unsigned short s_x[8192];         // 16KB swizzled [32 rows][32 ch]
  __shared__ unsigned short s_h[8192];         // 16KB
  __shared__ float zsm[4 * 32 * 17];           // [gate][row][col pad17]
  __shared__ float cls[32 * 16];               // c state for this layer
  __shared__ float sbias[64];                  // bih+bhh for this layer [g][j]
  __shared__ float sb2[64];                    // beff+bhh0 [g][j]

  const int tid = threadIdx.x;
  const int bid = blockIdx.x;
  const int l   = bid >> 4;                    // layer 0..9
  const int jg  = bid & 15;
  const int col0 = jg * 16;
  const int lane = tid & 63, g = tid >> 6;     // wave = gate
  const int l15 = lane & 15, l4 = lane >> 4;
  const int gtid = bid * 256 + tid;

  unsigned* cown  = bar + 32 + l * 32;
  unsigned* cprev = bar + 32 + (l - 1) * 32;
  unsigned* cnext = bar + 32 + (l + 1) * 32;
  unsigned* c9    = bar + 32 + 9 * 32;
  unsigned* c0    = bar + 32;

  // ---- init: zbf transpose+bf16, zero hbf parity 1 ----
  for (int i = gtid; i < 16 * 32 * 256; i += LSTM_NB * 256) {
    int k = i & 255, r = i >> 8;
    int tt = r >> 5, b = r & 31;
    zbf[i] = f2bf(z[(size_t)(b * 32 + tt) * 256 + k]);
  }
  for (int i = gtid; i < 81920; i += LSTM_NB * 256) hbf[81920 + i] = 0;
  // ---- stage this layer's weights into LDS ----
  for (int c = tid; c < 4096; c += 256) {
    int gm = c >> 9;
    int gg = gm >> 1, m = gm & 1;
    int c2 = c & 511;
    const unsigned short* src = (m == 0 ? wihb : whhb)
        + ((size_t)(l * 64 + gg * 16 + jg) * 8) * 512;
    *(int4*)&s_w[(size_t)c * 8] = *(const int4*)&src[(size_t)c2 * 8];
  }
  for (int i = tid; i < 512; i += 256) cls[i] = 0.f;
  if (tid < 64) {
    int gg = tid >> 4, j = tid & 15;
    sbias[tid] = bih[l * 1024 + gg * 256 + col0 + j]
               + bhh[l * 1024 + gg * 256 + col0 + j];
    sb2[tid]   = beff[gg * 256 + col0 + j] + bhh[gg * 256 + col0 + j];
  }

  gridbar(bar, LSTM_NB);   // one global barrier: init staging visible

  auto cell = [&](int t, bool p2) {
    const int cur = t & 1, prv = cur ^ 1;
    const bool p2l0 = p2 && (l == 0);
    const unsigned short* xb =
        (l == 0) ? (p2 ? (hbf + (size_t)((prv * 10 + 9) * 32) * 256)
                       : (zbf + (size_t)t * 32 * 256))
                 : (hbf + (size_t)((cur * 10 + l - 1) * 32) * 256);
    const unsigned short* hb = hbf + (size_t)((prv * 10 + l) * 32) * 256;
    // ---- stage x,h -> LDS (XOR-swizzled), 4+4 parallel 16B loads/thread ----
#pragma unroll
    for (int i = 0; i < 4; ++i) {
      int c = tid + i * 256;                     // chunk 0..1023
      int sw = (c & ~31) | ((c & 31) ^ ((c >> 5) & 7));
      *(int4*)&s_x[(size_t)sw * 8] = *(const int4*)&xb[(size_t)c * 8];
      *(int4*)&s_h[(size_t)sw * 8] = *(const int4*)&hb[(size_t)c * 8];
    }
    __syncthreads();
    // ---- MFMA: 4 chains of 8, frags from LDS ----
    f4_t a0 = {}, a1 = {}, b0 = {}, b1 = {};
#pragma unroll
    for (int ks = 0; ks < 8; ++ks) {
      bf8_t bwi = *(const bf8_t*)&s_w[(size_t)((g * 2 + 0) * 4096 + ks * 512 + lane * 8)];
      bf8_t bwh = *(const bf8_t*)&s_w[(size_t)((g * 2 + 1) * 4096 + ks * 512 + lane * 8)];
      int cx0 = (l15 << 5) | ((ks * 4 + l4) ^ (l15 & 7));
      int cx1 = ((16 + l15) << 5) | ((ks * 4 + l4) ^ (l15 & 7));
      bf8_t ax0 = *(const bf8_t*)&s_x[(size_t)cx0 * 8];
      bf8_t ax1 = *(const bf8_t*)&s_x[(size_t)cx1 * 8];
      bf8_t ah0 = *(const bf8_t*)&s_h[(size_t)cx0 * 8];
      bf8_t ah1 = *(const bf8_t*)&s_h[(size_t)cx1 * 8];
      a0 = __builtin_amdgcn_mfma_f32_16x16x32_bf16(ax0, bwi, a0, 0, 0, 0);
      a1 = __builtin_amdgcn_mfma_f32_16x16x32_bf16(ax1, bwi, a1, 0, 0, 0);
      b0 = __builtin_amdgcn_mfma_f32_16x16x32_bf16(ah0, bwh, b0, 0, 0, 0);
      b1 = __builtin_amdgcn_mfma_f32_16x16x32_bf16(ah1, bwh, b1, 0, 0, 0);
    }
#pragma unroll
    for (int r = 0; r < 4; ++r) {
      zsm[(g * 32 + l4 * 4 + r) * 17 + l15] = a0[r] + b0[r];
      zsm[(g * 32 + 16 + l4 * 4 + r) * 17 + l15] = a1[r] + b1[r];
    }
    __syncthreads();
    // ---- gate math: 512 elems, 2/thread ----
#pragma unroll
    for (int half = 0; half < 2; ++half) {
      int e = tid + half * 256;
      int b = e >> 4, j = e & 15;
      float zi = zsm[(0 * 32 + b) * 17 + j] + (p2l0 ? sb2[j]      : sbias[j]);
      float zf = zsm[(1 * 32 + b) * 17 + j] + (p2l0 ? sb2[16 + j] : sbias[16 + j]);
      float zg = zsm[(2 * 32 + b) * 17 + j] + (p2l0 ? sb2[32 + j] : sbias[32 + j]);
      float zo = zsm[(3 * 32 + b) * 17 + j] + (p2l0 ? sb2[48 + j] : sbias[48 + j]);
      float cold = cls[b * 16 + j];
      float cn = sigm_f(zf) * cold + sigm_f(zi) * tanhf(zg);
      cls[b * 16 + j] = cn;
      float hn = sigm_f(zo) * tanhf(cn);
      unsigned short hv = f2bf(hn);
      hbf[(size_t)((cur * 10 + l) * 32 + b) * 256 + col0 + j] = hv;
      if (l == 9 && t >= 15) h9sav[(size_t)((t - 15) * 32 + b) * 256 + col0 + j] = hv;
    }
    __syncthreads();   // drains stores before the release flag add
  };

  for (int t = 0; t <= 30; ++t) {
    // ---- dataflow waits (thread0 polls; single acquire; block joins) ----
    if (tid == 0) {
      spin_ge(cown, 16u * t);                         // siblings done t-1
      if (l == 0) {
        if (t >= 16) spin_ge(c9, 16u * t);
      } else {
        spin_ge(cprev, 16u * (t + 1));
      }
      if (t >= 2) {
        if (l < 9) spin_ge(cnext, 16u * (t - 1));
        else if (t >= 17) spin_ge(c0, 16u * t);
      }
      (void)__hip_atomic_load(cown, __ATOMIC_ACQUIRE, __HIP_MEMORY_SCOPE_AGENT);
    }
    __syncthreads();
    cell(t, t >= 16);
    if (tid == 0)
      __hip_atomic_fetch_add(cown, 1u, __ATOMIC_RELEASE, __HIP_MEMORY_SCOPE_AGENT);
    // ---- l=0: hot-swap wi LDS region -> Meff between t=15 and t=16 ----
    if (l == 0 && t == 15) {
      for (int c = tid; c < 2048; c += 256) {
        int gg = c >> 9, c2 = c & 511;
        const unsigned short* src = meffb + ((size_t)(gg * 16 + jg) * 8) * 512;
        *(int4*)&s_w[(size_t)((gg * 2) * 512 + c2) * 8] = *(const int4*)&src[(size_t)c2 * 8];
      }
      __syncthreads();
    }
  }
}

// ---------------------------------------------------------------------------
// Decoder input gather -> bf16: rows 0..511 = y_t, rows 512..1023 = z_x
// ---------------------------------------------------------------------------
__global__ __launch_bounds__(256) void gather_dec_k(
    const float* __restrict__ outs, const float* __restrict__ z,
    unsigned short* __restrict__ ydec)
{
  int idx = blockIdx.x * 256 + threadIdx.x;   // < 262144
  int rrow = idx >> 8, k = idx & 255;
  float v;
  if (rrow < 512) {
    int b = rrow >> 4, i = rrow & 15;
    v = outs[(size_t)((15 + i) * 32 + b) * 256 + k];
  } else {
    int rr = rrow - 512;
    int b = rr >> 4, tt = rr & 15;
    v = z[(size_t)(b * 32 + tt) * 256 + k];
  }
  ydec[idx] = f2bf(v);
}

// ---------------------------------------------------------------------------
extern "C" void kernel_launch(void* const* d_in, const int* in_sizes, int n_in,
                              void* d_out, int out_size, void* d_ws, size_t ws_size,
                              hipStream_t stream) {
  const float* x     = (const float*)d_in[0];
  const float* t     = (const float*)d_in[1];
  const float* ec1_w = (const float*)d_in[2];
  const float* ec1_b = (const float*)d_in[3];
  const float* ec2_w = (const float*)d_in[4];
  const float* ec2_b = (const float*)d_in[5];
  const float* ec3_w = (const float*)d_in[6];
  const float* ec3_b = (const float*)d_in[7];
  const float* ec4_w = (const float*)d_in[8];
  const float* ec4_b = (const float*)d_in[9];
  const float* ec5_w = (const float*)d_in[10];
  const float* ec5_b = (const float*)d_in[11];
  const float* el_w  = (const float*)d_in[12];
  const float* el_b  = (const float*)d_in[13];
  const float* dl_w  = (const float*)d_in[14];
  const float* dl_b  = (const float*)d_in[15];
  const float* dt1_w = (const float*)d_in[16];
  const float* dt1_b = (const float*)d_in[17];
  const float* dc1_w = (const float*)d_in[18];
  const float* dc1_b = (const float*)d_in[19];
  const float* dt2_w = (const float*)d_in[20];
  const float* dt2_b = (const float*)d_in[21];
  const float* dc2_w = (const float*)d_in[22];
  const float* dc2_b = (const float*)d_in[23];
  const float* dt3_w = (const float*)d_in[24];
  const float* dt3_b = (const float*)d_in[25];
  const float* Wih   = (const float*)d_in[26];
  const float* Whh   = (const float*)d_in[27];
  const float* bih   = (const float*)d_in[28];
  const float* bhh   = (const float*)d_in[29];
  const float* lw    = (const float*)d_in[30];
  const float* lb    = (const float*)d_in[31];
  float* out = (float*)d_out;

  char* base = (char*)d_ws;
  size_t off = 0;
  auto alloc = [&](size_t bytes) -> char* {
    char* p = base + off;
    off += (bytes + 255) & ~(size_t)255;
    return p;
  };
  typedef unsigned short us;
  unsigned* bar   = (unsigned*)alloc(4096);
  float* zbuf     = (float*)alloc((size_t)1024 * 256 * 4);
  float* outsbuf  = (float*)alloc((size_t)31 * 32 * 256 * 4);
  us*    zbf      = (us*)alloc((size_t)16 * 32 * 256 * 2);
  us*    hbf      = (us*)alloc((size_t)2 * 10 * 32 * 256 * 2);
  us*    h9sav    = (us*)alloc((size_t)16 * 32 * 256 * 2);
  us*    ydec     = (us*)alloc((size_t)1024 * 256 * 2);
  float* partials = (float*)alloc((size_t)16384 * 4);
  us* wb_ec2 = (us*)alloc((size_t)32 * 288 * 2);
  us* wb_ec3 = (us*)alloc((size_t)64 * 288 * 2);
  us* wb_ec4 = (us*)alloc((size_t)64 * 576 * 2);
  us* wb_ec5 = (us*)alloc((size_t)64 * 576 * 2);
  us* wbp_dt1 = (us*)alloc((size_t)64 * 576 * 2);
  us* wb_dc1 = (us*)alloc((size_t)64 * 576 * 2);
  us* wbp_dt2 = (us*)alloc((size_t)32 * 576 * 2);
  us* wb_dc2 = (us*)alloc((size_t)32 * 288 * 2);
  us* elWb   = (us*)alloc((size_t)256 * 4096 * 2);
  us* dlWb   = (us*)alloc((size_t)4096 * 256 * 2);
  us* wihb   = (us*)alloc((size_t)10 * 1024 * 256 * 2);      // 5 MB
  us* whhb   = (us*)alloc((size_t)10 * 1024 * 256 * 2);      // 5 MB
  us* wih0b  = (us*)alloc((size_t)1024 * 256 * 2);
  us* lwTb   = (us*)alloc((size_t)256 * 256 * 2);
  us* lwbp   = (us*)alloc((size_t)256 * 256 * 2);
  us* meffp  = (us*)alloc((size_t)1024 * 256 * 2);
  us* meffb  = (us*)alloc((size_t)1024 * 256 * 2);
  float* beff = (float*)alloc((size_t)1024 * 4);
  us* enc5   = (us*)alloc((size_t)1024 * 4096 * 2);          // 8.4 MB
  us* bufA   = (us*)alloc((size_t)1024 * 32 * 32 * 32 * 2);  // 67 MB
  us* bufB   = (us*)alloc((size_t)1024 * 32 * 32 * 32 * 2);  // 67 MB
  (void)in_sizes; (void)n_in; (void)out_size; (void)ws_size;

  hipMemsetAsync(bar, 0, 4096, stream);

  // ---- weight prep (fused) ----
  prepw_all_k<<<792, 256, 0, stream>>>(ec2_w, ec3_w, ec4_w, ec5_w,
                                       dt1_w, dc1_w, dt2_w, dc2_w,
                                       wb_ec2, wb_ec3, wb_ec4, wb_ec5,
                                       wbp_dt1, wb_dc1, wbp_dt2, wb_dc2);
  prep_misc_k<<<1540, 256, 0, stream>>>(Wih, lw, lb, bih, wih0b, lwTb, lwbp, beff);
  prep_el_k<<<4096, 256, 0, stream>>>(el_w, elWb);
  prep_dl_k<<<4096, 256, 0, stream>>>(dl_w, dlWb);
  prep_wlstm_k<<<10240, 256, 0, stream>>>(Wih, wihb);
  prep_wlstm_k<<<10240, 256, 0, stream>>>(Whh, whhb);
  // Meff = Wih0 @ lw (1024x256)
  gemm16_k<2, false, true><<<dim3(4, 16), 256, 0, stream>>>(wih0b, lwTb, lb, meffp, 1024, 256, 256);
  prep_wl1_k<<<1024, 256, 0, stream>>>(meffp, meffb);

  // ---- encoder: single 1024-image pass ----
  ec1_k<<<4096, 256, 0, stream>>>(x, t, ec1_w, ec1_b, bufA);
  convmf_k<32, 32, 32, 32, 32, 32, 0><<<1024, 256, 0, stream>>>(bufA, wb_ec2, ec2_b, bufB);
  convmf_k<32, 64, 32, 32, 16, 16, 1><<<1024, 256, 0, stream>>>(bufB, wb_ec3, ec3_b, bufA);
  convmf_k<64, 64, 16, 16, 16, 16, 0><<<1024, 256, 0, stream>>>(bufA, wb_ec4, ec4_b, bufB);
  convmf_k<64, 64, 16, 16, 8, 8, 1><<<1024, 256, 0, stream>>>(bufB, wb_ec5, ec5_b, enc5);
  gemm16_k<0, false, false><<<dim3(4, 16), 256, 0, stream>>>(enc5, elWb, el_b, zbuf, 1024, 256, 4096);

  // ---- LSTM (MFMA, 160 blocks, dataflow sync + sibling guard) ----
  lstm9_k<<<LSTM_NB, 256, 0, stream>>>(zbuf, wihb, whhb, meffb, bih, bhh, beff,
                                       zbf, hbf, h9sav, bar);
  // outs[t=15..30] = h9sav @ lw^T + lb
  gemm16_k<0, false, false><<<dim3(4, 8), 256, 0, stream>>>(
      h9sav, lwbp, lb, outsbuf + (size_t)15 * 32 * 256, 512, 256, 256);

  // ---- decoder: single 1024-row pass (rows 0..511 pred, 512..1023 rec) ----
  gather_dec_k<<<1024, 256, 0, stream>>>(outsbuf, zbuf, ydec);
  gemm16_k<1, true, true><<<dim3(64, 16), 256, 0, stream>>>(ydec, dlWb, dl_b, bufB, 1024, 4096, 256);
  tconvp_k<64, 64, 8, 8, 8, 8><<<1024, 256, 0, stream>>>(bufB, wbp_dt1, dt1_b, bufA);
  convmf_k<64, 64, 16, 16, 16, 16, 0><<<1024, 256, 0, stream>>>(bufA, wb_dc1, dc1_b, bufB);
  tconvp_k<64, 32, 16, 16, 8, 16><<<2048, 256, 0, stream>>>(bufB, wbp_dt2, dt2_b, bufA);
  convmf_k<32, 32, 32, 32, 32, 32, 0><<<1024, 256, 0, stream>>>(bufA, wb_dc2, dc2_b, bufB);
  dt3_loss_k<<<16384, 256, 0, stream>>>(bufB, dt3_w, dt3_b, x, t, out + 2, partials);
  loss_final_k<<<2, 256, 0, stream>>>(partials, out);
}

// Round 11
// 1639.905 us; speedup vs baseline: 1.7233x; 1.0681x over previous
//
#include <hip/hip_runtime.h>
#include <math.h>

#define DEV __device__ __forceinline__

typedef __attribute__((ext_vector_type(8))) short bf8_t;   // 8 x bf16 (4 VGPR)
typedef __attribute__((ext_vector_type(4))) float f4_t;    // MFMA acc

DEV float gelu_f(float v) { return 0.5f * v * (1.0f + erff(v * 0.70710678118654752f)); }
DEV float sigm_f(float v) { return 1.0f / (1.0f + __expf(-v)); }
DEV float tanh_f(float v) { return fmaf(-2.0f, 1.0f / (1.0f + __expf(2.0f * v)), 1.0f); }
DEV unsigned short f2bf(float f) {            // RNE float->bf16
  unsigned u = __float_as_uint(f);
  u = (u + 0x7FFFu + ((u >> 16) & 1u)) >> 16;
  return (unsigned short)u;
}
DEV float bf2f(unsigned short u) { return __uint_as_float((unsigned)u << 16); }

// ---------------------------------------------------------------------------
// Fused conv-weight prep: 8 tensors in one launch.
// ---------------------------------------------------------------------------
DEV void prep_norm(int li, const float* w, unsigned short* wb, int CIN) {
  int ci = li % CIN;
  int r  = li / CIN;
  int kw = r % 3; r /= 3;
  int kh = r % 3;
  int co = r / 3;
  wb[li] = f2bf(w[((co * CIN + ci) * 3 + kh) * 3 + kw]);
}
DEV void prep_par(int li, const float* w, unsigned short* wb, int COUT, int CIN) {
  const int TAPORD[9] = {4, 3, 5, 1, 7, 0, 2, 6, 8};
  int ci = li % CIN;
  int r  = li / CIN;
  int ti = r % 9;
  int co = r / 9;
  int tap = TAPORD[ti];
  int kh = tap / 3, kw = tap % 3;
  wb[li] = f2bf(w[((ci * COUT + co) * 3 + (2 - kh)) * 3 + (2 - kw)]);
}

__global__ __launch_bounds__(256) void prepw_all_k(
    const float* __restrict__ ec2, const float* __restrict__ ec3,
    const float* __restrict__ ec4, const float* __restrict__ ec5,
    const float* __restrict__ dt1, const float* __restrict__ dc1,
    const float* __restrict__ dt2, const float* __restrict__ dc2,
    unsigned short* __restrict__ o_ec2, unsigned short* __restrict__ o_ec3,
    unsigned short* __restrict__ o_ec4, unsigned short* __restrict__ o_ec5,
    unsigned short* __restrict__ o_dt1, unsigned short* __restrict__ o_dc1,
    unsigned short* __restrict__ o_dt2, unsigned short* __restrict__ o_dc2)
{
  int idx = blockIdx.x * 256 + threadIdx.x;            // < 202752
  if (idx < 9216)        prep_norm(idx,          ec2, o_ec2, 32);
  else if (idx < 27648)  prep_norm(idx - 9216,   ec3, o_ec3, 32);
  else if (idx < 64512)  prep_norm(idx - 27648,  ec4, o_ec4, 64);
  else if (idx < 101376) prep_norm(idx - 64512,  ec5, o_ec5, 64);
  else if (idx < 138240) prep_par (idx - 101376, dt1, o_dt1, 64, 64);
  else if (idx < 175104) prep_norm(idx - 138240, dc1, o_dc1, 64);
  else if (idx < 193536) prep_par (idx - 175104, dt2, o_dt2, 32, 64);
  else if (idx < 202752) prep_norm(idx - 193536, dc2, o_dc2, 32);
}

// misc prep: cast Wih->bf16, lwT, beff
__global__ __launch_bounds__(256) void prep_misc_k(
    const float* __restrict__ Wih, const float* __restrict__ lw,
    const float* __restrict__ lb,  const float* __restrict__ bih,
    unsigned short* __restrict__ wih0b, unsigned short* __restrict__ lwTb,
    unsigned short* __restrict__ lwbp,  float* __restrict__ beff)
{
  int idx = blockIdx.x * 256 + threadIdx.x;            // < 394240
  if (idx < 262144) {
    wih0b[idx] = f2bf(Wih[idx]);
  } else if (idx < 327680) {
    int i = idx - 262144;
    int n = i & 255, kcol = i >> 8;
    lwTb[i] = f2bf(lw[(size_t)n * 256 + kcol]);
  } else if (idx < 393216) {
    int i = idx - 327680;
    lwbp[i] = f2bf(lw[i]);
  } else if (idx < 394240) {
    int j = idx - 393216;
    float s = bih[j];
    const float* row = Wih + (size_t)j * 256;
    for (int n = 0; n < 256; ++n) s = fmaf(row[n], lb[n], s);
    beff[j] = s;
  }
}

// big prep: el (1M) + dl (1M) + wih frag (2.62M) + whh frag (2.62M)
__global__ __launch_bounds__(256) void prep_big_k(
    const float* __restrict__ el_w, const float* __restrict__ dl_w,
    const float* __restrict__ Wih,  const float* __restrict__ Whh,
    unsigned short* __restrict__ elWb, unsigned short* __restrict__ dlWb,
    unsigned short* __restrict__ wihb, unsigned short* __restrict__ whhb)
{
  int idx = blockIdx.x * 256 + threadIdx.x;            // < 7340032
  if (idx < 1048576) {
    int i = idx;
    int kn = i & 4095, n = i >> 12;
    elWb[i] = f2bf(el_w[(size_t)n * 4096 + ((kn & 63) * 64 + (kn >> 6))]);
  } else if (idx < 2097152) {
    int i = idx - 1048576;
    int k = i & 255, nout = i >> 8;
    dlWb[i] = f2bf(dl_w[(size_t)((nout & 63) * 64 + (nout >> 6)) * 256 + k]);
  } else if (idx < 4718592) {
    int i = idx - 2097152;
    int e = i & 7, lane = (i >> 3) & 63, ks = (i >> 9) & 7;
    int nt = (i >> 12) & 63, l = i >> 18;
    wihb[i] = f2bf(Wih[((size_t)l * 1024 + nt * 16 + (lane & 15)) * 256
                       + ks * 32 + (lane >> 4) * 8 + e]);
  } else {
    int i = idx - 4718592;
    int e = i & 7, lane = (i >> 3) & 63, ks = (i >> 9) & 7;
    int nt = (i >> 12) & 63, l = i >> 18;
    whhb[i] = f2bf(Whh[((size_t)l * 1024 + nt * 16 + (lane & 15)) * 256
                       + ks * 32 + (lane >> 4) * 8 + e]);
  }
}

// single-layer (1024x256) bf16 [j][k] -> frag layout
__global__ __launch_bounds__(256) void prep_wl1_k(
    const unsigned short* __restrict__ src, unsigned short* __restrict__ wb)
{
  int idx = blockIdx.x * 256 + threadIdx.x;   // 262144 = 1024 blocks
  int e = idx & 7, lane = (idx >> 3) & 63, ks = (idx >> 9) & 7, nt = idx >> 12;
  wb[idx] = src[(size_t)(nt * 16 + (lane & 15)) * 256 + ks * 32 + (lane >> 4) * 8 + e];
}

// ---------------------------------------------------------------------------
// ec1: 1ch 64x64 s2 -> 32ch 32x32, NHWC bf16 out. 1024 images.
// ---------------------------------------------------------------------------
__global__ __launch_bounds__(256) void ec1_k(
    const float* __restrict__ x, const float* __restrict__ t,
    const float* __restrict__ w, const float* __restrict__ bias,
    unsigned short* __restrict__ out)
{
  __shared__ float sw[288];
  __shared__ float sb[32];
  for (int i = threadIdx.x; i < 288; i += 256) sw[i] = w[i];
  if (threadIdx.x < 32) sb[threadIdx.x] = bias[threadIdx.x];
  __syncthreads();
  int idx = blockIdx.x * 256 + threadIdx.x;     // < 1024*32*32
  int ox = idx & 31, oy = (idx >> 5) & 31, n = idx >> 10;
  int b = n >> 5, j = n & 31;
  const float* ip = (j < 16) ? (x + (size_t)(b * 16 + j) * 4096)
                             : (t + (size_t)(b * 16 + j - 16) * 4096);
  float pv[9];
#pragma unroll
  for (int kh = 0; kh < 3; ++kh) {
    int iy = oy * 2 + kh - 1;
#pragma unroll
    for (int kw = 0; kw < 3; ++kw) {
      int ix = ox * 2 + kw - 1;
      pv[kh * 3 + kw] = ((unsigned)iy < 64u && (unsigned)ix < 64u) ? ip[iy * 64 + ix] : 0.f;
    }
  }
  unsigned short u[32];
#pragma unroll
  for (int co = 0; co < 32; ++co) {
    float a = sb[co];
#pragma unroll
    for (int i = 0; i < 9; ++i) a = fmaf(pv[i], sw[co * 9 + i], a);
    u[co] = f2bf(gelu_f(a));
  }
  unsigned short* op = out + (size_t)idx * 32;
#pragma unroll
  for (int p = 0; p < 4; ++p) {
    uint4 v;
    v.x = u[p*8+0] | (u[p*8+1] << 16);
    v.y = u[p*8+2] | (u[p*8+3] << 16);
    v.z = u[p*8+4] | (u[p*8+5] << 16);
    v.w = u[p*8+6] | (u[p*8+7] << 16);
    *(uint4*)&op[p * 8] = v;
  }
}

// ---------------------------------------------------------------------------
// MFMA implicit-GEMM conv. NHWC bf16 in/out. MODE: 0=s1, 1=s2.
// ---------------------------------------------------------------------------
template<int CIN, int COUT, int HIN, int WIN, int TH, int TW, int MODE>
__global__ __launch_bounds__(256) void convmf_k(
    const unsigned short* __restrict__ in, const unsigned short* __restrict__ wb,
    const float* __restrict__ bias, unsigned short* __restrict__ out)
{
  constexpr int HO  = (MODE == 1) ? HIN / 2 : HIN;
  constexpr int WO  = (MODE == 1) ? WIN / 2 : WIN;
  constexpr int TIH = (MODE == 1) ? 2 * TH + 1 : TH + 2;
  constexpr int TIW = (MODE == 1) ? 2 * TW + 1 : TW + 2;
  constexpr int CG  = CIN / 8;
  constexpr int K   = 9 * CIN;
  constexpr int KS  = K / 32;
  constexpr int NT  = COUT / 16;
  constexpr int MT  = (TH * TW) / 16;
  constexpr int MPW = MT / 4;
  constexpr int TY  = HO / TH, TX = WO / TW;

  __shared__ unsigned short lds[TIH * TIW * CG * 8];

  const int bid = blockIdx.x;
  const int n = bid / (TY * TX);
  const int trem = bid % (TY * TX);
  const int ty0 = (trem / TX) * TH, tx0 = (trem % TX) * TW;

  constexpr int ENT = TIH * TIW * CG;
  for (int e = threadIdx.x; e < ENT; e += 256) {
    int txx = e % TIW;
    int rr  = e / TIW;
    int cg  = rr % CG;
    int tyy = rr / CG;
    int iy, ix; bool ok;
    if (MODE == 0) {
      iy = ty0 + tyy - 1; ix = tx0 + txx - 1;
      ok = (unsigned)iy < (unsigned)HIN && (unsigned)ix < (unsigned)WIN;
    } else {
      iy = 2 * ty0 + tyy - 1; ix = 2 * tx0 + txx - 1;
      ok = (unsigned)iy < (unsigned)HIN && (unsigned)ix < (unsigned)WIN;
    }
    int4 val = {0, 0, 0, 0};
    if (ok) val = *(const int4*)&in[(((size_t)n * HIN + iy) * WIN + ix) * CIN + cg * 8];
    *(int4*)&lds[(size_t)e * 8] = val;
  }
  __syncthreads();

  const int lane = threadIdx.x & 63, wv = threadIdx.x >> 6;
  const int l15 = lane & 15, l4 = lane >> 4;

  f4_t acc[MPW][NT] = {};
  for (int ks = 0; ks < KS; ++ks) {
    const int tap = (ks * 32) / CIN;
    const int kh = tap / 3, kw = tap % 3;
    const int cb = ((ks * 32) % CIN) / 8 + l4;
    bf8_t bf[NT];
#pragma unroll
    for (int nt = 0; nt < NT; ++nt)
      bf[nt] = *(const bf8_t*)&wb[(size_t)(nt * 16 + l15) * K + ks * 32 + 8 * l4];
#pragma unroll
    for (int mi = 0; mi < MPW; ++mi) {
      int m = (wv * MPW + mi) * 16 + l15;
      int oy = m / TW, ox = m % TW;
      int rt = ((MODE == 1) ? 2 * oy : oy) + kh;
      int ct = ((MODE == 1) ? 2 * ox : ox) + kw;
      bf8_t a = *(const bf8_t*)&lds[(((size_t)rt * CG + cb) * TIW + ct) * 8];
#pragma unroll
      for (int nt = 0; nt < NT; ++nt)
        acc[mi][nt] = __builtin_amdgcn_mfma_f32_16x16x32_bf16(a, bf[nt], acc[mi][nt], 0, 0, 0);
    }
  }

#pragma unroll
  for (int mi = 0; mi < MPW; ++mi) {
    int mbase = (wv * MPW + mi) * 16;
#pragma unroll
    for (int nt = 0; nt < NT; ++nt) {
      int co = nt * 16 + l15;
      float bv = bias[co];
#pragma unroll
      for (int r = 0; r < 4; ++r) {
        int m = mbase + l4 * 4 + r;
        int oy = m / TW, ox = m % TW;
        float v = acc[mi][nt][r] + bv;
        out[(((size_t)n * HO + ty0 + oy) * WO + (tx0 + ox)) * COUT + co] = f2bf(gelu_f(v));
      }
    }
  }
}

// ---------------------------------------------------------------------------
// Parity-decomposed tconv (lhs_dilation=2). Wave = parity.
// ---------------------------------------------------------------------------
template<int CIN, int COUT, int HIN, int WIN, int SH, int SW>
__global__ __launch_bounds__(256) void tconvp_k(
    const unsigned short* __restrict__ in, const unsigned short* __restrict__ wbp,
    const float* __restrict__ bias, unsigned short* __restrict__ out)
{
  constexpr int HO = 2 * HIN, WO = 2 * WIN;
  constexpr int CG = CIN / 8;
  constexpr int TIH = SH + 1, TIW = SW + 1;
  constexpr int NT = COUT / 16;
  constexpr int MPW_P = (SH * SW) / 16;
  constexpr int TY = HIN / SH, TX = WIN / SW;

  __shared__ unsigned short lds[TIH * TIW * CG * 8];

  const int bid = blockIdx.x;
  const int n = bid / (TY * TX);
  const int trem = bid % (TY * TX);
  const int toy = trem / TX, tox = trem % TX;
  const int ty0s = toy * SH, tx0s = tox * SW;

  constexpr int ENT = TIH * TIW * CG;
  for (int e = threadIdx.x; e < ENT; e += 256) {
    int txx = e % TIW;
    int rr  = e / TIW;
    int cg  = rr % CG;
    int tyy = rr / CG;
    int iy = ty0s + tyy, ix = tx0s + txx;
    int4 val = {0, 0, 0, 0};
    if (iy < HIN && ix < WIN)
      val = *(const int4*)&in[(((size_t)n * HIN + iy) * WIN + ix) * CIN + cg * 8];
    *(int4*)&lds[(size_t)((tyy * CG + cg) * TIW + txx) * 8] = val;
  }
  __syncthreads();

  const int lane = threadIdx.x & 63, wv = threadIdx.x >> 6;
  const int l15 = lane & 15, l4 = lane >> 4;
  const int dy = wv >> 1, dx = wv & 1;
  const int NXT = 1 + dx;
  const int KS2 = ((1 + dy) * (1 + dx) * CIN) / 32;
  const int koff = (dy ? (dx ? 5 : 3) : (dx ? 1 : 0)) * CIN;

  f4_t acc[MPW_P][NT] = {};
  for (int ks = 0; ks < KS2; ++ks) {
    const int tapi = (ks * 32) / CIN;
    const int cb = ((ks * 32) % CIN) / 8 + l4;
    const int ra = tapi / NXT, rb = tapi % NXT;
    bf8_t bf[NT];
#pragma unroll
    for (int nt = 0; nt < NT; ++nt)
      bf[nt] = *(const bf8_t*)&wbp[(size_t)(nt * 16 + l15) * 9 * CIN + koff + ks * 32 + 8 * l4];
#pragma unroll
    for (int mi = 0; mi < MPW_P; ++mi) {
      int m = mi * 16 + l15;
      int i = m / SW, j = m % SW;
      bf8_t a = *(const bf8_t*)&lds[(size_t)(((i + ra) * CG + cb) * TIW + (j + rb)) * 8];
#pragma unroll
      for (int nt = 0; nt < NT; ++nt)
        acc[mi][nt] = __builtin_amdgcn_mfma_f32_16x16x32_bf16(a, bf[nt], acc[mi][nt], 0, 0, 0);
    }
  }

#pragma unroll
  for (int mi = 0; mi < MPW_P; ++mi) {
#pragma unroll
    for (int nt = 0; nt < NT; ++nt) {
      int co = nt * 16 + l15;
      float bv = bias[co];
#pragma unroll
      for (int r = 0; r < 4; ++r) {
        int m = mi * 16 + l4 * 4 + r;
        int i = m / SW, j = m % SW;
        int orow = 2 * (ty0s + i) + dy, ocol = 2 * (tx0s + j) + dx;
        float v = acc[mi][nt][r] + bv;
        out[(((size_t)n * HO + orow) * WO + ocol) * COUT + co] = f2bf(gelu_f(v));
      }
    }
  }
}

// ---------------------------------------------------------------------------
// MFMA GEMM. BIASMODE: 0=bias[col], 1=dl-permuted bias, 2=none.
// OUTMODE: 0=float rowmajor, 1=bf16 rowmajor, 2=bf16 ydec-permute
//          (gemm row r = tt*32+b -> out row b*16+tt; for outs->ydec fusion).
// ---------------------------------------------------------------------------
template<int BIASMODE, bool GELU, int OUTMODE>
__global__ __launch_bounds__(256) void gemm16_k(
    const unsigned short* __restrict__ A, const unsigned short* __restrict__ Bw,
    const float* __restrict__ bias, void* __restrict__ Cv, int M, int N, int K)
{
  const int lane = threadIdx.x & 63, wv = threadIdx.x >> 6;
  const int l15 = lane & 15, l4 = lane >> 4;
  const int mbase = blockIdx.y * 64 + wv * 16;
  const int nbase = blockIdx.x * 64;
  f4_t acc[4] = {};
  for (int k0 = 0; k0 < K; k0 += 32) {
    bf8_t a = *(const bf8_t*)&A[(size_t)(mbase + l15) * K + k0 + 8 * l4];
#pragma unroll
    for (int nt = 0; nt < 4; ++nt) {
      bf8_t b = *(const bf8_t*)&Bw[(size_t)(nbase + nt * 16 + l15) * K + k0 + 8 * l4];
      acc[nt] = __builtin_amdgcn_mfma_f32_16x16x32_bf16(a, b, acc[nt], 0, 0, 0);
    }
  }
#pragma unroll
  for (int nt = 0; nt < 4; ++nt) {
    int col = nbase + nt * 16 + l15;
    float bv = 0.f;
    if (BIASMODE == 0) bv = bias[col];
    if (BIASMODE == 1) bv = bias[(col & 63) * 64 + (col >> 6)];
#pragma unroll
    for (int r = 0; r < 4; ++r) {
      int row = mbase + l4 * 4 + r;
      float v = acc[nt][r] + bv;
      if (GELU) v = gelu_f(v);
      if (OUTMODE == 0)      ((float*)Cv)[(size_t)row * N + col] = v;
      else if (OUTMODE == 1) ((unsigned short*)Cv)[(size_t)row * N + col] = f2bf(v);
      else {
        int orow = (row & 31) * 16 + (row >> 5);   // b*16 + tt
        ((unsigned short*)Cv)[(size_t)orow * N + col] = f2bf(v);
      }
    }
  }
}

// ---------------------------------------------------------------------------
// dt3 (tconv 32->1) + tanh + fused loss partials.
// ---------------------------------------------------------------------------
__global__ __launch_bounds__(256) void dt3_loss_k(
    const unsigned short* __restrict__ in,
    const float* __restrict__ w, const float* __restrict__ bias,
    const float* __restrict__ xref, const float* __restrict__ tref,
    float* __restrict__ fout, float* __restrict__ partials)
{
  __shared__ float sw[288];
  for (int i = threadIdx.x; i < 288; i += 256) sw[i] = w[i];
  __syncthreads();
  int idx = blockIdx.x * 256 + threadIdx.x;
  int q = idx & 63, p = (idx >> 6) & 63, n = idx >> 12;
  float acc = bias[0];
#pragma unroll
  for (int kh = 0; kh < 3; ++kh) {
    int u = p + kh - 1;
    if (u < 0 || (u & 1) || u >= 64) continue;
#pragma unroll
    for (int kw = 0; kw < 3; ++kw) {
      int v = q + kw - 1;
      if (v < 0 || (v & 1) || v >= 64) continue;
      const uint4* r4 = (const uint4*)(in + (((size_t)n * 32 + (u >> 1)) * 32 + (v >> 1)) * 32);
      int wo = (2 - kh) * 3 + (2 - kw);
#pragma unroll
      for (int q4 = 0; q4 < 4; ++q4) {
        uint4 dv = r4[q4];
        unsigned wr[4] = {dv.x, dv.y, dv.z, dv.w};
#pragma unroll
        for (int h2 = 0; h2 < 4; ++h2) {
          unsigned d2 = wr[h2];
          int c = q4 * 8 + h2 * 2;
          acc = fmaf(__uint_as_float(d2 << 16),         sw[c * 9 + wo], acc);
          acc = fmaf(__uint_as_float(d2 & 0xffff0000u), sw[(c + 1) * 9 + wo], acc);
        }
      }
    }
  }
  float val = tanhf(acc);
  float d;
  int pix = p * 64 + q;
  if (n < 512) {
    fout[(size_t)n * 4096 + pix] = val;
    d = val - tref[(size_t)n * 4096 + pix];
  } else {
    d = val - xref[(size_t)(n - 512) * 4096 + pix];
  }
  float s = d * d;
#pragma unroll
  for (int off = 32; off > 0; off >>= 1) s += __shfl_down(s, off);
  __shared__ float ws4[4];
  if ((threadIdx.x & 63) == 0) ws4[threadIdx.x >> 6] = s;
  __syncthreads();
  if (threadIdx.x == 0) partials[blockIdx.x] = ws4[0] + ws4[1] + ws4[2] + ws4[3];
}

__global__ __launch_bounds__(256) void loss_final_k(
    const float* __restrict__ partials, float* __restrict__ out01)
{
  __shared__ float red[256];
  int base = blockIdx.x * 8192;
  float s = 0.f;
  for (int i = threadIdx.x; i < 8192; i += 256) s += partials[base + i];
  red[threadIdx.x] = s;
  __syncthreads();
#pragma unroll
  for (int st = 128; st > 0; st >>= 1) {
    if (threadIdx.x < st) red[threadIdx.x] += red[threadIdx.x + st];
    __syncthreads();
  }
  if (threadIdx.x == 0) out01[blockIdx.x] = red[0] * (1.0f / 2097152.0f);
}

// ---------------------------------------------------------------------------
// LSTM v10: like v9 but SPLIT waits — sibling-guard acquire first, then
// h-staging loads are issued and overlap tid0's poll on the x-flag (the
// last-arriving dependency). Fast __expf gate math.
// ---------------------------------------------------------------------------
#define LSTM_NB 160

DEV void gridbar(unsigned* bar, unsigned target) {
  __syncthreads();
  if (threadIdx.x == 0) {
    __hip_atomic_fetch_add(bar, 1u, __ATOMIC_RELEASE, __HIP_MEMORY_SCOPE_AGENT);
    unsigned spins = 0;
    while (__hip_atomic_load(bar, __ATOMIC_RELAXED, __HIP_MEMORY_SCOPE_AGENT) < target) {
      __builtin_amdgcn_s_sleep(2);
      if (++spins > (1u << 24)) break;   // safety valve
    }
    (void)__hip_atomic_load(bar, __ATOMIC_ACQUIRE, __HIP_MEMORY_SCOPE_AGENT);
  }
  __syncthreads();
}

DEV void spin_ge(unsigned* c, unsigned tgt) {
  unsigned spins = 0;
  while (__hip_atomic_load(c, __ATOMIC_RELAXED, __HIP_MEMORY_SCOPE_AGENT) < tgt) {
    __builtin_amdgcn_s_sleep(1);
    if (++spins > (1u << 24)) break;     // safety valve
  }
}

__global__ __launch_bounds__(256, 1) void lstm10_k(
    const float* __restrict__ z,              // (1024,256) fp32, row = b*32+t
    const unsigned short* __restrict__ wihb,  // frag-swizzled bf16 (10 layers)
    const unsigned short* __restrict__ whhb,
    const unsigned short* __restrict__ meffb, // frag-swizzled Meff (1 layer)
    const float* __restrict__ bih, const float* __restrict__ bhh,
    const float* __restrict__ beff,
    unsigned short* __restrict__ zbf,     // (16,32,256) bf16 [t][b][k]
    unsigned short* __restrict__ hbf,     // (2,10,32,256) bf16
    unsigned short* __restrict__ h9sav,   // (16,32,256) bf16, slot tt=t-15
    unsigned* __restrict__ bar)           // bar[0]=init barrier; cnt[l]=bar[32+l*32]
{
  __shared__ unsigned short s_w[4 * 2 * 4096]; // 64KB [g][wi/wh][frag 4096]
  __shared__ unsigned short s_x[8192];         // 16KB swizzled [32 rows][32 ch]
  __shared__ unsigned short s_h[8192];         // 16KB
  __shared__ float zsm[4 * 32 * 17];           // [gate][row][col pad17]
  __shared__ float cls[32 * 16];               // c state for this layer
  __shared__ float sbias[64];                  // bih+bhh for this layer [g][j]
  __shared__ float sb2[64];                    // beff+bhh0 [g][j]

  const int tid = threadIdx.x;
  const int bid = blockIdx.x;
  const int l   = bid >> 4;                    // layer 0..9
  const int jg  = bid & 15;
  const int col0 = jg * 16;
  const int lane = tid & 63, g = tid >> 6;     // wave = gate
  const int l15 = lane & 15, l4 = lane >> 4;
  const int gtid = bid * 256 + tid;

  unsigned* cown  = bar + 32 + l * 32;
  unsigned* cprev = bar + 32 + (l - 1) * 32;
  unsigned* cnext = bar + 32 + (l + 1) * 32;
  unsigned* c9    = bar + 32 + 9 * 32;
  unsigned* c0    = bar + 32;

  // ---- init: zbf transpose+bf16, zero hbf parity 1 ----
  for (int i = gtid; i < 16 * 32 * 256; i += LSTM_NB * 256) {
    int k = i & 255, r = i >> 8;
    int tt = r >> 5, b = r & 31;
    zbf[i] = f2bf(z[(size_t)(b * 32 + tt) * 256 + k]);
  }
  for (int i = gtid; i < 81920; i += LSTM_NB * 256) hbf[81920 + i] = 0;
  // ---- stage this layer's weights into LDS ----
  for (int c = tid; c < 4096; c += 256) {
    int gm = c >> 9;
    int gg = gm >> 1, m = gm & 1;
    int c2 = c & 511;
    const unsigned short* src = (m == 0 ? wihb : whhb)
        + ((size_t)(l * 64 + gg * 16 + jg) * 8) * 512;
    *(int4*)&s_w[(size_t)c * 8] = *(const int4*)&src[(size_t)c2 * 8];
  }
  for (int i = tid; i < 512; i += 256) cls[i] = 0.f;
  if (tid < 64) {
    int gg = tid >> 4, j = tid & 15;
    sbias[tid] = bih[l * 1024 + gg * 256 + col0 + j]
               + bhh[l * 1024 + gg * 256 + col0 + j];
    sb2[tid]   = beff[gg * 256 + col0 + j] + bhh[gg * 256 + col0 + j];
  }

  gridbar(bar, LSTM_NB);   // one global barrier: init staging visible

  for (int t = 0; t <= 30; ++t) {
    const int cur = t & 1, prv = cur ^ 1;
    const bool p2 = (t >= 16);
    const bool p2l0 = p2 && (l == 0);

    // ---- wait 1: own-layer siblings done t-1 (h_prev ready) ----
    if (tid == 0) {
      spin_ge(cown, 16u * t);
      (void)__hip_atomic_load(cown, __ATOMIC_ACQUIRE, __HIP_MEMORY_SCOPE_AGENT);
    }
    __syncthreads();
    // ---- stage h (loads overlap tid0's x-flag poll below) ----
    const unsigned short* hb = hbf + (size_t)((prv * 10 + l) * 32) * 256;
#pragma unroll
    for (int i = 0; i < 4; ++i) {
      int c = tid + i * 256;
      int sw = (c & ~31) | ((c & 31) ^ ((c >> 5) & 7));
      *(int4*)&s_h[(size_t)sw * 8] = *(const int4*)&hb[(size_t)c * 8];
    }
    // ---- wait 2: x-input + WAR guards ----
    if (tid == 0) {
      if (l == 0) {
        if (t >= 16) spin_ge(c9, 16u * t);
      } else {
        spin_ge(cprev, 16u * (t + 1));
      }
      if (t >= 2) {
        if (l < 9) spin_ge(cnext, 16u * (t - 1));
        else if (t >= 17) spin_ge(c0, 16u * t);
      }
      (void)__hip_atomic_load(cown, __ATOMIC_ACQUIRE, __HIP_MEMORY_SCOPE_AGENT);
    }
    __syncthreads();
    // ---- stage x ----
    const unsigned short* xb =
        (l == 0) ? (p2 ? (hbf + (size_t)((prv * 10 + 9) * 32) * 256)
                       : (zbf + (size_t)t * 32 * 256))
                 : (hbf + (size_t)((cur * 10 + l - 1) * 32) * 256);
#pragma unroll
    for (int i = 0; i < 4; ++i) {
      int c = tid + i * 256;
      int sw = (c & ~31) | ((c & 31) ^ ((c >> 5) & 7));
      *(int4*)&s_x[(size_t)sw * 8] = *(const int4*)&xb[(size_t)c * 8];
    }
    __syncthreads();
    // ---- MFMA: 4 chains of 8, frags from LDS ----
    f4_t a0 = {}, a1 = {}, b0 = {}, b1 = {};
#pragma unroll
    for (int ks = 0; ks < 8; ++ks) {
      bf8_t bwi = *(const bf8_t*)&s_w[(size_t)((g * 2 + 0) * 4096 + ks * 512 + lane * 8)];
      bf8_t bwh = *(const bf8_t*)&s_w[(size_t)((g * 2 + 1) * 4096 + ks * 512 + lane * 8)];
      int cx0 = (l15 << 5) | ((ks * 4 + l4) ^ (l15 & 7));
      int cx1 = ((16 + l15) << 5) | ((ks * 4 + l4) ^ (l15 & 7));
      bf8_t ax0 = *(const bf8_t*)&s_x[(size_t)cx0 * 8];
      bf8_t ax1 = *(const bf8_t*)&s_x[(size_t)cx1 * 8];
      bf8_t ah0 = *(const bf8_t*)&s_h[(size_t)cx0 * 8];
      bf8_t ah1 = *(const bf8_t*)&s_h[(size_t)cx1 * 8];
      a0 = __builtin_amdgcn_mfma_f32_16x16x32_bf16(ax0, bwi, a0, 0, 0, 0);
      a1 = __builtin_amdgcn_mfma_f32_16x16x32_bf16(ax1, bwi, a1, 0, 0, 0);
      b0 = __builtin_amdgcn_mfma_f32_16x16x32_bf16(ah0, bwh, b0, 0, 0, 0);
      b1 = __builtin_amdgcn_mfma_f32_16x16x32_bf16(ah1, bwh, b1, 0, 0, 0);
    }
#pragma unroll
    for (int r = 0; r < 4; ++r) {
      zsm[(g * 32 + l4 * 4 + r) * 17 + l15] = a0[r] + b0[r];
      zsm[(g * 32 + 16 + l4 * 4 + r) * 17 + l15] = a1[r] + b1[r];
    }
    __syncthreads();
    // ---- gate math: 512 elems, 2/thread (fast __expf) ----
#pragma unroll
    for (int half = 0; half < 2; ++half) {
      int e = tid + half * 256;
      int b = e >> 4, j = e & 15;
      float zi = zsm[(0 * 32 + b) * 17 + j] + (p2l0 ? sb2[j]      : sbias[j]);
      float zf = zsm[(1 * 32 + b) * 17 + j] + (p2l0 ? sb2[16 + j] : sbias[16 + j]);
      float zg = zsm[(2 * 32 + b) * 17 + j] + (p2l0 ? sb2[32 + j] : sbias[32 + j]);
      float zo = zsm[(3 * 32 + b) * 17 + j] + (p2l0 ? sb2[48 + j] : sbias[48 + j]);
      float cold = cls[b * 16 + j];
      float cn = sigm_f(zf) * cold + sigm_f(zi) * tanh_f(zg);
      cls[b * 16 + j] = cn;
      float hn = sigm_f(zo) * tanh_f(cn);
      unsigned short hv = f2bf(hn);
      hbf[(size_t)((cur * 10 + l) * 32 + b) * 256 + col0 + j] = hv;
      if (l == 9 && t >= 15) h9sav[(size_t)((t - 15) * 32 + b) * 256 + col0 + j] = hv;
    }
    __syncthreads();   // drains stores before the release flag add
    if (tid == 0)
      __hip_atomic_fetch_add(cown, 1u, __ATOMIC_RELEASE, __HIP_MEMORY_SCOPE_AGENT);
    // ---- l=0: hot-swap wi LDS region -> Meff between t=15 and t=16 ----
    if (l == 0 && t == 15) {
      for (int c = tid; c < 2048; c += 256) {
        int gg = c >> 9, c2 = c & 511;
        const unsigned short* src = meffb + ((size_t)(gg * 16 + jg) * 8) * 512;
        *(int4*)&s_w[(size_t)((gg * 2) * 512 + c2) * 8] = *(const int4*)&src[(size_t)c2 * 8];
      }
      __syncthreads();
    }
  }
}

// ---------------------------------------------------------------------------
// Decoder input gather (z half only; y_t half written by outs-GEMM OUTMODE=2)
// ---------------------------------------------------------------------------
__global__ __launch_bounds__(256) void gather_z_k(
    const float* __restrict__ z, unsigned short* __restrict__ ydec)
{
  int idx = blockIdx.x * 256 + threadIdx.x;   // < 131072
  int rr = idx >> 8, k = idx & 255;
  int b = rr >> 4, tt = rr & 15;
  ydec[(size_t)(512 + rr) * 256 + k] = f2bf(z[(size_t)(b * 32 + tt) * 256 + k]);
}

// ---------------------------------------------------------------------------
extern "C" void kernel_launch(void* const* d_in, const int* in_sizes, int n_in,
                              void* d_out, int out_size, void* d_ws, size_t ws_size,
                              hipStream_t stream) {
  const float* x     = (const float*)d_in[0];
  const float* t     = (const float*)d_in[1];
  const float* ec1_w = (const float*)d_in[2];
  const float* ec1_b = (const float*)d_in[3];
  const float* ec2_w = (const float*)d_in[4];
  const float* ec2_b = (const float*)d_in[5];
  const float* ec3_w = (const float*)d_in[6];
  const float* ec3_b = (const float*)d_in[7];
  const float* ec4_w = (const float*)d_in[8];
  const float* ec4_b = (const float*)d_in[9];
  const float* ec5_w = (const float*)d_in[10];
  const float* ec5_b = (const float*)d_in[11];
  const float* el_w  = (const float*)d_in[12];
  const float* el_b  = (const float*)d_in[13];
  const float* dl_w  = (const float*)d_in[14];
  const float* dl_b  = (const float*)d_in[15];
  const float* dt1_w = (const float*)d_in[16];
  const float* dt1_b = (const float*)d_in[17];
  const float* dc1_w = (const float*)d_in[18];
  const float* dc1_b = (const float*)d_in[19];
  const float* dt2_w = (const float*)d_in[20];
  const float* dt2_b = (const float*)d_in[21];
  const float* dc2_w = (const float*)d_in[22];
  const float* dc2_b = (const float*)d_in[23];
  const float* dt3_w = (const float*)d_in[24];
  const float* dt3_b = (const float*)d_in[25];
  const float* Wih   = (const float*)d_in[26];
  const float* Whh   = (const float*)d_in[27];
  const float* bih   = (const float*)d_in[28];
  const float* bhh   = (const float*)d_in[29];
  const float* lw    = (const float*)d_in[30];
  const float* lb    = (const float*)d_in[31];
  float* out = (float*)d_out;

  char* base = (char*)d_ws;
  size_t off = 0;
  auto alloc = [&](size_t bytes) -> char* {
    char* p = base + off;
    off += (bytes + 255) & ~(size_t)255;
    return p;
  };
  typedef unsigned short us;
  unsigned* bar   = (unsigned*)alloc(4096);
  float* zbuf     = (float*)alloc((size_t)1024 * 256 * 4);
  us*    zbf      = (us*)alloc((size_t)16 * 32 * 256 * 2);
  us*    hbf      = (us*)alloc((size_t)2 * 10 * 32 * 256 * 2);
  us*    h9sav    = (us*)alloc((size_t)16 * 32 * 256 * 2);
  us*    ydec     = (us*)alloc((size_t)1024 * 256 * 2);
  float* partials = (float*)alloc((size_t)16384 * 4);
  us* wb_ec2 = (us*)alloc((size_t)32 * 288 * 2);
  us* wb_ec3 = (us*)alloc((size_t)64 * 288 * 2);
  us* wb_ec4 = (us*)alloc((size_t)64 * 576 * 2);
  us* wb_ec5 = (us*)alloc((size_t)64 * 576 * 2);
  us* wbp_dt1 = (us*)alloc((size_t)64 * 576 * 2);
  us* wb_dc1 = (us*)alloc((size_t)64 * 576 * 2);
  us* wbp_dt2 = (us*)alloc((size_t)32 * 576 * 2);
  us* wb_dc2 = (us*)alloc((size_t)32 * 288 * 2);
  us* elWb   = (us*)alloc((size_t)256 * 4096 * 2);
  us* dlWb   = (us*)alloc((size_t)4096 * 256 * 2);
  us* wihb   = (us*)alloc((size_t)10 * 1024 * 256 * 2);      // 5 MB
  us* whhb   = (us*)alloc((size_t)10 * 1024 * 256 * 2);      // 5 MB
  us* wih0b  = (us*)alloc((size_t)1024 * 256 * 2);
  us* lwTb   = (us*)alloc((size_t)256 * 256 * 2);
  us* lwbp   = (us*)alloc((size_t)256 * 256 * 2);
  us* meffp  = (us*)alloc((size_t)1024 * 256 * 2);
  us* meffb  = (us*)alloc((size_t)1024 * 256 * 2);
  float* beff = (float*)alloc((size_t)1024 * 4);
  us* enc5   = (us*)alloc((size_t)1024 * 4096 * 2);          // 8.4 MB
  us* bufA   = (us*)alloc((size_t)1024 * 32 * 32 * 32 * 2);  // 67 MB
  us* bufB   = (us*)alloc((size_t)1024 * 32 * 32 * 32 * 2);  // 67 MB
  (void)in_sizes; (void)n_in; (void)out_size; (void)ws_size;

  hipMemsetAsync(bar, 0, 4096, stream);

  // ---- weight prep (fused: 5 launches) ----
  prepw_all_k<<<792, 256, 0, stream>>>(ec2_w, ec3_w, ec4_w, ec5_w,
                                       dt1_w, dc1_w, dt2_w, dc2_w,
                                       wb_ec2, wb_ec3, wb_ec4, wb_ec5,
                                       wbp_dt1, wb_dc1, wbp_dt2, wb_dc2);
  prep_misc_k<<<1540, 256, 0, stream>>>(Wih, lw, lb, bih, wih0b, lwTb, lwbp, beff);
  prep_big_k<<<28672, 256, 0, stream>>>(el_w, dl_w, Wih, Whh, elWb, dlWb, wihb, whhb);
  gemm16_k<2, false, 1><<<dim3(4, 16), 256, 0, stream>>>(wih0b, lwTb, lb, meffp, 1024, 256, 256);
  prep_wl1_k<<<1024, 256, 0, stream>>>(meffp, meffb);

  // ---- encoder: single 1024-image pass ----
  ec1_k<<<4096, 256, 0, stream>>>(x, t, ec1_w, ec1_b, bufA);
  convmf_k<32, 32, 32, 32, 32, 32, 0><<<1024, 256, 0, stream>>>(bufA, wb_ec2, ec2_b, bufB);
  convmf_k<32, 64, 32, 32, 16, 16, 1><<<1024, 256, 0, stream>>>(bufB, wb_ec3, ec3_b, bufA);
  convmf_k<64, 64, 16, 16, 16, 16, 0><<<1024, 256, 0, stream>>>(bufA, wb_ec4, ec4_b, bufB);
  convmf_k<64, 64, 16, 16, 8, 8, 1><<<1024, 256, 0, stream>>>(bufB, wb_ec5, ec5_b, enc5);
  gemm16_k<0, false, 0><<<dim3(4, 16), 256, 0, stream>>>(enc5, elWb, el_b, zbuf, 1024, 256, 4096);

  // ---- LSTM (MFMA, 160 blocks, split-wait dataflow sync) ----
  lstm10_k<<<LSTM_NB, 256, 0, stream>>>(zbuf, wihb, whhb, meffb, bih, bhh, beff,
                                        zbf, hbf, h9sav, bar);
  // ydec rows 0..511 = (h9sav @ lw^T + lb) permuted; rows 512..1023 = z_x
  gemm16_k<0, false, 2><<<dim3(4, 8), 256, 0, stream>>>(
      h9sav, lwbp, lb, ydec, 512, 256, 256);
  gather_z_k<<<512, 256, 0, stream>>>(zbuf, ydec);

  // ---- decoder: single 1024-row pass (rows 0..511 pred, 512..1023 rec) ----
  gemm16_k<1, true, 1><<<dim3(64, 16), 256, 0, stream>>>(ydec, dlWb, dl_b, bufB, 1024, 4096, 256);
  tconvp_k<64, 64, 8, 8, 8, 8><<<1024, 256, 0, stream>>>(bufB, wbp_dt1, dt1_b, bufA);
  convmf_k<64, 64, 16, 16, 16, 16, 0><<<1024, 256, 0, stream>>>(bufA, wb_dc1, dc1_b, bufB);
  tconvp_k<64, 32, 16, 16, 8, 16><<<2048, 256, 0, stream>>>(bufB, wbp_dt2, dt2_b, bufA);
  convmf_k<32, 32, 32, 32, 32, 32, 0><<<1024, 256, 0, stream>>>(bufA, wb_dc2, dc2_b, bufB);
  dt3_loss_k<<<16384, 256, 0, stream>>>(bufB, dt3_w, dt3_b, x, t, out + 2, partials);
  loss_final_k<<<2, 256, 0, stream>>>(partials, out);
}

// Round 12
// 1613.915 us; speedup vs baseline: 1.7510x; 1.0161x over previous
//
#include <hip/hip_runtime.h>
#include <math.h>

#define DEV __device__ __forceinline__

typedef __attribute__((ext_vector_type(8))) short bf8_t;   // 8 x bf16 (4 VGPR)
typedef __attribute__((ext_vector_type(4))) float f4_t;    // MFMA acc

DEV float gelu_f(float v) { return 0.5f * v * (1.0f + erff(v * 0.70710678118654752f)); }
DEV float sigm_f(float v) { return 1.0f / (1.0f + __expf(-v)); }
DEV float tanh_f(float v) { return fmaf(-2.0f, 1.0f / (1.0f + __expf(2.0f * v)), 1.0f); }
DEV unsigned short f2bf(float f) {            // RNE float->bf16
  unsigned u = __float_as_uint(f);
  u = (u + 0x7FFFu + ((u >> 16) & 1u)) >> 16;
  return (unsigned short)u;
}
DEV float bf2f(unsigned short u) { return __uint_as_float((unsigned)u << 16); }

DEV void astore(unsigned* p, unsigned v) {
  __hip_atomic_store(p, v, __ATOMIC_RELAXED, __HIP_MEMORY_SCOPE_AGENT);
}

// ---------------------------------------------------------------------------
// Fused conv-weight prep: 8 tensors in one launch.
// ---------------------------------------------------------------------------
DEV void prep_norm(int li, const float* w, unsigned short* wb, int CIN) {
  int ci = li % CIN;
  int r  = li / CIN;
  int kw = r % 3; r /= 3;
  int kh = r % 3;
  int co = r / 3;
  wb[li] = f2bf(w[((co * CIN + ci) * 3 + kh) * 3 + kw]);
}
DEV void prep_par(int li, const float* w, unsigned short* wb, int COUT, int CIN) {
  const int TAPORD[9] = {4, 3, 5, 1, 7, 0, 2, 6, 8};
  int ci = li % CIN;
  int r  = li / CIN;
  int ti = r % 9;
  int co = r / 9;
  int tap = TAPORD[ti];
  int kh = tap / 3, kw = tap % 3;
  wb[li] = f2bf(w[((ci * COUT + co) * 3 + (2 - kh)) * 3 + (2 - kw)]);
}

__global__ __launch_bounds__(256) void prepw_all_k(
    const float* __restrict__ ec2, const float* __restrict__ ec3,
    const float* __restrict__ ec4, const float* __restrict__ ec5,
    const float* __restrict__ dt1, const float* __restrict__ dc1,
    const float* __restrict__ dt2, const float* __restrict__ dc2,
    unsigned short* __restrict__ o_ec2, unsigned short* __restrict__ o_ec3,
    unsigned short* __restrict__ o_ec4, unsigned short* __restrict__ o_ec5,
    unsigned short* __restrict__ o_dt1, unsigned short* __restrict__ o_dc1,
    unsigned short* __restrict__ o_dt2, unsigned short* __restrict__ o_dc2)
{
  int idx = blockIdx.x * 256 + threadIdx.x;            // < 202752
  if (idx < 9216)        prep_norm(idx,          ec2, o_ec2, 32);
  else if (idx < 27648)  prep_norm(idx - 9216,   ec3, o_ec3, 32);
  else if (idx < 64512)  prep_norm(idx - 27648,  ec4, o_ec4, 64);
  else if (idx < 101376) prep_norm(idx - 64512,  ec5, o_ec5, 64);
  else if (idx < 138240) prep_par (idx - 101376, dt1, o_dt1, 64, 64);
  else if (idx < 175104) prep_norm(idx - 138240, dc1, o_dc1, 64);
  else if (idx < 193536) prep_par (idx - 175104, dt2, o_dt2, 32, 64);
  else if (idx < 202752) prep_norm(idx - 193536, dc2, o_dc2, 32);
}

// misc prep: cast Wih->bf16, lwT, beff
__global__ __launch_bounds__(256) void prep_misc_k(
    const float* __restrict__ Wih, const float* __restrict__ lw,
    const float* __restrict__ lb,  const float* __restrict__ bih,
    unsigned short* __restrict__ wih0b, unsigned short* __restrict__ lwTb,
    unsigned short* __restrict__ lwbp,  float* __restrict__ beff)
{
  int idx = blockIdx.x * 256 + threadIdx.x;            // < 394240
  if (idx < 262144) {
    wih0b[idx] = f2bf(Wih[idx]);
  } else if (idx < 327680) {
    int i = idx - 262144;
    int n = i & 255, kcol = i >> 8;
    lwTb[i] = f2bf(lw[(size_t)n * 256 + kcol]);
  } else if (idx < 393216) {
    int i = idx - 327680;
    lwbp[i] = f2bf(lw[i]);
  } else if (idx < 394240) {
    int j = idx - 393216;
    float s = bih[j];
    const float* row = Wih + (size_t)j * 256;
    for (int n = 0; n < 256; ++n) s = fmaf(row[n], lb[n], s);
    beff[j] = s;
  }
}

// big prep: el (1M) + dl (1M) + wih frag (2.62M) + whh frag (2.62M)
__global__ __launch_bounds__(256) void prep_big_k(
    const float* __restrict__ el_w, const float* __restrict__ dl_w,
    const float* __restrict__ Wih,  const float* __restrict__ Whh,
    unsigned short* __restrict__ elWb, unsigned short* __restrict__ dlWb,
    unsigned short* __restrict__ wihb, unsigned short* __restrict__ whhb)
{
  int idx = blockIdx.x * 256 + threadIdx.x;            // < 7340032
  if (idx < 1048576) {
    int i = idx;
    int kn = i & 4095, n = i >> 12;
    elWb[i] = f2bf(el_w[(size_t)n * 4096 + ((kn & 63) * 64 + (kn >> 6))]);
  } else if (idx < 2097152) {
    int i = idx - 1048576;
    int k = i & 255, nout = i >> 8;
    dlWb[i] = f2bf(dl_w[(size_t)((nout & 63) * 64 + (nout >> 6)) * 256 + k]);
  } else if (idx < 4718592) {
    int i = idx - 2097152;
    int e = i & 7, lane = (i >> 3) & 63, ks = (i >> 9) & 7;
    int nt = (i >> 12) & 63, l = i >> 18;
    wihb[i] = f2bf(Wih[((size_t)l * 1024 + nt * 16 + (lane & 15)) * 256
                       + ks * 32 + (lane >> 4) * 8 + e]);
  } else {
    int i = idx - 4718592;
    int e = i & 7, lane = (i >> 3) & 63, ks = (i >> 9) & 7;
    int nt = (i >> 12) & 63, l = i >> 18;
    whhb[i] = f2bf(Whh[((size_t)l * 1024 + nt * 16 + (lane & 15)) * 256
                       + ks * 32 + (lane >> 4) * 8 + e]);
  }
}

// single-layer (1024x256) bf16 [j][k] -> frag layout
__global__ __launch_bounds__(256) void prep_wl1_k(
    const unsigned short* __restrict__ src, unsigned short* __restrict__ wb)
{
  int idx = blockIdx.x * 256 + threadIdx.x;   // 262144 = 1024 blocks
  int e = idx & 7, lane = (idx >> 3) & 63, ks = (idx >> 9) & 7, nt = idx >> 12;
  wb[idx] = src[(size_t)(nt * 16 + (lane & 15)) * 256 + ks * 32 + (lane >> 4) * 8 + e];
}

// ---------------------------------------------------------------------------
// ec1: 1ch 64x64 s2 -> 32ch 32x32, NHWC bf16 out. 1024 images.
// ---------------------------------------------------------------------------
__global__ __launch_bounds__(256) void ec1_k(
    const float* __restrict__ x, const float* __restrict__ t,
    const float* __restrict__ w, const float* __restrict__ bias,
    unsigned short* __restrict__ out)
{
  __shared__ float sw[288];
  __shared__ float sb[32];
  for (int i = threadIdx.x; i < 288; i += 256) sw[i] = w[i];
  if (threadIdx.x < 32) sb[threadIdx.x] = bias[threadIdx.x];
  __syncthreads();
  int idx = blockIdx.x * 256 + threadIdx.x;     // < 1024*32*32
  int ox = idx & 31, oy = (idx >> 5) & 31, n = idx >> 10;
  int b = n >> 5, j = n & 31;
  const float* ip = (j < 16) ? (x + (size_t)(b * 16 + j) * 4096)
                             : (t + (size_t)(b * 16 + j - 16) * 4096);
  float pv[9];
#pragma unroll
  for (int kh = 0; kh < 3; ++kh) {
    int iy = oy * 2 + kh - 1;
#pragma unroll
    for (int kw = 0; kw < 3; ++kw) {
      int ix = ox * 2 + kw - 1;
      pv[kh * 3 + kw] = ((unsigned)iy < 64u && (unsigned)ix < 64u) ? ip[iy * 64 + ix] : 0.f;
    }
  }
  unsigned short u[32];
#pragma unroll
  for (int co = 0; co < 32; ++co) {
    float a = sb[co];
#pragma unroll
    for (int i = 0; i < 9; ++i) a = fmaf(pv[i], sw[co * 9 + i], a);
    u[co] = f2bf(gelu_f(a));
  }
  unsigned short* op = out + (size_t)idx * 32;
#pragma unroll
  for (int p = 0; p < 4; ++p) {
    uint4 v;
    v.x = u[p*8+0] | (u[p*8+1] << 16);
    v.y = u[p*8+2] | (u[p*8+3] << 16);
    v.z = u[p*8+4] | (u[p*8+5] << 16);
    v.w = u[p*8+6] | (u[p*8+7] << 16);
    *(uint4*)&op[p * 8] = v;
  }
}

// ---------------------------------------------------------------------------
// MFMA implicit-GEMM conv. NHWC bf16 in/out. MODE: 0=s1, 1=s2.
// ---------------------------------------------------------------------------
template<int CIN, int COUT, int HIN, int WIN, int TH, int TW, int MODE>
__global__ __launch_bounds__(256) void convmf_k(
    const unsigned short* __restrict__ in, const unsigned short* __restrict__ wb,
    const float* __restrict__ bias, unsigned short* __restrict__ out)
{
  constexpr int HO  = (MODE == 1) ? HIN / 2 : HIN;
  constexpr int WO  = (MODE == 1) ? WIN / 2 : WIN;
  constexpr int TIH = (MODE == 1) ? 2 * TH + 1 : TH + 2;
  constexpr int TIW = (MODE == 1) ? 2 * TW + 1 : TW + 2;
  constexpr int CG  = CIN / 8;
  constexpr int K   = 9 * CIN;
  constexpr int KS  = K / 32;
  constexpr int NT  = COUT / 16;
  constexpr int MT  = (TH * TW) / 16;
  constexpr int MPW = MT / 4;
  constexpr int TY  = HO / TH, TX = WO / TW;

  __shared__ unsigned short lds[TIH * TIW * CG * 8];

  const int bid = blockIdx.x;
  const int n = bid / (TY * TX);
  const int trem = bid % (TY * TX);
  const int ty0 = (trem / TX) * TH, tx0 = (trem % TX) * TW;

  constexpr int ENT = TIH * TIW * CG;
  for (int e = threadIdx.x; e < ENT; e += 256) {
    int txx = e % TIW;
    int rr  = e / TIW;
    int cg  = rr % CG;
    int tyy = rr / CG;
    int iy, ix; bool ok;
    if (MODE == 0) {
      iy = ty0 + tyy - 1; ix = tx0 + txx - 1;
      ok = (unsigned)iy < (unsigned)HIN && (unsigned)ix < (unsigned)WIN;
    } else {
      iy = 2 * ty0 + tyy - 1; ix = 2 * tx0 + txx - 1;
      ok = (unsigned)iy < (unsigned)HIN && (unsigned)ix < (unsigned)WIN;
    }
    int4 val = {0, 0, 0, 0};
    if (ok) val = *(const int4*)&in[(((size_t)n * HIN + iy) * WIN + ix) * CIN + cg * 8];
    *(int4*)&lds[(size_t)e * 8] = val;
  }
  __syncthreads();

  const int lane = threadIdx.x & 63, wv = threadIdx.x >> 6;
  const int l15 = lane & 15, l4 = lane >> 4;

  f4_t acc[MPW][NT] = {};
  for (int ks = 0; ks < KS; ++ks) {
    const int tap = (ks * 32) / CIN;
    const int kh = tap / 3, kw = tap % 3;
    const int cb = ((ks * 32) % CIN) / 8 + l4;
    bf8_t bf[NT];
#pragma unroll
    for (int nt = 0; nt < NT; ++nt)
      bf[nt] = *(const bf8_t*)&wb[(size_t)(nt * 16 + l15) * K + ks * 32 + 8 * l4];
#pragma unroll
    for (int mi = 0; mi < MPW; ++mi) {
      int m = (wv * MPW + mi) * 16 + l15;
      int oy = m / TW, ox = m % TW;
      int rt = ((MODE == 1) ? 2 * oy : oy) + kh;
      int ct = ((MODE == 1) ? 2 * ox : ox) + kw;
      bf8_t a = *(const bf8_t*)&lds[(((size_t)rt * CG + cb) * TIW + ct) * 8];
#pragma unroll
      for (int nt = 0; nt < NT; ++nt)
        acc[mi][nt] = __builtin_amdgcn_mfma_f32_16x16x32_bf16(a, bf[nt], acc[mi][nt], 0, 0, 0);
    }
  }

#pragma unroll
  for (int mi = 0; mi < MPW; ++mi) {
    int mbase = (wv * MPW + mi) * 16;
#pragma unroll
    for (int nt = 0; nt < NT; ++nt) {
      int co = nt * 16 + l15;
      float bv = bias[co];
#pragma unroll
      for (int r = 0; r < 4; ++r) {
        int m = mbase + l4 * 4 + r;
        int oy = m / TW, ox = m % TW;
        float v = acc[mi][nt][r] + bv;
        out[(((size_t)n * HO + ty0 + oy) * WO + (tx0 + ox)) * COUT + co] = f2bf(gelu_f(v));
      }
    }
  }
}

// ---------------------------------------------------------------------------
// Parity-decomposed tconv (lhs_dilation=2). Wave = parity.
// ---------------------------------------------------------------------------
template<int CIN, int COUT, int HIN, int WIN, int SH, int SW>
__global__ __launch_bounds__(256) void tconvp_k(
    const unsigned short* __restrict__ in, const unsigned short* __restrict__ wbp,
    const float* __restrict__ bias, unsigned short* __restrict__ out)
{
  constexpr int HO = 2 * HIN, WO = 2 * WIN;
  constexpr int CG = CIN / 8;
  constexpr int TIH = SH + 1, TIW = SW + 1;
  constexpr int NT = COUT / 16;
  constexpr int MPW_P = (SH * SW) / 16;
  constexpr int TY = HIN / SH, TX = WIN / SW;

  __shared__ unsigned short lds[TIH * TIW * CG * 8];

  const int bid = blockIdx.x;
  const int n = bid / (TY * TX);
  const int trem = bid % (TY * TX);
  const int toy = trem / TX, tox = trem % TX;
  const int ty0s = toy * SH, tx0s = tox * SW;

  constexpr int ENT = TIH * TIW * CG;
  for (int e = threadIdx.x; e < ENT; e += 256) {
    int txx = e % TIW;
    int rr  = e / TIW;
    int cg  = rr % CG;
    int tyy = rr / CG;
    int iy = ty0s + tyy, ix = tx0s + txx;
    int4 val = {0, 0, 0, 0};
    if (iy < HIN && ix < WIN)
      val = *(const int4*)&in[(((size_t)n * HIN + iy) * WIN + ix) * CIN + cg * 8];
    *(int4*)&lds[(size_t)((tyy * CG + cg) * TIW + txx) * 8] = val;
  }
  __syncthreads();

  const int lane = threadIdx.x & 63, wv = threadIdx.x >> 6;
  const int l15 = lane & 15, l4 = lane >> 4;
  const int dy = wv >> 1, dx = wv & 1;
  const int NXT = 1 + dx;
  const int KS2 = ((1 + dy) * (1 + dx) * CIN) / 32;
  const int koff = (dy ? (dx ? 5 : 3) : (dx ? 1 : 0)) * CIN;

  f4_t acc[MPW_P][NT] = {};
  for (int ks = 0; ks < KS2; ++ks) {
    const int tapi = (ks * 32) / CIN;
    const int cb = ((ks * 32) % CIN) / 8 + l4;
    const int ra = tapi / NXT, rb = tapi % NXT;
    bf8_t bf[NT];
#pragma unroll
    for (int nt = 0; nt < NT; ++nt)
      bf[nt] = *(const bf8_t*)&wbp[(size_t)(nt * 16 + l15) * 9 * CIN + koff + ks * 32 + 8 * l4];
#pragma unroll
    for (int mi = 0; mi < MPW_P; ++mi) {
      int m = mi * 16 + l15;
      int i = m / SW, j = m % SW;
      bf8_t a = *(const bf8_t*)&lds[(size_t)(((i + ra) * CG + cb) * TIW + (j + rb)) * 8];
#pragma unroll
      for (int nt = 0; nt < NT; ++nt)
        acc[mi][nt] = __builtin_amdgcn_mfma_f32_16x16x32_bf16(a, bf[nt], acc[mi][nt], 0, 0, 0);
    }
  }

#pragma unroll
  for (int mi = 0; mi < MPW_P; ++mi) {
#pragma unroll
    for (int nt = 0; nt < NT; ++nt) {
      int co = nt * 16 + l15;
      float bv = bias[co];
#pragma unroll
      for (int r = 0; r < 4; ++r) {
        int m = mi * 16 + l4 * 4 + r;
        int i = m / SW, j = m % SW;
        int orow = 2 * (ty0s + i) + dy, ocol = 2 * (tx0s + j) + dx;
        float v = acc[mi][nt][r] + bv;
        out[(((size_t)n * HO + orow) * WO + ocol) * COUT + co] = f2bf(gelu_f(v));
      }
    }
  }
}

// ---------------------------------------------------------------------------
// MFMA GEMM. BIASMODE: 0=bias[col], 1=dl-permuted bias, 2=none.
// OUTMODE: 0=float rowmajor, 1=bf16 rowmajor, 2=bf16 ydec-permute.
// ---------------------------------------------------------------------------
template<int BIASMODE, bool GELU, int OUTMODE>
__global__ __launch_bounds__(256) void gemm16_k(
    const unsigned short* __restrict__ A, const unsigned short* __restrict__ Bw,
    const float* __restrict__ bias, void* __restrict__ Cv, int M, int N, int K)
{
  const int lane = threadIdx.x & 63, wv = threadIdx.x >> 6;
  const int l15 = lane & 15, l4 = lane >> 4;
  const int mbase = blockIdx.y * 64 + wv * 16;
  const int nbase = blockIdx.x * 64;
  f4_t acc[4] = {};
  for (int k0 = 0; k0 < K; k0 += 32) {
    bf8_t a = *(const bf8_t*)&A[(size_t)(mbase + l15) * K + k0 + 8 * l4];
#pragma unroll
    for (int nt = 0; nt < 4; ++nt) {
      bf8_t b = *(const bf8_t*)&Bw[(size_t)(nbase + nt * 16 + l15) * K + k0 + 8 * l4];
      acc[nt] = __builtin_amdgcn_mfma_f32_16x16x32_bf16(a, b, acc[nt], 0, 0, 0);
    }
  }
#pragma unroll
  for (int nt = 0; nt < 4; ++nt) {
    int col = nbase + nt * 16 + l15;
    float bv = 0.f;
    if (BIASMODE == 0) bv = bias[col];
    if (BIASMODE == 1) bv = bias[(col & 63) * 64 + (col >> 6)];
#pragma unroll
    for (int r = 0; r < 4; ++r) {
      int row = mbase + l4 * 4 + r;
      float v = acc[nt][r] + bv;
      if (GELU) v = gelu_f(v);
      if (OUTMODE == 0)      ((float*)Cv)[(size_t)row * N + col] = v;
      else if (OUTMODE == 1) ((unsigned short*)Cv)[(size_t)row * N + col] = f2bf(v);
      else {
        int orow = (row & 31) * 16 + (row >> 5);   // b*16 + tt
        ((unsigned short*)Cv)[(size_t)orow * N + col] = f2bf(v);
      }
    }
  }
}

// ---------------------------------------------------------------------------
// dt3 quad version: thread owns input (i,j), computes the 2x2 output quad
// (2i..2i+1, 2j..2j+1). 4 input rows loaded once serve all 4 outputs.
// Taps per output (p,q) with u=p+kh-1 even: derived compile-time.
// ---------------------------------------------------------------------------
__global__ __launch_bounds__(256) void dt3_loss_k(
    const unsigned short* __restrict__ in,   // (1024,32,32,32) NHWC
    const float* __restrict__ w, const float* __restrict__ bias,
    const float* __restrict__ xref, const float* __restrict__ tref,
    float* __restrict__ fout, float* __restrict__ partials)
{
  __shared__ float sw[288];
  for (int i2 = threadIdx.x; i2 < 288; i2 += 256) sw[i2] = w[i2];
  __syncthreads();
  int idx = blockIdx.x * 256 + threadIdx.x;   // < 1048576, grid 4096
  int j = idx & 31, i = (idx >> 5) & 31, n = idx >> 10;
  bool okj = (j < 31), oki = (i < 31);
  const unsigned short* r00 = in + (((size_t)n * 32 + i) * 32 + j) * 32;
  const unsigned short* r01 = r00 + 32;
  const unsigned short* r10 = r00 + 1024;
  const unsigned short* r11 = r10 + 32;
  float b0 = bias[0];
  float acc00 = b0, acc01 = b0, acc10 = b0, acc11 = b0;
  uint4 z4 = {0, 0, 0, 0};
#pragma unroll
  for (int g2 = 0; g2 < 4; ++g2) {
    uint4 v00 = *(const uint4*)&r00[g2 * 8];
    uint4 v01 = okj ? *(const uint4*)&r01[g2 * 8] : z4;
    uint4 v10 = oki ? *(const uint4*)&r10[g2 * 8] : z4;
    uint4 v11 = (oki && okj) ? *(const uint4*)&r11[g2 * 8] : z4;
    unsigned a00[4] = {v00.x, v00.y, v00.z, v00.w};
    unsigned a01[4] = {v01.x, v01.y, v01.z, v01.w};
    unsigned a10[4] = {v10.x, v10.y, v10.z, v10.w};
    unsigned a11[4] = {v11.x, v11.y, v11.z, v11.w};
#pragma unroll
    for (int h2 = 0; h2 < 4; ++h2) {
      int c0 = (g2 * 8 + h2 * 2) * 9;
      float xl, xh;
      xl = __uint_as_float(a00[h2] << 16); xh = __uint_as_float(a00[h2] & 0xffff0000u);
      acc00 = fmaf(xl, sw[c0 + 4], acc00); acc00 = fmaf(xh, sw[c0 + 13], acc00);
      acc01 = fmaf(xl, sw[c0 + 5], acc01); acc01 = fmaf(xh, sw[c0 + 14], acc01);
      acc10 = fmaf(xl, sw[c0 + 7], acc10); acc10 = fmaf(xh, sw[c0 + 16], acc10);
      acc11 = fmaf(xl, sw[c0 + 8], acc11); acc11 = fmaf(xh, sw[c0 + 17], acc11);
      xl = __uint_as_float(a01[h2] << 16); xh = __uint_as_float(a01[h2] & 0xffff0000u);
      acc01 = fmaf(xl, sw[c0 + 3], acc01); acc01 = fmaf(xh, sw[c0 + 12], acc01);
      acc11 = fmaf(xl, sw[c0 + 6], acc11); acc11 = fmaf(xh, sw[c0 + 15], acc11);
      xl = __uint_as_float(a10[h2] << 16); xh = __uint_as_float(a10[h2] & 0xffff0000u);
      acc10 = fmaf(xl, sw[c0 + 1], acc10); acc10 = fmaf(xh, sw[c0 + 10], acc10);
      acc11 = fmaf(xl, sw[c0 + 2], acc11); acc11 = fmaf(xh, sw[c0 + 11], acc11);
      xl = __uint_as_float(a11[h2] << 16); xh = __uint_as_float(a11[h2] & 0xffff0000u);
      acc11 = fmaf(xl, sw[c0 + 0], acc11); acc11 = fmaf(xh, sw[c0 + 9], acc11);
    }
  }
  float o00 = tanhf(acc00), o01 = tanhf(acc01);
  float o10 = tanhf(acc10), o11 = tanhf(acc11);
  int p0 = 2 * i, q0 = 2 * j;
  size_t px = (size_t)p0 * 64 + q0;
  float s;
  if (n < 512) {
    float* fb = fout + (size_t)n * 4096;
    fb[px] = o00;      fb[px + 1] = o01;
    fb[px + 64] = o10; fb[px + 65] = o11;
    const float* tr = tref + (size_t)n * 4096;
    float d0 = o00 - tr[px],      d1 = o01 - tr[px + 1];
    float d2 = o10 - tr[px + 64], d3 = o11 - tr[px + 65];
    s = d0 * d0 + d1 * d1 + d2 * d2 + d3 * d3;
  } else {
    const float* xr = xref + (size_t)(n - 512) * 4096;
    float d0 = o00 - xr[px],      d1 = o01 - xr[px + 1];
    float d2 = o10 - xr[px + 64], d3 = o11 - xr[px + 65];
    s = d0 * d0 + d1 * d1 + d2 * d2 + d3 * d3;
  }
#pragma unroll
  for (int off = 32; off > 0; off >>= 1) s += __shfl_down(s, off);
  __shared__ float ws4[4];
  if ((threadIdx.x & 63) == 0) ws4[threadIdx.x >> 6] = s;
  __syncthreads();
  if (threadIdx.x == 0) partials[blockIdx.x] = ws4[0] + ws4[1] + ws4[2] + ws4[3];
}

__global__ __launch_bounds__(256) void loss_final_k(
    const float* __restrict__ partials, float* __restrict__ out01)
{
  __shared__ float red[256];
  int base = blockIdx.x * 2048;        // block 0: pred, block 1: rec
  float s = 0.f;
  for (int i = threadIdx.x; i < 2048; i += 256) s += partials[base + i];
  red[threadIdx.x] = s;
  __syncthreads();
#pragma unroll
  for (int st = 128; st > 0; st >>= 1) {
    if (threadIdx.x < st) red[threadIdx.x] += red[threadIdx.x + st];
    __syncthreads();
  }
  if (threadIdx.x == 0) out01[blockIdx.x] = red[0] * (1.0f / 2097152.0f);
}

// ---------------------------------------------------------------------------
// LSTM v11: R11 structure (split waits, release/acquire flags, vector staging)
// + PACKED AGENT-ATOMIC h/h9sav stores (write-through -> producer L2 stays
// clean -> the release's buffer_wbl2 has nothing dirty to write back).
// ---------------------------------------------------------------------------
#define LSTM_NB 160

DEV void gridbar(unsigned* bar, unsigned target) {
  __syncthreads();
  if (threadIdx.x == 0) {
    __hip_atomic_fetch_add(bar, 1u, __ATOMIC_RELEASE, __HIP_MEMORY_SCOPE_AGENT);
    unsigned spins = 0;
    while (__hip_atomic_load(bar, __ATOMIC_RELAXED, __HIP_MEMORY_SCOPE_AGENT) < target) {
      __builtin_amdgcn_s_sleep(2);
      if (++spins > (1u << 24)) break;   // safety valve
    }
    (void)__hip_atomic_load(bar, __ATOMIC_ACQUIRE, __HIP_MEMORY_SCOPE_AGENT);
  }
  __syncthreads();
}

DEV void spin_ge(unsigned* c, unsigned tgt) {
  unsigned spins = 0;
  while (__hip_atomic_load(c, __ATOMIC_RELAXED, __HIP_MEMORY_SCOPE_AGENT) < tgt) {
    __builtin_amdgcn_s_sleep(1);
    if (++spins > (1u << 24)) break;     // safety valve
  }
}

__global__ __launch_bounds__(256, 1) void lstm11_k(
    const float* __restrict__ z,              // (1024,256) fp32, row = b*32+t
    const unsigned short* __restrict__ wihb,  // frag-swizzled bf16 (10 layers)
    const unsigned short* __restrict__ whhb,
    const unsigned short* __restrict__ meffb, // frag-swizzled Meff (1 layer)
    const float* __restrict__ bih, const float* __restrict__ bhh,
    const float* __restrict__ beff,
    unsigned short* __restrict__ zbf,     // (16,32,256) bf16 [t][b][k]
    unsigned short* __restrict__ hbf,     // (2,10,32,256) bf16
    unsigned short* __restrict__ h9sav,   // (16,32,256) bf16, slot tt=t-15
    unsigned* __restrict__ bar)           // bar[0]=init barrier; cnt[l]=bar[32+l*32]
{
  __shared__ unsigned short s_w[4 * 2 * 4096]; // 64KB [g][wi/wh][frag 4096]
  __shared__ unsigned short s_x[8192];         // 16KB swizzled [32 rows][32 ch]
  __shared__ unsigned short s_h[8192];         // 16KB
  __shared__ float zsm[4 * 32 * 17];           // [gate][row][col pad17]
  __shared__ float cls[32 * 16];               // c state for this layer
  __shared__ float sbias[64];                  // bih+bhh for this layer [g][j]
  __shared__ float sb2[64];                    // beff+bhh0 [g][j]

  const int tid = threadIdx.x;
  const int bid = blockIdx.x;
  const int l   = bid >> 4;                    // layer 0..9
  const int jg  = bid & 15;
  const int col0 = jg * 16;
  const int lane = tid & 63, g = tid >> 6;     // wave = gate
  const int l15 = lane & 15, l4 = lane >> 4;
  const int gtid = bid * 256 + tid;

  unsigned* cown  = bar + 32 + l * 32;
  unsigned* cprev = bar + 32 + (l - 1) * 32;
  unsigned* cnext = bar + 32 + (l + 1) * 32;
  unsigned* c9    = bar + 32 + 9 * 32;
  unsigned* c0    = bar + 32;

  // ---- init: zbf transpose+bf16, zero hbf parity 1 ----
  for (int i = gtid; i < 16 * 32 * 256; i += LSTM_NB * 256) {
    int k = i & 255, r = i >> 8;
    int tt = r >> 5, b = r & 31;
    zbf[i] = f2bf(z[(size_t)(b * 32 + tt) * 256 + k]);
  }
  for (int i = gtid; i < 81920; i += LSTM_NB * 256) hbf[81920 + i] = 0;
  // ---- stage this layer's weights into LDS ----
  for (int c = tid; c < 4096; c += 256) {
    int gm = c >> 9;
    int gg = gm >> 1, m = gm & 1;
    int c2 = c & 511;
    const unsigned short* src = (m == 0 ? wihb : whhb)
        + ((size_t)(l * 64 + gg * 16 + jg) * 8) * 512;
    *(int4*)&s_w[(size_t)c * 8] = *(const int4*)&src[(size_t)c2 * 8];
  }
  for (int i = tid; i < 512; i += 256) cls[i] = 0.f;
  if (tid < 64) {
    int gg = tid >> 4, j = tid & 15;
    sbias[tid] = bih[l * 1024 + gg * 256 + col0 + j]
               + bhh[l * 1024 + gg * 256 + col0 + j];
    sb2[tid]   = beff[gg * 256 + col0 + j] + bhh[gg * 256 + col0 + j];
  }

  gridbar(bar, LSTM_NB);   // one global barrier: init staging visible

  for (int t = 0; t <= 30; ++t) {
    const int cur = t & 1, prv = cur ^ 1;
    const bool p2 = (t >= 16);
    const bool p2l0 = p2 && (l == 0);

    // ---- wait 1: own-layer siblings done t-1 (h_prev ready) ----
    if (tid == 0) {
      spin_ge(cown, 16u * t);
      (void)__hip_atomic_load(cown, __ATOMIC_ACQUIRE, __HIP_MEMORY_SCOPE_AGENT);
    }
    __syncthreads();
    // ---- stage h (loads overlap tid0's x-flag poll below) ----
    const unsigned short* hb = hbf + (size_t)((prv * 10 + l) * 32) * 256;
#pragma unroll
    for (int i = 0; i < 4; ++i) {
      int c = tid + i * 256;
      int sw = (c & ~31) | ((c & 31) ^ ((c >> 5) & 7));
      *(int4*)&s_h[(size_t)sw * 8] = *(const int4*)&hb[(size_t)c * 8];
    }
    // ---- wait 2: x-input + WAR guards ----
    if (tid == 0) {
      if (l == 0) {
        if (t >= 16) spin_ge(c9, 16u * t);
      } else {
        spin_ge(cprev, 16u * (t + 1));
      }
      if (t >= 2) {
        if (l < 9) spin_ge(cnext, 16u * (t - 1));
        else if (t >= 17) spin_ge(c0, 16u * t);
      }
      (void)__hip_atomic_load(cown, __ATOMIC_ACQUIRE, __HIP_MEMORY_SCOPE_AGENT);
    }
    __syncthreads();
    // ---- stage x ----
    const unsigned short* xb =
        (l == 0) ? (p2 ? (hbf + (size_t)((prv * 10 + 9) * 32) * 256)
                       : (zbf + (size_t)t * 32 * 256))
                 : (hbf + (size_t)((cur * 10 + l - 1) * 32) * 256);
#pragma unroll
    for (int i = 0; i < 4; ++i) {
      int c = tid + i * 256;
      int sw = (c & ~31) | ((c & 31) ^ ((c >> 5) & 7));
      *(int4*)&s_x[(size_t)sw * 8] = *(const int4*)&xb[(size_t)c * 8];
    }
    __syncthreads();
    // ---- MFMA: 4 chains of 8, frags from LDS ----
    f4_t a0 = {}, a1 = {}, b0 = {}, b1 = {};
#pragma unroll
    for (int ks = 0; ks < 8; ++ks) {
      bf8_t bwi = *(const bf8_t*)&s_w[(size_t)((g * 2 + 0) * 4096 + ks * 512 + lane * 8)];
      bf8_t bwh = *(const bf8_t*)&s_w[(size_t)((g * 2 + 1) * 4096 + ks * 512 + lane * 8)];
      int cx0 = (l15 << 5) | ((ks * 4 + l4) ^ (l15 & 7));
      int cx1 = ((16 + l15) << 5) | ((ks * 4 + l4) ^ (l15 & 7));
      bf8_t ax0 = *(const bf8_t*)&s_x[(size_t)cx0 * 8];
      bf8_t ax1 = *(const bf8_t*)&s_x[(size_t)cx1 * 8];
      bf8_t ah0 = *(const bf8_t*)&s_h[(size_t)cx0 * 8];
      bf8_t ah1 = *(const bf8_t*)&s_h[(size_t)cx1 * 8];
      a0 = __builtin_amdgcn_mfma_f32_16x16x32_bf16(ax0, bwi, a0, 0, 0, 0);
      a1 = __builtin_amdgcn_mfma_f32_16x16x32_bf16(ax1, bwi, a1, 0, 0, 0);
      b0 = __builtin_amdgcn_mfma_f32_16x16x32_bf16(ah0, bwh, b0, 0, 0, 0);
      b1 = __builtin_amdgcn_mfma_f32_16x16x32_bf16(ah1, bwh, b1, 0, 0, 0);
    }
#pragma unroll
    for (int r = 0; r < 4; ++r) {
      zsm[(g * 32 + l4 * 4 + r) * 17 + l15] = a0[r] + b0[r];
      zsm[(g * 32 + 16 + l4 * 4 + r) * 17 + l15] = a1[r] + b1[r];
    }
    __syncthreads();
    // ---- gate math: 512 elems, 2/thread; packed atomic write-through ----
#pragma unroll
    for (int half = 0; half < 2; ++half) {
      int e = tid + half * 256;
      int b = e >> 4, j = e & 15;
      float zi = zsm[(0 * 32 + b) * 17 + j] + (p2l0 ? sb2[j]      : sbias[j]);
      float zf = zsm[(1 * 32 + b) * 17 + j] + (p2l0 ? sb2[16 + j] : sbias[16 + j]);
      float zg = zsm[(2 * 32 + b) * 17 + j] + (p2l0 ? sb2[32 + j] : sbias[32 + j]);
      float zo = zsm[(3 * 32 + b) * 17 + j] + (p2l0 ? sb2[48 + j] : sbias[48 + j]);
      float cold = cls[b * 16 + j];
      float cn = sigm_f(zf) * cold + sigm_f(zi) * tanh_f(zg);
      cls[b * 16 + j] = cn;
      float hn = sigm_f(zo) * tanh_f(cn);
      float hn_hi = __shfl_down(hn, 1);
      if (!(j & 1)) {
        unsigned pk = (unsigned)f2bf(hn) | ((unsigned)f2bf(hn_hi) << 16);
        astore((unsigned*)&hbf[(size_t)((cur * 10 + l) * 32 + b) * 256 + col0 + j], pk);
        if (l == 9 && t >= 15)
          astore((unsigned*)&h9sav[(size_t)((t - 15) * 32 + b) * 256 + col0 + j], pk);
      }
    }
    __syncthreads();   // drains stores before the release flag add
    if (tid == 0)
      __hip_atomic_fetch_add(cown, 1u, __ATOMIC_RELEASE, __HIP_MEMORY_SCOPE_AGENT);
    // ---- l=0: hot-swap wi LDS region -> Meff between t=15 and t=16 ----
    if (l == 0 && t == 15) {
      for (int c = tid; c < 2048; c += 256) {
        int gg = c >> 9, c2 = c & 511;
        const unsigned short* src = meffb + ((size_t)(gg * 16 + jg) * 8) * 512;
        *(int4*)&s_w[(size_t)((gg * 2) * 512 + c2) * 8] = *(const int4*)&src[(size_t)c2 * 8];
      }
      __syncthreads();
    }
  }
}

// ---------------------------------------------------------------------------
// Decoder input gather (z half only; y_t half written by outs-GEMM OUTMODE=2)
// ---------------------------------------------------------------------------
__global__ __launch_bounds__(256) void gather_z_k(
    const float* __restrict__ z, unsigned short* __restrict__ ydec)
{
  int idx = blockIdx.x * 256 + threadIdx.x;   // < 131072
  int rr = idx >> 8, k = idx & 255;
  int b = rr >> 4, tt = rr & 15;
  ydec[(size_t)(512 + rr) * 256 + k] = f2bf(z[(size_t)(b * 32 + tt) * 256 + k]);
}

// ---------------------------------------------------------------------------
extern "C" void kernel_launch(void* const* d_in, const int* in_sizes, int n_in,
                              void* d_out, int out_size, void* d_ws, size_t ws_size,
                              hipStream_t stream) {
  const float* x     = (const float*)d_in[0];
  const float* t     = (const float*)d_in[1];
  const float* ec1_w = (const float*)d_in[2];
  const float* ec1_b = (const float*)d_in[3];
  const float* ec2_w = (const float*)d_in[4];
  const float* ec2_b = (const float*)d_in[5];
  const float* ec3_w = (const float*)d_in[6];
  const float* ec3_b = (const float*)d_in[7];
  const float* ec4_w = (const float*)d_in[8];
  const float* ec4_b = (const float*)d_in[9];
  const float* ec5_w = (const float*)d_in[10];
  const float* ec5_b = (const float*)d_in[11];
  const float* el_w  = (const float*)d_in[12];
  const float* el_b  = (const float*)d_in[13];
  const float* dl_w  = (const float*)d_in[14];
  const float* dl_b  = (const float*)d_in[15];
  const float* dt1_w = (const float*)d_in[16];
  const float* dt1_b = (const float*)d_in[17];
  const float* dc1_w = (const float*)d_in[18];
  const float* dc1_b = (const float*)d_in[19];
  const float* dt2_w = (const float*)d_in[20];
  const float* dt2_b = (const float*)d_in[21];
  const float* dc2_w = (const float*)d_in[22];
  const float* dc2_b = (const float*)d_in[23];
  const float* dt3_w = (const float*)d_in[24];
  const float* dt3_b = (const float*)d_in[25];
  const float* Wih   = (const float*)d_in[26];
  const float* Whh   = (const float*)d_in[27];
  const float* bih   = (const float*)d_in[28];
  const float* bhh   = (const float*)d_in[29];
  const float* lw    = (const float*)d_in[30];
  const float* lb    = (const float*)d_in[31];
  float* out = (float*)d_out;

  char* base = (char*)d_ws;
  size_t off = 0;
  auto alloc = [&](size_t bytes) -> char* {
    char* p = base + off;
    off += (bytes + 255) & ~(size_t)255;
    return p;
  };
  typedef unsigned short us;
  unsigned* bar   = (unsigned*)alloc(4096);
  float* zbuf     = (float*)alloc((size_t)1024 * 256 * 4);
  us*    zbf      = (us*)alloc((size_t)16 * 32 * 256 * 2);
  us*    hbf      = (us*)alloc((size_t)2 * 10 * 32 * 256 * 2);
  us*    h9sav    = (us*)alloc((size_t)16 * 32 * 256 * 2);
  us*    ydec     = (us*)alloc((size_t)1024 * 256 * 2);
  float* partials = (float*)alloc((size_t)16384 * 4);
  us* wb_ec2 = (us*)alloc((size_t)32 * 288 * 2);
  us* wb_ec3 = (us*)alloc((size_t)64 * 288 * 2);
  us* wb_ec4 = (us*)alloc((size_t)64 * 576 * 2);
  us* wb_ec5 = (us*)alloc((size_t)64 * 576 * 2);
  us* wbp_dt1 = (us*)alloc((size_t)64 * 576 * 2);
  us* wb_dc1 = (us*)alloc((size_t)64 * 576 * 2);
  us* wbp_dt2 = (us*)alloc((size_t)32 * 576 * 2);
  us* wb_dc2 = (us*)alloc((size_t)32 * 288 * 2);
  us* elWb   = (us*)alloc((size_t)256 * 4096 * 2);
  us* dlWb   = (us*)alloc((size_t)4096 * 256 * 2);
  us* wihb   = (us*)alloc((size_t)10 * 1024 * 256 * 2);      // 5 MB
  us* whhb   = (us*)alloc((size_t)10 * 1024 * 256 * 2);      // 5 MB
  us* wih0b  = (us*)alloc((size_t)1024 * 256 * 2);
  us* lwTb   = (us*)alloc((size_t)256 * 256 * 2);
  us* lwbp   = (us*)alloc((size_t)256 * 256 * 2);
  us* meffp  = (us*)alloc((size_t)1024 * 256 * 2);
  us* meffb  = (us*)alloc((size_t)1024 * 256 * 2);
  float* beff = (float*)alloc((size_t)1024 * 4);
  us* enc5   = (us*)alloc((size_t)1024 * 4096 * 2);          // 8.4 MB
  us* bufA   = (us*)alloc((size_t)1024 * 32 * 32 * 32 * 2);  // 67 MB
  us* bufB   = (us*)alloc((size_t)1024 * 32 * 32 * 32 * 2);  // 67 MB
  (void)in_sizes; (void)n_in; (void)out_size; (void)ws_size;

  hipMemsetAsync(bar, 0, 4096, stream);

  // ---- weight prep (fused: 5 launches) ----
  prepw_all_k<<<792, 256, 0, stream>>>(ec2_w, ec3_w, ec4_w, ec5_w,
                                       dt1_w, dc1_w, dt2_w, dc2_w,
                                       wb_ec2, wb_ec3, wb_ec4, wb_ec5,
                                       wbp_dt1, wb_dc1, wbp_dt2, wb_dc2);
  prep_misc_k<<<1540, 256, 0, stream>>>(Wih, lw, lb, bih, wih0b, lwTb, lwbp, beff);
  prep_big_k<<<28672, 256, 0, stream>>>(el_w, dl_w, Wih, Whh, elWb, dlWb, wihb, whhb);
  gemm16_k<2, false, 1><<<dim3(4, 16), 256, 0, stream>>>(wih0b, lwTb, lb, meffp, 1024, 256, 256);
  prep_wl1_k<<<1024, 256, 0, stream>>>(meffp, meffb);

  // ---- encoder: single 1024-image pass ----
  ec1_k<<<4096, 256, 0, stream>>>(x, t, ec1_w, ec1_b, bufA);
  convmf_k<32, 32, 32, 32, 32, 32, 0><<<1024, 256, 0, stream>>>(bufA, wb_ec2, ec2_b, bufB);
  convmf_k<32, 64, 32, 32, 16, 16, 1><<<1024, 256, 0, stream>>>(bufB, wb_ec3, ec3_b, bufA);
  convmf_k<64, 64, 16, 16, 16, 16, 0><<<1024, 256, 0, stream>>>(bufA, wb_ec4, ec4_b, bufB);
  convmf_k<64, 64, 16, 16, 8, 8, 1><<<1024, 256, 0, stream>>>(bufB, wb_ec5, ec5_b, enc5);
  gemm16_k<0, false, 0><<<dim3(4, 16), 256, 0, stream>>>(enc5, elWb, el_b, zbuf, 1024, 256, 4096);

  // ---- LSTM (MFMA, 160 blocks, clean-L2 dataflow sync) ----
  lstm11_k<<<LSTM_NB, 256, 0, stream>>>(zbuf, wihb, whhb, meffb, bih, bhh, beff,
                                        zbf, hbf, h9sav, bar);
  // ydec rows 0..511 = (h9sav @ lw^T + lb) permuted; rows 512..1023 = z_x
  gemm16_k<0, false, 2><<<dim3(4, 8), 256, 0, stream>>>(
      h9sav, lwbp, lb, ydec, 512, 256, 256);
  gather_z_k<<<512, 256, 0, stream>>>(zbuf, ydec);

  // ---- decoder: single 1024-row pass (rows 0..511 pred, 512..1023 rec) ----
  gemm16_k<1, true, 1><<<dim3(64, 16), 256, 0, stream>>>(ydec, dlWb, dl_b, bufB, 1024, 4096, 256);
  tconvp_k<64, 64, 8, 8, 8, 8><<<1024, 256, 0, stream>>>(bufB, wbp_dt1, dt1_b, bufA);
  convmf_k<64, 64, 16, 16, 16, 16, 0><<<1024, 256, 0, stream>>>(bufA, wb_dc1, dc1_b, bufB);
  tconvp_k<64, 32, 16, 16, 8, 16><<<2048, 256, 0, stream>>>(bufB, wbp_dt2, dt2_b, bufA);
  convmf_k<32, 32, 32, 32, 32, 32, 0><<<1024, 256, 0, stream>>>(bufA, wb_dc2, dc2_b, bufB);
  dt3_loss_k<<<4096, 256, 0, stream>>>(bufB, dt3_w, dt3_b, x, t, out + 2, partials);
  loss_final_k<<<2, 256, 0, stream>>>(partials, out);
}